// Round 20
// baseline (669.849 us; speedup 1.0000x reference)
//
#include <hip/hip_runtime.h>
#include <hip/hip_bf16.h>
#include <hip/hip_fp16.h>
#include <math.h>

#define NQ 8192
#define NA 32768
#define NE 500000
#define F_IN 128
#define E_E2Q 131072
#define E_E2E 800000
#define E_E2A 262144
#define E_Q2A 32768
#define N_POS 8192
#define N_NEG 24576

#define NT_TOTAL (NQ + NA + NE)
#define E_TOTAL (E_E2Q + E_E2E + E_E2A + E_Q2A)
#define NBLK_SCAN ((NT_TOTAL + 1023) / 1024)         // 529
#define CDIV(a, b) (((a) + (b) - 1) / (b))

#define BASE_Q 0
#define BASE_A NQ
#define BASE_E (NQ + NA)

// in-proj block counts (1 block per bstats row)
#define GIN_Q 128
#define GIN_A 512
#define GIN_E 768
#define GIN_TOT (GIN_Q + GIN_A + GIN_E)   // 1408
#define HB 1024                            // hist blocks appended

// gather grid
#define GB_Q 2048
#define GB_E 4096
#define GB_A 8192

// out-proj grid
#define TOP_Q 64
#define TOP_A 256
#define TOP_E 3907

// kqv grid
#define KQ_Q 32        // CDIV(NQ,256)
#define KQ_E 1954      // CDIV(NE,256), x2 col tiles
#define KQ_A 128       // CDIV(NA,256)
#define KQ_TOT (KQ_Q + 2 * KQ_E + KQ_A)   // 4068
#define SMEM_KQV 64512

typedef _Float16 half8_t __attribute__((ext_vector_type(8)));
typedef _Float16 half2_t __attribute__((ext_vector_type(2)));
typedef float f32x4_t __attribute__((ext_vector_type(4)));

__device__ inline void load_lds16(const void* g, void* l) {
  __builtin_amdgcn_global_load_lds((const __attribute__((address_space(1))) void*)g,
                                   (__attribute__((address_space(3))) void*)l, 16, 0, 0);
}

__device__ inline float fast_gelu(float v) {
  float u = 1.5957691216057308f * fmaf(0.044715f * v * v, v, v);
  return v / (1.f + __expf(-u));
}

// ---------------- K1: prep (zero row_start + WinT + WoutT) ----------------

__global__ __launch_bounds__(256) void prep_misc(
    float* __restrict__ row_start_f,
    const float* __restrict__ W_in, _Float16* __restrict__ WinT,
    const float* __restrict__ W_out, _Float16* __restrict__ WoutT)
{
  int bid = blockIdx.x;
  if (bid < 128) {
    size_t i = (size_t)bid * 256 + threadIdx.x;
    size_t stride = (size_t)128 * 256;
    for (; i < NT_TOTAL; i += stride) row_start_f[i] = 0.f;
  } else if (bid < 320) {
    int b = bid - 128;
    int t = b >> 6, n = b & 63, k = threadIdx.x;
    if (k < 136) {
      float v = (k < 128) ? W_in[(size_t)t * 128 * 64 + (size_t)k * 64 + n] : 0.f;
      WinT[((size_t)t * 64 + n) * 136 + k] = (_Float16)v;
    }
  } else {
    int b = bid - 320;
    int t = b >> 6, n = b & 63, k = threadIdx.x;
    if (k < 72) {
      float v = (k < 64) ? W_out[(size_t)t * 64 * 64 + (size_t)k * 64 + n] : 0.f;
      WoutT[((size_t)t * 64 + n) * 72 + k] = (_Float16)v;
    }
  }
}

// ---------------- K2: in-proj (pipelined LDS stage) + hist, block-range merged ----------------

__global__ __launch_bounds__(256) void inproj_hist_all(
    const float* __restrict__ xq, const float* __restrict__ xa,
    const float* __restrict__ xe,
    const _Float16* __restrict__ WinT, const float* __restrict__ b_in,
    _Float16* __restrict__ y_h, float* __restrict__ bstats,
    const int* __restrict__ hd0, const int* __restrict__ hd1,
    const int* __restrict__ hd2, const int* __restrict__ hd3,
    unsigned* __restrict__ cnt)
{
  __shared__ __align__(16) float bufA[32 * 128];
  __shared__ __align__(16) float bufB[32 * 128];
  __shared__ _Float16 Bs[64 * 136];
  __shared__ float s1[64], s2[64];

  int bid = blockIdx.x;
  if (bid >= GIN_TOT) {
    int i = (bid - GIN_TOT) * 256 + threadIdx.x;
    int stride = HB * 256;
    for (; i < E_TOTAL; i += stride) {
      if (i < E_E2Q) atomicAdd(&cnt[BASE_Q + hd0[i]], 1u);
      else if (i < E_E2Q + E_E2E) atomicAdd(&cnt[BASE_E + hd1[i - E_E2Q]], 1u);
      else if (i < E_E2Q + E_E2E + E_E2A)
        atomicAdd(&cnt[BASE_A + hd2[i - E_E2Q - E_E2E]], 1u);
      else atomicAdd(&cnt[BASE_A + hd3[i - E_E2Q - E_E2E - E_E2A]], 1u);
    }
    return;
  }

  int t, lb, nb;
  const float* Af;
  _Float16* oh;
  if (bid < GIN_Q)              { t = 0; lb = bid;                 nb = GIN_Q; Af = xq; oh = y_h; }
  else if (bid < GIN_Q + GIN_A) { t = 1; lb = bid - GIN_Q;         nb = GIN_A; Af = xa; oh = y_h + (size_t)NQ * 64; }
  else                          { t = 2; lb = bid - GIN_Q - GIN_A; nb = GIN_E; Af = xe; oh = y_h + (size_t)(NQ + NA) * 64; }
  int M = (t == 0) ? NQ : (t == 1) ? NA : NE;
  int nh = CDIV(M, 32);
  const _Float16* WT = WinT + (size_t)t * 64 * 136;
  const float* bias = b_in + t * 64;

  int tid = threadIdx.x, w = tid >> 6, l = tid & 63;
  int lr = l & 15, lg = l >> 4;
  int wrow = (w & 1) * 16;
  int wcol = (w >> 1) * 32;

  for (int idx = tid; idx < 64 * 136 / 8; idx += 256)
    *(half8_t*)&Bs[idx * 8] = *(const half8_t*)&WT[(size_t)idx * 8];
  if (tid < 64) { s1[tid] = 0.f; s2[tid] = 0.f; }

  float bval[2];
  bval[0] = bias[wcol + lr];
  bval[1] = bias[wcol + 16 + lr];
  float ps1[2] = {}, ps2[2] = {};

  auto stage = [&](float* buf, int h) {
    const char* srcbase = (const char*)Af + (size_t)h * 32 * 512;
    int rowlim = M - h * 32;
#pragma unroll
    for (int r = 0; r < 4; ++r) {
      int unit = r * 4 + w;
      char* ldst = (char*)buf + unit * 1024;
      int p = unit * 1024 + l * 16;
      int row = p >> 9;
      const char* src = (row < rowlim) ? srcbase + (size_t)row * 512 + (p & 511)
                                       : srcbase;
      load_lds16(src, ldst);
    }
  };

  int h0 = lb;
  if (h0 < nh) stage(bufA, h0);
  __syncthreads();

  float* cur = bufA;
  float* nxt = bufB;
  for (int h = h0; h < nh; h += nb) {
    int h2 = h + nb;
    bool more = h2 < nh;
    if (more) {
      stage(nxt, h2);
      asm volatile("s_waitcnt vmcnt(4)" ::: "memory");
    } else {
      asm volatile("s_waitcnt vmcnt(0)" ::: "memory");
    }
    __builtin_amdgcn_sched_barrier(0);
    __builtin_amdgcn_s_barrier();

    f32x4_t acc[2] = {};
#pragma unroll
    for (int ks = 0; ks < 4; ++ks) {
      const float4* pa = (const float4*)((const char*)cur +
                          (wrow + lr) * 512 + ks * 128 + lg * 32);
      float4 x0 = pa[0], x1 = pa[1];
      half8_t a0 = {(_Float16)x0.x, (_Float16)x0.y, (_Float16)x0.z, (_Float16)x0.w,
                    (_Float16)x1.x, (_Float16)x1.y, (_Float16)x1.z, (_Float16)x1.w};
#pragma unroll
      for (int ct = 0; ct < 2; ++ct) {
        half8_t b = *(const half8_t*)&Bs[(wcol + ct * 16 + lr) * 136 + ks * 32 + lg * 8];
        acc[ct] = __builtin_amdgcn_mfma_f32_16x16x32_f16(a0, b, acc[ct], 0, 0, 0);
      }
    }
    int rbase = h * 32 + wrow + lg * 4;
#pragma unroll
    for (int ct = 0; ct < 2; ++ct) {
      int col = wcol + ct * 16 + lr;
#pragma unroll
      for (int j = 0; j < 4; ++j) {
        int row = rbase + j;
        if (row >= M) continue;
        float val = fmaxf(acc[ct][j] + bval[ct], 0.f);
        oh[(size_t)row * 64 + col] = (_Float16)val;
        ps1[ct] += val;
        ps2[ct] += val * val;
      }
    }
    __builtin_amdgcn_s_barrier();
    float* tmp = cur; cur = nxt; nxt = tmp;
  }

#pragma unroll
  for (int ct = 0; ct < 2; ++ct) {
    int col = wcol + ct * 16 + lr;
    atomicAdd(&s1[col], ps1[ct]);
    atomicAdd(&s2[col], ps2[ct]);
  }
  __syncthreads();
  if (tid < 64) {
    bstats[(size_t)blockIdx.x * 128 + tid] = s1[tid];
    bstats[(size_t)blockIdx.x * 128 + 64 + tid] = s2[tid];
  }
}

// ---------------- K3: stats_reduce + scan1 merged ----------------

__global__ __launch_bounds__(256) void reduce_scan1(
    const float* __restrict__ bstats, float* __restrict__ stats,
    unsigned* __restrict__ arr, unsigned* __restrict__ bsums)
{
  __shared__ __align__(16) char shbuf[1024];
  int bid = blockIdx.x;
  int t0 = threadIdx.x;
  if (bid < 384) {
    float* sh = (float*)shbuf;
    int t = bid >> 7, c = bid & 127;
    int nb = (t == 0) ? GIN_Q : (t == 1) ? GIN_A : GIN_E;
    int base = (t == 0) ? 0 : (t == 1) ? GIN_Q : (GIN_Q + GIN_A);
    float s = 0.f;
    for (int i = t0; i < nb; i += 256)
      s += bstats[(size_t)(base + i) * 128 + c];
    sh[t0] = s;
    __syncthreads();
    for (int off2 = 128; off2 > 0; off2 >>= 1) {
      if (t0 < off2) sh[t0] += sh[t0 + off2];
      __syncthreads();
    }
    if (t0 == 0) stats[t * 128 + c] = sh[0];
  } else {
    unsigned* sh = (unsigned*)shbuf;
    int blk = bid - 384;
    int base = blk * 1024 + t0 * 4;
    unsigned v[4];
    unsigned s = 0;
#pragma unroll
    for (int j = 0; j < 4; ++j) {
      v[j] = (base + j < NT_TOTAL) ? arr[base + j] : 0u;
      s += v[j];
    }
    sh[t0] = s;
    __syncthreads();
    for (int off = 1; off < 256; off <<= 1) {
      unsigned x = (t0 >= off) ? sh[t0 - off] : 0u;
      __syncthreads();
      sh[t0] += x;
      __syncthreads();
    }
    unsigned run = sh[t0] - s;
#pragma unroll
    for (int j = 0; j < 4; ++j) {
      if (base + j < NT_TOTAL) arr[base + j] = run;
      run += v[j];
    }
    if (t0 == 255) bsums[blk] = sh[255];
  }
}

// ---------------- K4: scan2 (block 0) + bn_finalize+kqv_bias2 (block 1) ----------------

__global__ __launch_bounds__(256) void scan2_bn(
    unsigned* __restrict__ bsums, int nbk,
    const float* __restrict__ stats,
    const float* __restrict__ gamma, const float* __restrict__ beta,
    float* __restrict__ scale, float* __restrict__ shift,
    const float* __restrict__ b_kqv, const float* __restrict__ W_kqv,
    float* __restrict__ bias2)
{
  int t0 = threadIdx.x;
  if (blockIdx.x == 0) {
    __shared__ unsigned sh[256];
    __shared__ unsigned carry;
    if (t0 == 0) carry = 0;
    __syncthreads();
    for (int chunk = 0; chunk < nbk; chunk += 256) {
      int i = chunk + t0;
      unsigned v = (i < nbk) ? bsums[i] : 0u;
      sh[t0] = v;
      __syncthreads();
      for (int off = 1; off < 256; off <<= 1) {
        unsigned x = (t0 >= off) ? sh[t0 - off] : 0u;
        __syncthreads();
        sh[t0] += x;
        __syncthreads();
      }
      unsigned inc = sh[t0];
      unsigned c = carry;
      __syncthreads();
      if (i < nbk) bsums[i] = c + inc - v;
      if (t0 == 255) carry = c + sh[255];
      __syncthreads();
    }
  } else {
    __shared__ float sshift[192];
    if (t0 < 192) {
      int ty = t0 >> 6, c = t0 & 63;
      float invN = (ty == 0) ? (1.f / NQ) : (ty == 1) ? (1.f / NA) : (1.f / NE);
      float mu = stats[ty * 128 + c] * invN;
      float var = stats[ty * 128 + 64 + c] * invN - mu * mu;
      float rs = rsqrtf(var + 1e-5f);
      float gm = gamma[t0];
      float sc = gm * rs;
      float sf = beta[t0] - gm * mu * rs;
      scale[t0] = sc;
      shift[t0] = sf;
      sshift[t0] = sf;
    }
    __syncthreads();
    for (int idx = t0; idx < 576; idx += 256) {
      int t = idx / 192, n = idx % 192;
      float s = b_kqv[t * 192 + n];
      for (int k = 0; k < 64; ++k)
        s += sshift[t * 64 + k] * W_kqv[(size_t)t * 64 * 192 + k * 192 + n];
      bias2[t * 192 + n] = s;
    }
  }
}

// ---------------- K5: scan3 + wprep_kqv merged ----------------

__global__ __launch_bounds__(256) void scan3_wprep(
    unsigned* __restrict__ arr, const unsigned* __restrict__ bsums,
    unsigned* __restrict__ cursor,
    const float* __restrict__ W_kqv, const float* __restrict__ bias2,
    const float* __restrict__ A_k, const float* __restrict__ A_v,
    const float* __restrict__ scale,
    _Float16* __restrict__ WqT, _Float16* __restrict__ WeT,
    _Float16* __restrict__ WaT, float* __restrict__ bias_big)
{
  int bid = blockIdx.x;
  int t0 = threadIdx.x;
  if (bid < NBLK_SCAN) {
    int base = bid * 1024 + t0 * 4;
    unsigned add = bsums[bid];
#pragma unroll
    for (int j = 0; j < 4; ++j) {
      int idx = base + j;
      if (idx < NT_TOTAL) {
        unsigned r = arr[idx] + add;
        arr[idx] = r;
        cursor[idx] = r;
      }
    }
    return;
  }
  int j = (bid - NBLK_SCAN) * 4 + (t0 >> 6);
  int c = t0 & 63;
  if (j >= 640) return;
  int t, jj, bofs;
  _Float16* W;
  if (j < 192)      { t = 0; jj = j;       W = WqT; bofs = 0; }
  else if (j < 512) { t = 2; jj = j - 192; W = WeT; bofs = 192; }
  else              { t = 1; jj = j - 512; W = WaT; bofs = 512; }
  const float* Wt = W_kqv + (size_t)t * 64 * 192;
  const float* b2 = bias2 + t * 192;
  int mode = 0, rel = 0, sub = 0;
  if (t == 1) { mode = 1; rel = (jj < 64) ? 2 : 3; sub = jj & 63; }
  else if (jj >= 64 && jj < 128) { mode = 1; rel = (t == 0) ? 0 : 1; sub = jj - 64; }
  else if (jj >= 128) {
    mode = 2; sub = (jj - 128) & 63;
    rel = (t == 0) ? 3 : ((jj - 128) >> 6);
  }
  int h = sub >> 5, x = sub & 31;
  float wv, bv;
  if (mode == 0) {
    wv = Wt[(size_t)c * 192 + jj];
    bv = b2[jj];
  } else if (mode == 1) {
    const float* Ar = A_k + ((size_t)rel * 2048 + h * 1024 + x * 32);
    float s = 0.f, sb = 0.f;
    for (int f = 0; f < 32; ++f) {
      float a = Ar[f];
      s = fmaf(a, Wt[(size_t)c * 192 + 64 + h * 32 + f], s);
      sb = fmaf(a, b2[64 + h * 32 + f], sb);
    }
    wv = s; bv = sb;
  } else {
    const float* Ar = A_v + ((size_t)rel * 2048 + h * 1024 + x);
    float s = 0.f, sb = 0.f;
    for (int d = 0; d < 32; ++d) {
      float a = Ar[d * 32];
      s = fmaf(a, Wt[(size_t)c * 192 + 128 + h * 32 + d], s);
      sb = fmaf(a, b2[128 + h * 32 + d], sb);
    }
    wv = s; bv = sb;
  }
  wv *= scale[t * 64 + c];
  W[(size_t)jj * 72 + c] = (_Float16)wv;
  if (c < 8) W[(size_t)jj * 72 + 64 + c] = (_Float16)0.f;
  if (c == 0) bias_big[bofs + jj] = bv;
}

// ---------------- K6: scatter (standalone, no LDS) ----------------

__global__ __launch_bounds__(256) void scatter_all(
    const int* __restrict__ s0, const int* __restrict__ d0,
    const int* __restrict__ s1, const int* __restrict__ d1,
    const int* __restrict__ s2, const int* __restrict__ d2,
    const int* __restrict__ s3, const int* __restrict__ d3,
    unsigned* __restrict__ cursor, unsigned* __restrict__ eidx)
{
  int i = blockIdx.x * blockDim.x + threadIdx.x;
  int stride = gridDim.x * blockDim.x;
  for (; i < E_TOTAL; i += stride) {
    unsigned pos, pay;
    if (i < E_E2Q) {
      pos = atomicAdd(&cursor[BASE_Q + d0[i]], 1u);
      pay = (unsigned)(s0[i] * 320);
    } else if (i < E_E2Q + E_E2E) {
      int k = i - E_E2Q;
      pos = atomicAdd(&cursor[BASE_E + d1[k]], 1u);
      pay = (unsigned)(s1[k] * 320);
    } else if (i < E_E2Q + E_E2E + E_E2A) {
      int k = i - E_E2Q - E_E2E;
      pos = atomicAdd(&cursor[BASE_A + d2[k]], 1u);
      pay = (unsigned)(s2[k] * 320);
    } else {
      int k = i - E_E2Q - E_E2E - E_E2A;
      pos = atomicAdd(&cursor[BASE_A + d3[k]], 1u);
      pay = (unsigned)(s3[k] * 192) | 0x80000000u;
    }
    eidx[pos] = pay;
  }
}

// ---------------- kqv GEMM body (device fn; 512 threads, BM=256) ----------------

template <int BNT>
__device__ __forceinline__ void kqv_body(
    char* smem,
    const _Float16* __restrict__ Ah,
    const _Float16* __restrict__ WT, const float* __restrict__ bias, int M,
    _Float16* __restrict__ oh, int LDO, int row0, int colbase)
{
  constexpr int KP = 72;
  constexpr int TP = BNT + 8;
  _Float16* As = (_Float16*)smem;
  _Float16* Bs = As + 256 * KP;
  _Float16* Ts = (_Float16*)smem;
  int tid = threadIdx.x;

  {
    for (int idx = tid; idx < 256 * 8; idx += 512) {
      int row = idx >> 3, c = (idx & 7);
      int gr = row0 + row;
      half8_t a8 = {};
      if (gr < M) a8 = *(const half8_t*)&Ah[(size_t)gr * 64 + c * 8];
      *(half8_t*)&As[row * KP + c * 8] = a8;
    }
  }
  {
    const _Float16* wsrc = WT + (size_t)colbase * KP;
    for (int idx = tid; idx < BNT * KP / 8; idx += 512)
      *(half8_t*)&Bs[idx * 8] = *(const half8_t*)&wsrc[(size_t)idx * 8];
  }
  __syncthreads();

  int w = tid >> 6, l = tid & 63;
  int lr = l & 15, lg = l >> 4;
  constexpr int NCT = BNT / 16;
  f32x4_t acc[2][NCT] = {};
#pragma unroll
  for (int ks = 0; ks < 2; ++ks) {
    half8_t a0 = *(const half8_t*)&As[(w * 32 + lr) * KP + ks * 32 + lg * 8];
    half8_t a1 = *(const half8_t*)&As[(w * 32 + 16 + lr) * KP + ks * 32 + lg * 8];
#pragma unroll
    for (int ct = 0; ct < NCT; ++ct) {
      half8_t b = *(const half8_t*)&Bs[(ct * 16 + lr) * KP + ks * 32 + lg * 8];
      acc[0][ct] = __builtin_amdgcn_mfma_f32_16x16x32_f16(a0, b, acc[0][ct], 0, 0, 0);
      acc[1][ct] = __builtin_amdgcn_mfma_f32_16x16x32_f16(a1, b, acc[1][ct], 0, 0, 0);
    }
  }

  float bval[NCT];
#pragma unroll
  for (int ct = 0; ct < NCT; ++ct) bval[ct] = bias[colbase + ct * 16 + lr];

#pragma unroll
  for (int rt = 0; rt < 2; ++rt) {
    __syncthreads();
    int r2base = w * 16 + lg * 4;
#pragma unroll
    for (int ct = 0; ct < NCT; ++ct) {
      int colL = ct * 16 + lr;
#pragma unroll
      for (int j = 0; j < 4; ++j)
        Ts[(r2base + j) * TP + colL] = (_Float16)(acc[rt][ct][j] + bval[ct]);
    }
    __syncthreads();
    constexpr int C8 = BNT / 8;
    for (int idx = tid; idx < 128 * C8; idx += 512) {
      int r2 = idx / C8, c8 = (idx % C8) * 8;
      int gr = row0 + (r2 >> 4) * 32 + rt * 16 + (r2 & 15);
      if (gr < M)
        *(half8_t*)&oh[(size_t)gr * LDO + colbase + c8] = *(const half8_t*)&Ts[r2 * TP + c8];
    }
  }
}

// ---------------- K7: kqv GEMMs merged (512 threads) ----------------

__global__ __launch_bounds__(512) void kqv_all(
    const _Float16* __restrict__ y_h,
    const _Float16* __restrict__ WqT, const _Float16* __restrict__ WeT,
    const _Float16* __restrict__ WaT, const float* __restrict__ bias_big,
    _Float16* __restrict__ kqvQ, _Float16* __restrict__ kqvE,
    _Float16* __restrict__ kqvA)
{
  extern __shared__ __align__(16) char smem[];
  int bid = blockIdx.x;
  if (bid < KQ_Q) {
    kqv_body<192>(smem, y_h, WqT, bias_big, NQ, kqvQ, 192, bid * 256, 0);
  } else if (bid < KQ_Q + 2 * KQ_E) {
    int b = bid - KQ_Q;
    int ct = b / KQ_E;
    int rb = b % KQ_E;
    kqv_body<160>(smem, y_h + (size_t)(NQ + NA) * 64, WeT, bias_big + 192, NE,
                  kqvE, 320, rb * 256, ct * 160);
  } else {
    int b = bid - KQ_Q - 2 * KQ_E;
    kqv_body<128>(smem, y_h + (size_t)NQ * 64, WaT, bias_big + 512, NA,
                  kqvA, 128, b * 256, 0);
  }
}

// ---------------- gather body ----------------

template <int NREL>
__device__ __forceinline__ void gather_body(
    int bidLocal, int nblocks, int N, int nodebase,
    const unsigned* __restrict__ row_start, const unsigned* __restrict__ row_end,
    const unsigned* __restrict__ eidx,
    const _Float16* __restrict__ baseA, int vofA,
    const _Float16* __restrict__ baseB, int vofB,
    const _Float16* __restrict__ qtA, int ldqA,
    const _Float16* __restrict__ qtB, int ldqB,
    const float* __restrict__ prelA, const float* __restrict__ prelB,
    _Float16* __restrict__ agg)
{
  int lane = threadIdx.x & 63;
  int h = lane >> 5, f = lane & 31;
  int idx2 = h * 32 + 2 * (f & 15);
  const float isd = 0.17677669529663687f;
  float pr0 = prelA[h] * isd;
  float pr1 = (NREL == 2) ? prelB[h] * isd : 0.f;

  int wid = (int)(((size_t)bidLocal * 256 + threadIdx.x) >> 6);
  int nw = nblocks * 4;

  int n0 = wid;
  unsigned b0s = 0, b0e = 0, e00 = 0, e01 = 0;
  half2_t q00p = {}, q01p = {};
  if (n0 < N) {
    b0s = row_start[nodebase + n0];
    b0e = row_end[nodebase + n0];
    q00p = *(const half2_t*)&qtA[(size_t)n0 * ldqA + idx2];
    if (NREL == 2) q01p = *(const half2_t*)&qtB[(size_t)n0 * ldqB + idx2];
    e00 = eidx[b0s];
    e01 = eidx[b0s + 1];
  }
  int n1 = n0 + nw;
  unsigned b1s = 0, b1e = 0;
  half2_t q10p = {}, q11p = {};
  if (n0 < N && n1 < N) {
    b1s = row_start[nodebase + n1];
    b1e = row_end[nodebase + n1];
    q10p = *(const half2_t*)&qtA[(size_t)n1 * ldqA + idx2];
    if (NREL == 2) q11p = *(const half2_t*)&qtB[(size_t)n1 * ldqB + idx2];
  }

  while (n0 < N) {
    unsigned e10 = 0, e11 = 0;
    if (n1 < N) {
      e10 = eidx[b1s];
      e11 = eidx[b1s + 1];
    }
    int n2 = n1 + nw;
    unsigned b2s = 0, b2e = 0;
    half2_t q20p = {}, q21p = {};
    if (n2 < N) {
      b2s = row_start[nodebase + n2];
      b2e = row_end[nodebase + n2];
      q20p = *(const half2_t*)&qtA[(size_t)n2 * ldqA + idx2];
      if (NREL == 2) q21p = *(const half2_t*)&qtB[(size_t)n2 * ldqB + idx2];
    }

    float vs = 0.f, ss = 0.f;
    unsigned i = b0s;

    auto do_pair = [&](unsigned p1, unsigned p2) {
      unsigned o1 = p1 & 0x7FFFFFFFu, o2 = p2 & 0x7FFFFFFFu;
      bool r1 = (NREL == 2) && (p1 >> 31);
      bool r2 = (NREL == 2) && (p2 >> 31);
      const _Float16* b1 = (r1 ? baseB : baseA) + o1;
      const _Float16* b2 = (r2 ? baseB : baseA) + o2;
      half2_t k21 = *(const half2_t*)&b1[idx2];
      float v1 = (float)b1[(r1 ? vofB : vofA) + lane];
      half2_t k22 = *(const half2_t*)&b2[idx2];
      float v2 = (float)b2[(r2 ? vofB : vofA) + lane];
      float sa = __builtin_amdgcn_fdot2(k21, r1 ? q01p : q00p, 0.f, false);
      float sb = __builtin_amdgcn_fdot2(k22, r2 ? q01p : q00p, 0.f, false);
#pragma unroll
      for (int off = 1; off <= 8; off <<= 1) {
        sa += __shfl_xor(sa, off, 32);
        sb += __shfl_xor(sb, off, 32);
      }
      float w1 = __expf(sa * (r1 ? pr1 : pr0));
      float w2 = __expf(sb * (r2 ? pr1 : pr0));
      ss += w1 + w2;
      vs = fmaf(w1, v1, vs);
      vs = fmaf(w2, v2, vs);
    };
    auto do_single = [&](unsigned p1) {
      unsigned o1 = p1 & 0x7FFFFFFFu;
      bool r1 = (NREL == 2) && (p1 >> 31);
      const _Float16* b1 = (r1 ? baseB : baseA) + o1;
      half2_t k21 = *(const half2_t*)&b1[idx2];
      float v1 = (float)b1[(r1 ? vofB : vofA) + lane];
      float sa = __builtin_amdgcn_fdot2(k21, r1 ? q01p : q00p, 0.f, false);
#pragma unroll
      for (int off = 1; off <= 8; off <<= 1) sa += __shfl_xor(sa, off, 32);
      float w1 = __expf(sa * (r1 ? pr1 : pr0));
      ss += w1;
      vs = fmaf(w1, v1, vs);
    };

    if (i + 2 <= b0e) { do_pair(e00, e01); i += 2; }
    else if (i < b0e) { do_single(e00); i = b0e; }
    for (; i + 2 <= b0e; i += 2) do_pair(eidx[i], eidx[i + 1]);
    if (i < b0e) do_single(eidx[i]);

    float val = (ss > 0.f) ? vs / ss : 0.f;
    val = fast_gelu(val);
    agg[((size_t)(nodebase + n0)) * 64 + lane] = (_Float16)val;

    n0 = n1; b0s = b1s; b0e = b1e; q00p = q10p; q01p = q11p; e00 = e10; e01 = e11;
    n1 = n2; b1s = b2s; b1e = b2e; q10p = q20p; q11p = q21p;
  }
}

__global__ __launch_bounds__(256) void gather_all(
    const unsigned* __restrict__ row_start, const unsigned* __restrict__ row_end,
    const unsigned* __restrict__ eidx,
    const _Float16* __restrict__ kqvQ, const _Float16* __restrict__ kqvE,
    const _Float16* __restrict__ kqvA,
    const float* __restrict__ p_rel, _Float16* __restrict__ agg)
{
  int bid = blockIdx.x;
  if (bid < GB_Q) {
    gather_body<1>(bid, GB_Q, NQ, BASE_Q, row_start, row_end, eidx,
                   kqvE, 128, kqvE, 128, kqvQ + 64, 192, kqvQ + 64, 192,
                   p_rel + 0, p_rel + 0, agg);
  } else if (bid < GB_Q + GB_E) {
    gather_body<1>(bid - GB_Q, GB_E, NE, BASE_E, row_start, row_end, eidx,
                   kqvE, 192, kqvE, 192, kqvE + 64, 320, kqvE + 64, 320,
                   p_rel + 2, p_rel + 2, agg);
  } else {
    gather_body<2>(bid - GB_Q - GB_E, GB_A, NA, BASE_A, row_start, row_end, eidx,
                   kqvE, 256, kqvQ, 128, kqvA, 128, kqvA + 64, 128,
                   p_rel + 4, p_rel + 6, agg);
  }
}

// ---------------- K9: merged out-proj ----------------

__global__ __launch_bounds__(256) void gemm_out_all(
    const _Float16* __restrict__ agg_h, const _Float16* __restrict__ y_h,
    const _Float16* __restrict__ WoutT, const float* __restrict__ b_out,
    const float* __restrict__ scale, const float* __restrict__ shift,
    const float* __restrict__ skip, float* __restrict__ zout)
{
  __shared__ _Float16 Bs[64 * 72];
  int bid = blockIdx.x;
  int t, row0, M;
  size_t nodeoff;
  if (bid < TOP_Q)              { t = 0; row0 = bid * 128;              M = NQ; nodeoff = 0; }
  else if (bid < TOP_Q + TOP_A) { t = 1; row0 = (bid - TOP_Q) * 128;    M = NA; nodeoff = NQ; }
  else                          { t = 2; row0 = (bid - TOP_Q - TOP_A) * 128; M = NE; nodeoff = NQ + NA; }
  const _Float16* Ah = agg_h + nodeoff * 64;
  const _Float16* resh = y_h + nodeoff * 64;
  float* Cf = zout + nodeoff * 64;
  const _Float16* WT = WoutT + (size_t)t * 64 * 72;
  const float* bias = b_out + t * 64;
  const float* rsc = scale + t * 64;
  const float* rsh = shift + t * 64;

  int tid = threadIdx.x;
  int w = tid >> 6, l = tid & 63;
  int lr = l & 15, lg = l >> 4;

  for (int idx = tid; idx < 64 * 72 / 8; idx += 256)
    *(half8_t*)&Bs[idx * 8] = *(const half8_t*)&WT[(size_t)idx * 8];

  half8_t afrag[2][2];
#pragma unroll
  for (int rt = 0; rt < 2; ++rt) {
    int gr = row0 + w * 32 + rt * 16 + lr;
    bool ok = gr < M;
#pragma unroll
    for (int ks = 0; ks < 2; ++ks) {
      half8_t h8 = {};
      if (ok) h8 = *(const half8_t*)&Ah[(size_t)gr * 64 + ks * 32 + lg * 8];
      afrag[rt][ks] = h8;
    }
  }
  __syncthreads();

  f32x4_t acc[2][4] = {};
#pragma unroll
  for (int ks = 0; ks < 2; ++ks) {
#pragma unroll
    for (int ct = 0; ct < 4; ++ct) {
      half8_t b = *(const half8_t*)&Bs[(ct * 16 + lr) * 72 + ks * 32 + lg * 8];
      acc[0][ct] = __builtin_amdgcn_mfma_f32_16x16x32_f16(afrag[0][ks], b, acc[0][ct], 0, 0, 0);
      acc[1][ct] = __builtin_amdgcn_mfma_f32_16x16x32_f16(afrag[1][ks], b, acc[1][ct], 0, 0, 0);
    }
  }

  float g = 1.f / (1.f + __expf(-skip[t]));
  float gb = 1.f - g;
#pragma unroll
  for (int rt = 0; rt < 2; ++rt) {
    int rbase = row0 + w * 32 + rt * 16 + lg * 4;
#pragma unroll
    for (int ct = 0; ct < 4; ++ct) {
      int col = ct * 16 + lr;
      float bval = bias[col];
#pragma unroll
      for (int j = 0; j < 4; ++j) {
        int row = rbase + j;
        if (row >= M) continue;
        float val = acc[rt][ct][j] + bval;
        float rv = (float)resh[(size_t)row * 64 + col];
        Cf[(size_t)row * 64 + col] = g * val + gb * (rsc[col] * rv + rsh[col]);
      }
    }
  }
}

// ---------------- K10: merged predictions ----------------

__global__ void pred_all(const int* __restrict__ pos, const int* __restrict__ neg,
                         const float* __restrict__ zq, const float* __restrict__ za,
                         float* __restrict__ outp) {
  int i = blockIdx.x * blockDim.x + threadIdx.x;
  if (i >= N_POS + N_NEG) return;
  int k; const int* qi; const int* ai; float* o;
  if (i < N_POS) { k = i; qi = pos; ai = pos + N_POS; o = outp; }
  else { k = i - N_POS; qi = neg; ai = neg + N_NEG; o = outp + N_POS; }
  const float4* a = (const float4*)(zq + (size_t)qi[k] * 64);
  const float4* b = (const float4*)(za + (size_t)ai[k] * 64);
  float ssum = 0.f;
#pragma unroll
  for (int j = 0; j < 16; ++j) {
    float4 x = a[j], y = b[j];
    ssum += x.x * y.x + x.y * y.y + x.z * y.z + x.w * y.w;
  }
  o[k] = ssum;
}

// ---------------- host launch ----------------

extern "C" void kernel_launch(void* const* d_in, const int* in_sizes, int n_in,
                              void* d_out, int out_size, void* d_ws, size_t ws_size,
                              hipStream_t stream) {
  const float* xq = (const float*)d_in[0];
  const float* xa = (const float*)d_in[1];
  const float* xe = (const float*)d_in[2];
  const int* e_e2q = (const int*)d_in[3];
  const int* e_e2e = (const int*)d_in[4];
  const int* e_e2a = (const int*)d_in[5];
  const int* e_q2a = (const int*)d_in[6];
  const int* pos_idx = (const int*)d_in[7];
  const int* neg_idx = (const int*)d_in[8];
  const float* W_in = (const float*)d_in[9];
  const float* b_in = (const float*)d_in[10];
  const float* bn_gamma = (const float*)d_in[11];
  const float* bn_beta = (const float*)d_in[12];
  const float* W_kqv = (const float*)d_in[13];
  const float* b_kqv = (const float*)d_in[14];
  const float* A_k = (const float*)d_in[15];
  const float* A_v = (const float*)d_in[16];
  const float* p_rel = (const float*)d_in[17];
  const float* W_out = (const float*)d_in[18];
  const float* b_out = (const float*)d_in[19];
  const float* skip = (const float*)d_in[20];
  float* out = (float*)d_out;

  float* ws = (float*)d_ws;
  size_t off = 0;
  _Float16* y_h = (_Float16*)(ws + off);    off += (size_t)NT_TOTAL * 32;
  _Float16* kqvQ = (_Float16*)(ws + off);   off += (size_t)NQ * 96;
  _Float16* kqvE = (_Float16*)(ws + off);   off += (size_t)NE * 160;
  _Float16* kqvA = (_Float16*)(ws + off);   off += (size_t)NA * 64;
  _Float16* agg_h = (_Float16*)(ws + off);  off += (size_t)NT_TOTAL * 32;
  float* stats = ws + off;                  off += 384;
  float* scale = ws + off;                  off += 192;
  float* shift = ws + off;                  off += 192;
  float* bias2 = ws + off;                  off += 576;
  float* bias_big = ws + off;               off += 640;
  _Float16* WqT = (_Float16*)(ws + off);    off += 192 * 72 / 2;
  _Float16* WeT = (_Float16*)(ws + off);    off += 320 * 72 / 2;
  _Float16* WaT = (_Float16*)(ws + off);    off += 128 * 72 / 2;
  _Float16* WinT = (_Float16*)(ws + off);   off += 3 * 64 * 136 / 2;
  _Float16* WoutT = (_Float16*)(ws + off);  off += 3 * 64 * 72 / 2;
  float* bstats = ws + off;                 off += (size_t)GIN_TOT * 128;
  unsigned* row_start = (unsigned*)(ws + off); off += NT_TOTAL;
  unsigned* cursor = (unsigned*)(ws + off);    off += NT_TOTAL;
  unsigned* bsums = (unsigned*)(ws + off);     off += 1024;
  unsigned* eidx = (unsigned*)(ws + off);      off += E_TOTAL + 8;

  float* zq_out = out + (N_POS + N_NEG);

  prep_misc<<<dim3(512), dim3(256), 0, stream>>>((float*)row_start, W_in, WinT, W_out, WoutT);

  inproj_hist_all<<<dim3(GIN_TOT + HB), dim3(256), 0, stream>>>(
      xq, xa, xe, WinT, b_in, y_h, bstats,
      e_e2q + E_E2Q, e_e2e + E_E2E, e_e2a + E_E2A, e_q2a + E_Q2A, row_start);

  reduce_scan1<<<dim3(384 + NBLK_SCAN), dim3(256), 0, stream>>>(
      bstats, stats, row_start, bsums);

  scan2_bn<<<dim3(2), dim3(256), 0, stream>>>(
      bsums, NBLK_SCAN, stats, bn_gamma, bn_beta, scale, shift, b_kqv, W_kqv, bias2);

  scan3_wprep<<<dim3(NBLK_SCAN + 160), dim3(256), 0, stream>>>(
      row_start, bsums, cursor, W_kqv, bias2, A_k, A_v, scale,
      WqT, WeT, WaT, bias_big);

  scatter_all<<<dim3(2048), dim3(256), 0, stream>>>(
      e_e2q, e_e2q + E_E2Q, e_e2e, e_e2e + E_E2E,
      e_e2a, e_e2a + E_E2A, e_q2a, e_q2a + E_Q2A, cursor, eidx);

  kqv_all<<<dim3(KQ_TOT), dim3(512), SMEM_KQV, stream>>>(
      y_h, WqT, WeT, WaT, bias_big, kqvQ, kqvE, kqvA);

  gather_all<<<dim3(GB_Q + GB_E + GB_A), dim3(256), 0, stream>>>(
      row_start, cursor, eidx, kqvQ, kqvE, kqvA, p_rel, agg_h);

  gemm_out_all<<<dim3(TOP_Q + TOP_A + TOP_E), dim3(256), 0, stream>>>(
      agg_h, y_h, WoutT, b_out, scale, shift, skip, zq_out);

  pred_all<<<dim3(CDIV(N_POS + N_NEG, 256)), dim3(256), 0, stream>>>(
      pos_idx, neg_idx, zq_out, zq_out + (size_t)NQ * 64, out);
}

// Round 21
// 661.973 us; speedup vs baseline: 1.0119x; 1.0119x over previous
//
#include <hip/hip_runtime.h>
#include <hip/hip_bf16.h>
#include <hip/hip_fp16.h>
#include <math.h>

#define NQ 8192
#define NA 32768
#define NE 500000
#define F_IN 128
#define E_E2Q 131072
#define E_E2E 800000
#define E_E2A 262144
#define E_Q2A 32768
#define N_POS 8192
#define N_NEG 24576

#define NT_TOTAL (NQ + NA + NE)
#define E_TOTAL (E_E2Q + E_E2E + E_E2A + E_Q2A)
#define NBLK_SCAN ((NT_TOTAL + 1023) / 1024)         // 529
#define CDIV(a, b) (((a) + (b) - 1) / (b))

#define BASE_Q 0
#define BASE_A NQ
#define BASE_E (NQ + NA)

// in-proj block counts (1 block per bstats row)
#define GIN_Q 128
#define GIN_A 512
#define GIN_E 768
#define GIN_TOT (GIN_Q + GIN_A + GIN_E)   // 1408
#define HB 1024                            // hist blocks appended

// gather grid
#define GB_Q 2048
#define GB_E 4096
#define GB_A 8192

// out-proj grid
#define TOP_Q 64
#define TOP_A 256
#define TOP_E 3907

// kqv_scatter2 grid: scatter first, then kqv (BM=128)
#define SCB 2048
#define KQ2_Q 64        // CDIV(NQ,128)
#define KQ2_E 3907      // CDIV(NE,128), x2 col tiles
#define KQ2_A 256       // CDIV(NA,128)
#define KS2_TOT (SCB + KQ2_Q + 2 * KQ2_E + KQ2_A)   // 12182
#define SMEM_KQV2 51200

typedef _Float16 half8_t __attribute__((ext_vector_type(8)));
typedef _Float16 half2_t __attribute__((ext_vector_type(2)));
typedef float f32x4_t __attribute__((ext_vector_type(4)));

__device__ inline void load_lds16(const void* g, void* l) {
  __builtin_amdgcn_global_load_lds((const __attribute__((address_space(1))) void*)g,
                                   (__attribute__((address_space(3))) void*)l, 16, 0, 0);
}

__device__ inline float fast_gelu(float v) {
  float u = 1.5957691216057308f * fmaf(0.044715f * v * v, v, v);
  return v / (1.f + __expf(-u));
}

// ---------------- K1: prep (zero row_start + WinT + WoutT) ----------------

__global__ __launch_bounds__(256) void prep_misc(
    float* __restrict__ row_start_f,
    const float* __restrict__ W_in, _Float16* __restrict__ WinT,
    const float* __restrict__ W_out, _Float16* __restrict__ WoutT)
{
  int bid = blockIdx.x;
  if (bid < 128) {
    size_t i = (size_t)bid * 256 + threadIdx.x;
    size_t stride = (size_t)128 * 256;
    for (; i < NT_TOTAL; i += stride) row_start_f[i] = 0.f;
  } else if (bid < 320) {
    int b = bid - 128;
    int t = b >> 6, n = b & 63, k = threadIdx.x;
    if (k < 136) {
      float v = (k < 128) ? W_in[(size_t)t * 128 * 64 + (size_t)k * 64 + n] : 0.f;
      WinT[((size_t)t * 64 + n) * 136 + k] = (_Float16)v;
    }
  } else {
    int b = bid - 320;
    int t = b >> 6, n = b & 63, k = threadIdx.x;
    if (k < 72) {
      float v = (k < 64) ? W_out[(size_t)t * 64 * 64 + (size_t)k * 64 + n] : 0.f;
      WoutT[((size_t)t * 64 + n) * 72 + k] = (_Float16)v;
    }
  }
}

// ---------------- K2: in-proj (pipelined LDS stage) + hist, block-range merged ----------------

__global__ __launch_bounds__(256) void inproj_hist_all(
    const float* __restrict__ xq, const float* __restrict__ xa,
    const float* __restrict__ xe,
    const _Float16* __restrict__ WinT, const float* __restrict__ b_in,
    _Float16* __restrict__ y_h, float* __restrict__ bstats,
    const int* __restrict__ hd0, const int* __restrict__ hd1,
    const int* __restrict__ hd2, const int* __restrict__ hd3,
    unsigned* __restrict__ cnt)
{
  __shared__ __align__(16) float bufA[32 * 128];
  __shared__ __align__(16) float bufB[32 * 128];
  __shared__ _Float16 Bs[64 * 136];
  __shared__ float s1[64], s2[64];

  int bid = blockIdx.x;
  if (bid >= GIN_TOT) {
    int i = (bid - GIN_TOT) * 256 + threadIdx.x;
    int stride = HB * 256;
    for (; i < E_TOTAL; i += stride) {
      if (i < E_E2Q) atomicAdd(&cnt[BASE_Q + hd0[i]], 1u);
      else if (i < E_E2Q + E_E2E) atomicAdd(&cnt[BASE_E + hd1[i - E_E2Q]], 1u);
      else if (i < E_E2Q + E_E2E + E_E2A)
        atomicAdd(&cnt[BASE_A + hd2[i - E_E2Q - E_E2E]], 1u);
      else atomicAdd(&cnt[BASE_A + hd3[i - E_E2Q - E_E2E - E_E2A]], 1u);
    }
    return;
  }

  int t, lb, nb;
  const float* Af;
  _Float16* oh;
  if (bid < GIN_Q)              { t = 0; lb = bid;                 nb = GIN_Q; Af = xq; oh = y_h; }
  else if (bid < GIN_Q + GIN_A) { t = 1; lb = bid - GIN_Q;         nb = GIN_A; Af = xa; oh = y_h + (size_t)NQ * 64; }
  else                          { t = 2; lb = bid - GIN_Q - GIN_A; nb = GIN_E; Af = xe; oh = y_h + (size_t)(NQ + NA) * 64; }
  int M = (t == 0) ? NQ : (t == 1) ? NA : NE;
  int nh = CDIV(M, 32);
  const _Float16* WT = WinT + (size_t)t * 64 * 136;
  const float* bias = b_in + t * 64;

  int tid = threadIdx.x, w = tid >> 6, l = tid & 63;
  int lr = l & 15, lg = l >> 4;
  int wrow = (w & 1) * 16;
  int wcol = (w >> 1) * 32;

  for (int idx = tid; idx < 64 * 136 / 8; idx += 256)
    *(half8_t*)&Bs[idx * 8] = *(const half8_t*)&WT[(size_t)idx * 8];
  if (tid < 64) { s1[tid] = 0.f; s2[tid] = 0.f; }

  float bval[2];
  bval[0] = bias[wcol + lr];
  bval[1] = bias[wcol + 16 + lr];
  float ps1[2] = {}, ps2[2] = {};

  auto stage = [&](float* buf, int h) {
    const char* srcbase = (const char*)Af + (size_t)h * 32 * 512;
    int rowlim = M - h * 32;
#pragma unroll
    for (int r = 0; r < 4; ++r) {
      int unit = r * 4 + w;
      char* ldst = (char*)buf + unit * 1024;
      int p = unit * 1024 + l * 16;
      int row = p >> 9;
      const char* src = (row < rowlim) ? srcbase + (size_t)row * 512 + (p & 511)
                                       : srcbase;
      load_lds16(src, ldst);
    }
  };

  int h0 = lb;
  if (h0 < nh) stage(bufA, h0);
  __syncthreads();

  float* cur = bufA;
  float* nxt = bufB;
  for (int h = h0; h < nh; h += nb) {
    int h2 = h + nb;
    bool more = h2 < nh;
    if (more) {
      stage(nxt, h2);
      asm volatile("s_waitcnt vmcnt(4)" ::: "memory");
    } else {
      asm volatile("s_waitcnt vmcnt(0)" ::: "memory");
    }
    __builtin_amdgcn_sched_barrier(0);
    __builtin_amdgcn_s_barrier();

    f32x4_t acc[2] = {};
#pragma unroll
    for (int ks = 0; ks < 4; ++ks) {
      const float4* pa = (const float4*)((const char*)cur +
                          (wrow + lr) * 512 + ks * 128 + lg * 32);
      float4 x0 = pa[0], x1 = pa[1];
      half8_t a0 = {(_Float16)x0.x, (_Float16)x0.y, (_Float16)x0.z, (_Float16)x0.w,
                    (_Float16)x1.x, (_Float16)x1.y, (_Float16)x1.z, (_Float16)x1.w};
#pragma unroll
      for (int ct = 0; ct < 2; ++ct) {
        half8_t b = *(const half8_t*)&Bs[(wcol + ct * 16 + lr) * 136 + ks * 32 + lg * 8];
        acc[ct] = __builtin_amdgcn_mfma_f32_16x16x32_f16(a0, b, acc[ct], 0, 0, 0);
      }
    }
    int rbase = h * 32 + wrow + lg * 4;
#pragma unroll
    for (int ct = 0; ct < 2; ++ct) {
      int col = wcol + ct * 16 + lr;
#pragma unroll
      for (int j = 0; j < 4; ++j) {
        int row = rbase + j;
        if (row >= M) continue;
        float val = fmaxf(acc[ct][j] + bval[ct], 0.f);
        oh[(size_t)row * 64 + col] = (_Float16)val;
        ps1[ct] += val;
        ps2[ct] += val * val;
      }
    }
    __builtin_amdgcn_s_barrier();
    float* tmp = cur; cur = nxt; nxt = tmp;
  }

#pragma unroll
  for (int ct = 0; ct < 2; ++ct) {
    int col = wcol + ct * 16 + lr;
    atomicAdd(&s1[col], ps1[ct]);
    atomicAdd(&s2[col], ps2[ct]);
  }
  __syncthreads();
  if (tid < 64) {
    bstats[(size_t)blockIdx.x * 128 + tid] = s1[tid];
    bstats[(size_t)blockIdx.x * 128 + 64 + tid] = s2[tid];
  }
}

// ---------------- K3: stats_reduce + scan1 merged ----------------

__global__ __launch_bounds__(256) void reduce_scan1(
    const float* __restrict__ bstats, float* __restrict__ stats,
    unsigned* __restrict__ arr, unsigned* __restrict__ bsums)
{
  __shared__ __align__(16) char shbuf[1024];
  int bid = blockIdx.x;
  int t0 = threadIdx.x;
  if (bid < 384) {
    float* sh = (float*)shbuf;
    int t = bid >> 7, c = bid & 127;
    int nb = (t == 0) ? GIN_Q : (t == 1) ? GIN_A : GIN_E;
    int base = (t == 0) ? 0 : (t == 1) ? GIN_Q : (GIN_Q + GIN_A);
    float s = 0.f;
    for (int i = t0; i < nb; i += 256)
      s += bstats[(size_t)(base + i) * 128 + c];
    sh[t0] = s;
    __syncthreads();
    for (int off2 = 128; off2 > 0; off2 >>= 1) {
      if (t0 < off2) sh[t0] += sh[t0 + off2];
      __syncthreads();
    }
    if (t0 == 0) stats[t * 128 + c] = sh[0];
  } else {
    unsigned* sh = (unsigned*)shbuf;
    int blk = bid - 384;
    int base = blk * 1024 + t0 * 4;
    unsigned v[4];
    unsigned s = 0;
#pragma unroll
    for (int j = 0; j < 4; ++j) {
      v[j] = (base + j < NT_TOTAL) ? arr[base + j] : 0u;
      s += v[j];
    }
    sh[t0] = s;
    __syncthreads();
    for (int off = 1; off < 256; off <<= 1) {
      unsigned x = (t0 >= off) ? sh[t0 - off] : 0u;
      __syncthreads();
      sh[t0] += x;
      __syncthreads();
    }
    unsigned run = sh[t0] - s;
#pragma unroll
    for (int j = 0; j < 4; ++j) {
      if (base + j < NT_TOTAL) arr[base + j] = run;
      run += v[j];
    }
    if (t0 == 255) bsums[blk] = sh[255];
  }
}

// ---------------- K4: scan2 (block 0) + bn_finalize+kqv_bias2 (block 1) ----------------

__global__ __launch_bounds__(256) void scan2_bn(
    unsigned* __restrict__ bsums, int nbk,
    const float* __restrict__ stats,
    const float* __restrict__ gamma, const float* __restrict__ beta,
    float* __restrict__ scale, float* __restrict__ shift,
    const float* __restrict__ b_kqv, const float* __restrict__ W_kqv,
    float* __restrict__ bias2)
{
  int t0 = threadIdx.x;
  if (blockIdx.x == 0) {
    __shared__ unsigned sh[256];
    __shared__ unsigned carry;
    if (t0 == 0) carry = 0;
    __syncthreads();
    for (int chunk = 0; chunk < nbk; chunk += 256) {
      int i = chunk + t0;
      unsigned v = (i < nbk) ? bsums[i] : 0u;
      sh[t0] = v;
      __syncthreads();
      for (int off = 1; off < 256; off <<= 1) {
        unsigned x = (t0 >= off) ? sh[t0 - off] : 0u;
        __syncthreads();
        sh[t0] += x;
        __syncthreads();
      }
      unsigned inc = sh[t0];
      unsigned c = carry;
      __syncthreads();
      if (i < nbk) bsums[i] = c + inc - v;
      if (t0 == 255) carry = c + sh[255];
      __syncthreads();
    }
  } else {
    __shared__ float sshift[192];
    if (t0 < 192) {
      int ty = t0 >> 6, c = t0 & 63;
      float invN = (ty == 0) ? (1.f / NQ) : (ty == 1) ? (1.f / NA) : (1.f / NE);
      float mu = stats[ty * 128 + c] * invN;
      float var = stats[ty * 128 + 64 + c] * invN - mu * mu;
      float rs = rsqrtf(var + 1e-5f);
      float gm = gamma[t0];
      float sc = gm * rs;
      float sf = beta[t0] - gm * mu * rs;
      scale[t0] = sc;
      shift[t0] = sf;
      sshift[t0] = sf;
    }
    __syncthreads();
    for (int idx = t0; idx < 576; idx += 256) {
      int t = idx / 192, n = idx % 192;
      float s = b_kqv[t * 192 + n];
      for (int k = 0; k < 64; ++k)
        s += sshift[t * 64 + k] * W_kqv[(size_t)t * 64 * 192 + k * 192 + n];
      bias2[t * 192 + n] = s;
    }
  }
}

// ---------------- K5: scan3 + wprep_kqv merged ----------------

__global__ __launch_bounds__(256) void scan3_wprep(
    unsigned* __restrict__ arr, const unsigned* __restrict__ bsums,
    unsigned* __restrict__ cursor,
    const float* __restrict__ W_kqv, const float* __restrict__ bias2,
    const float* __restrict__ A_k, const float* __restrict__ A_v,
    const float* __restrict__ scale,
    _Float16* __restrict__ WqT, _Float16* __restrict__ WeT,
    _Float16* __restrict__ WaT, float* __restrict__ bias_big)
{
  int bid = blockIdx.x;
  int t0 = threadIdx.x;
  if (bid < NBLK_SCAN) {
    int base = bid * 1024 + t0 * 4;
    unsigned add = bsums[bid];
#pragma unroll
    for (int j = 0; j < 4; ++j) {
      int idx = base + j;
      if (idx < NT_TOTAL) {
        unsigned r = arr[idx] + add;
        arr[idx] = r;
        cursor[idx] = r;
      }
    }
    return;
  }
  int j = (bid - NBLK_SCAN) * 4 + (t0 >> 6);
  int c = t0 & 63;
  if (j >= 640) return;
  int t, jj, bofs;
  _Float16* W;
  if (j < 192)      { t = 0; jj = j;       W = WqT; bofs = 0; }
  else if (j < 512) { t = 2; jj = j - 192; W = WeT; bofs = 192; }
  else              { t = 1; jj = j - 512; W = WaT; bofs = 512; }
  const float* Wt = W_kqv + (size_t)t * 64 * 192;
  const float* b2 = bias2 + t * 192;
  int mode = 0, rel = 0, sub = 0;
  if (t == 1) { mode = 1; rel = (jj < 64) ? 2 : 3; sub = jj & 63; }
  else if (jj >= 64 && jj < 128) { mode = 1; rel = (t == 0) ? 0 : 1; sub = jj - 64; }
  else if (jj >= 128) {
    mode = 2; sub = (jj - 128) & 63;
    rel = (t == 0) ? 3 : ((jj - 128) >> 6);
  }
  int h = sub >> 5, x = sub & 31;
  float wv, bv;
  if (mode == 0) {
    wv = Wt[(size_t)c * 192 + jj];
    bv = b2[jj];
  } else if (mode == 1) {
    const float* Ar = A_k + ((size_t)rel * 2048 + h * 1024 + x * 32);
    float s = 0.f, sb = 0.f;
    for (int f = 0; f < 32; ++f) {
      float a = Ar[f];
      s = fmaf(a, Wt[(size_t)c * 192 + 64 + h * 32 + f], s);
      sb = fmaf(a, b2[64 + h * 32 + f], sb);
    }
    wv = s; bv = sb;
  } else {
    const float* Ar = A_v + ((size_t)rel * 2048 + h * 1024 + x);
    float s = 0.f, sb = 0.f;
    for (int d = 0; d < 32; ++d) {
      float a = Ar[d * 32];
      s = fmaf(a, Wt[(size_t)c * 192 + 128 + h * 32 + d], s);
      sb = fmaf(a, b2[128 + h * 32 + d], sb);
    }
    wv = s; bv = sb;
  }
  wv *= scale[t * 64 + c];
  W[(size_t)jj * 72 + c] = (_Float16)wv;
  if (c < 8) W[(size_t)jj * 72 + 64 + c] = (_Float16)0.f;
  if (c == 0) bias_big[bofs + jj] = bv;
}

// ---------------- kqv GEMM body (BM=128, 256 threads, single-pass transpose) ----------------

template <int BNT>
__device__ __forceinline__ void kqv_body128(
    char* smem,
    const _Float16* __restrict__ Ah,
    const _Float16* __restrict__ WT, const float* __restrict__ bias, int M,
    _Float16* __restrict__ oh, int LDO, int row0, int colbase)
{
  constexpr int KP = 72;
  constexpr int TP = BNT + 8;
  _Float16* As = (_Float16*)smem;          // 128*72
  _Float16* Bs = As + 128 * KP;            // BNT*72
  _Float16* Ts = (_Float16*)smem;          // overlays after compute: 128*TP
  int tid = threadIdx.x;

  for (int idx = tid; idx < 128 * 8; idx += 256) {
    int row = idx >> 3, c = idx & 7;
    int gr = row0 + row;
    half8_t a8 = {};
    if (gr < M) a8 = *(const half8_t*)&Ah[(size_t)gr * 64 + c * 8];
    *(half8_t*)&As[row * KP + c * 8] = a8;
  }
  {
    const _Float16* wsrc = WT + (size_t)colbase * KP;
    for (int idx = tid; idx < BNT * KP / 8; idx += 256)
      *(half8_t*)&Bs[idx * 8] = *(const half8_t*)&wsrc[(size_t)idx * 8];
  }
  __syncthreads();

  int w = tid >> 6, l = tid & 63;
  int lr = l & 15, lg = l >> 4;
  constexpr int NCT = BNT / 16;
  f32x4_t acc[2][NCT] = {};
#pragma unroll
  for (int ks = 0; ks < 2; ++ks) {
    half8_t a0 = *(const half8_t*)&As[(w * 32 + lr) * KP + ks * 32 + lg * 8];
    half8_t a1 = *(const half8_t*)&As[(w * 32 + 16 + lr) * KP + ks * 32 + lg * 8];
#pragma unroll
    for (int ct = 0; ct < NCT; ++ct) {
      half8_t b = *(const half8_t*)&Bs[(ct * 16 + lr) * KP + ks * 32 + lg * 8];
      acc[0][ct] = __builtin_amdgcn_mfma_f32_16x16x32_f16(a0, b, acc[0][ct], 0, 0, 0);
      acc[1][ct] = __builtin_amdgcn_mfma_f32_16x16x32_f16(a1, b, acc[1][ct], 0, 0, 0);
    }
  }

  float bval[NCT];
#pragma unroll
  for (int ct = 0; ct < NCT; ++ct) bval[ct] = bias[colbase + ct * 16 + lr];

  __syncthreads();   // As/Bs dead
#pragma unroll
  for (int rt = 0; rt < 2; ++rt) {
    int r2base = w * 32 + rt * 16 + lg * 4;
#pragma unroll
    for (int ct = 0; ct < NCT; ++ct) {
      int colL = ct * 16 + lr;
#pragma unroll
      for (int j = 0; j < 4; ++j)
        Ts[(r2base + j) * TP + colL] = (_Float16)(acc[rt][ct][j] + bval[ct]);
    }
  }
  __syncthreads();
  constexpr int C8 = BNT / 8;
  for (int idx = tid; idx < 128 * C8; idx += 256) {
    int r2 = idx / C8, c8 = (idx % C8) * 8;
    int gr = row0 + r2;
    if (gr < M)
      *(half8_t*)&oh[(size_t)gr * LDO + colbase + c8] = *(const half8_t*)&Ts[r2 * TP + c8];
  }
}

// ---------------- K6: scatter-first + kqv GEMMs merged (256 threads, 3 blocks/CU) ----------------

__global__ __launch_bounds__(256) void kqv_scatter2(
    const _Float16* __restrict__ y_h,
    const _Float16* __restrict__ WqT, const _Float16* __restrict__ WeT,
    const _Float16* __restrict__ WaT, const float* __restrict__ bias_big,
    _Float16* __restrict__ kqvQ, _Float16* __restrict__ kqvE,
    _Float16* __restrict__ kqvA,
    const int* __restrict__ s0, const int* __restrict__ d0,
    const int* __restrict__ s1, const int* __restrict__ d1,
    const int* __restrict__ s2, const int* __restrict__ d2,
    const int* __restrict__ s3, const int* __restrict__ d3,
    unsigned* __restrict__ cursor, unsigned* __restrict__ eidx)
{
  extern __shared__ __align__(16) char smem[];
  int bid = blockIdx.x;
  if (bid < SCB) {
    // ---- scatter range (scheduled first; overlaps GEMM blocks) ----
    int i = bid * 256 + threadIdx.x;
    int stride = SCB * 256;
    for (; i < E_TOTAL; i += stride) {
      unsigned pos, pay;
      if (i < E_E2Q) {
        pos = atomicAdd(&cursor[BASE_Q + d0[i]], 1u);
        pay = (unsigned)(s0[i] * 320);
      } else if (i < E_E2Q + E_E2E) {
        int k = i - E_E2Q;
        pos = atomicAdd(&cursor[BASE_E + d1[k]], 1u);
        pay = (unsigned)(s1[k] * 320);
      } else if (i < E_E2Q + E_E2E + E_E2A) {
        int k = i - E_E2Q - E_E2E;
        pos = atomicAdd(&cursor[BASE_A + d2[k]], 1u);
        pay = (unsigned)(s2[k] * 320);
      } else {
        int k = i - E_E2Q - E_E2E - E_E2A;
        pos = atomicAdd(&cursor[BASE_A + d3[k]], 1u);
        pay = (unsigned)(s3[k] * 192) | 0x80000000u;
      }
      eidx[pos] = pay;
    }
  } else if (bid < SCB + 2 * KQ2_E) {
    int b = bid - SCB;
    int ct = b / KQ2_E;
    int rb = b % KQ2_E;
    kqv_body128<160>(smem, y_h + (size_t)(NQ + NA) * 64, WeT, bias_big + 192, NE,
                     kqvE, 320, rb * 128, ct * 160);
  } else if (bid < SCB + 2 * KQ2_E + KQ2_Q) {
    int b = bid - SCB - 2 * KQ2_E;
    kqv_body128<192>(smem, y_h, WqT, bias_big, NQ, kqvQ, 192, b * 128, 0);
  } else {
    int b = bid - SCB - 2 * KQ2_E - KQ2_Q;
    kqv_body128<128>(smem, y_h + (size_t)NQ * 64, WaT, bias_big + 512, NA,
                     kqvA, 128, b * 128, 0);
  }
}

// ---------------- gather body ----------------

template <int NREL>
__device__ __forceinline__ void gather_body(
    int bidLocal, int nblocks, int N, int nodebase,
    const unsigned* __restrict__ row_start, const unsigned* __restrict__ row_end,
    const unsigned* __restrict__ eidx,
    const _Float16* __restrict__ baseA, int vofA,
    const _Float16* __restrict__ baseB, int vofB,
    const _Float16* __restrict__ qtA, int ldqA,
    const _Float16* __restrict__ qtB, int ldqB,
    const float* __restrict__ prelA, const float* __restrict__ prelB,
    _Float16* __restrict__ agg)
{
  int lane = threadIdx.x & 63;
  int h = lane >> 5, f = lane & 31;
  int idx2 = h * 32 + 2 * (f & 15);
  const float isd = 0.17677669529663687f;
  float pr0 = prelA[h] * isd;
  float pr1 = (NREL == 2) ? prelB[h] * isd : 0.f;

  int wid = (int)(((size_t)bidLocal * 256 + threadIdx.x) >> 6);
  int nw = nblocks * 4;

  int n0 = wid;
  unsigned b0s = 0, b0e = 0, e00 = 0, e01 = 0;
  half2_t q00p = {}, q01p = {};
  if (n0 < N) {
    b0s = row_start[nodebase + n0];
    b0e = row_end[nodebase + n0];
    q00p = *(const half2_t*)&qtA[(size_t)n0 * ldqA + idx2];
    if (NREL == 2) q01p = *(const half2_t*)&qtB[(size_t)n0 * ldqB + idx2];
    e00 = eidx[b0s];
    e01 = eidx[b0s + 1];
  }
  int n1 = n0 + nw;
  unsigned b1s = 0, b1e = 0;
  half2_t q10p = {}, q11p = {};
  if (n0 < N && n1 < N) {
    b1s = row_start[nodebase + n1];
    b1e = row_end[nodebase + n1];
    q10p = *(const half2_t*)&qtA[(size_t)n1 * ldqA + idx2];
    if (NREL == 2) q11p = *(const half2_t*)&qtB[(size_t)n1 * ldqB + idx2];
  }

  while (n0 < N) {
    unsigned e10 = 0, e11 = 0;
    if (n1 < N) {
      e10 = eidx[b1s];
      e11 = eidx[b1s + 1];
    }
    int n2 = n1 + nw;
    unsigned b2s = 0, b2e = 0;
    half2_t q20p = {}, q21p = {};
    if (n2 < N) {
      b2s = row_start[nodebase + n2];
      b2e = row_end[nodebase + n2];
      q20p = *(const half2_t*)&qtA[(size_t)n2 * ldqA + idx2];
      if (NREL == 2) q21p = *(const half2_t*)&qtB[(size_t)n2 * ldqB + idx2];
    }

    float vs = 0.f, ss = 0.f;
    unsigned i = b0s;

    auto do_pair = [&](unsigned p1, unsigned p2) {
      unsigned o1 = p1 & 0x7FFFFFFFu, o2 = p2 & 0x7FFFFFFFu;
      bool r1 = (NREL == 2) && (p1 >> 31);
      bool r2 = (NREL == 2) && (p2 >> 31);
      const _Float16* b1 = (r1 ? baseB : baseA) + o1;
      const _Float16* b2 = (r2 ? baseB : baseA) + o2;
      half2_t k21 = *(const half2_t*)&b1[idx2];
      float v1 = (float)b1[(r1 ? vofB : vofA) + lane];
      half2_t k22 = *(const half2_t*)&b2[idx2];
      float v2 = (float)b2[(r2 ? vofB : vofA) + lane];
      float sa = __builtin_amdgcn_fdot2(k21, r1 ? q01p : q00p, 0.f, false);
      float sb = __builtin_amdgcn_fdot2(k22, r2 ? q01p : q00p, 0.f, false);
#pragma unroll
      for (int off = 1; off <= 8; off <<= 1) {
        sa += __shfl_xor(sa, off, 32);
        sb += __shfl_xor(sb, off, 32);
      }
      float w1 = __expf(sa * (r1 ? pr1 : pr0));
      float w2 = __expf(sb * (r2 ? pr1 : pr0));
      ss += w1 + w2;
      vs = fmaf(w1, v1, vs);
      vs = fmaf(w2, v2, vs);
    };
    auto do_single = [&](unsigned p1) {
      unsigned o1 = p1 & 0x7FFFFFFFu;
      bool r1 = (NREL == 2) && (p1 >> 31);
      const _Float16* b1 = (r1 ? baseB : baseA) + o1;
      half2_t k21 = *(const half2_t*)&b1[idx2];
      float v1 = (float)b1[(r1 ? vofB : vofA) + lane];
      float sa = __builtin_amdgcn_fdot2(k21, r1 ? q01p : q00p, 0.f, false);
#pragma unroll
      for (int off = 1; off <= 8; off <<= 1) sa += __shfl_xor(sa, off, 32);
      float w1 = __expf(sa * (r1 ? pr1 : pr0));
      ss += w1;
      vs = fmaf(w1, v1, vs);
    };

    if (i + 2 <= b0e) { do_pair(e00, e01); i += 2; }
    else if (i < b0e) { do_single(e00); i = b0e; }
    for (; i + 2 <= b0e; i += 2) do_pair(eidx[i], eidx[i + 1]);
    if (i < b0e) do_single(eidx[i]);

    float val = (ss > 0.f) ? vs / ss : 0.f;
    val = fast_gelu(val);
    agg[((size_t)(nodebase + n0)) * 64 + lane] = (_Float16)val;

    n0 = n1; b0s = b1s; b0e = b1e; q00p = q10p; q01p = q11p; e00 = e10; e01 = e11;
    n1 = n2; b1s = b2s; b1e = b2e; q10p = q20p; q11p = q21p;
  }
}

__global__ __launch_bounds__(256) void gather_all(
    const unsigned* __restrict__ row_start, const unsigned* __restrict__ row_end,
    const unsigned* __restrict__ eidx,
    const _Float16* __restrict__ kqvQ, const _Float16* __restrict__ kqvE,
    const _Float16* __restrict__ kqvA,
    const float* __restrict__ p_rel, _Float16* __restrict__ agg)
{
  int bid = blockIdx.x;
  if (bid < GB_Q) {
    gather_body<1>(bid, GB_Q, NQ, BASE_Q, row_start, row_end, eidx,
                   kqvE, 128, kqvE, 128, kqvQ + 64, 192, kqvQ + 64, 192,
                   p_rel + 0, p_rel + 0, agg);
  } else if (bid < GB_Q + GB_E) {
    gather_body<1>(bid - GB_Q, GB_E, NE, BASE_E, row_start, row_end, eidx,
                   kqvE, 192, kqvE, 192, kqvE + 64, 320, kqvE + 64, 320,
                   p_rel + 2, p_rel + 2, agg);
  } else {
    gather_body<2>(bid - GB_Q - GB_E, GB_A, NA, BASE_A, row_start, row_end, eidx,
                   kqvE, 256, kqvQ, 128, kqvA, 128, kqvA + 64, 128,
                   p_rel + 4, p_rel + 6, agg);
  }
}

// ---------------- K8: merged out-proj ----------------

__global__ __launch_bounds__(256) void gemm_out_all(
    const _Float16* __restrict__ agg_h, const _Float16* __restrict__ y_h,
    const _Float16* __restrict__ WoutT, const float* __restrict__ b_out,
    const float* __restrict__ scale, const float* __restrict__ shift,
    const float* __restrict__ skip, float* __restrict__ zout)
{
  __shared__ _Float16 Bs[64 * 72];
  int bid = blockIdx.x;
  int t, row0, M;
  size_t nodeoff;
  if (bid < TOP_Q)              { t = 0; row0 = bid * 128;              M = NQ; nodeoff = 0; }
  else if (bid < TOP_Q + TOP_A) { t = 1; row0 = (bid - TOP_Q) * 128;    M = NA; nodeoff = NQ; }
  else                          { t = 2; row0 = (bid - TOP_Q - TOP_A) * 128; M = NE; nodeoff = NQ + NA; }
  const _Float16* Ah = agg_h + nodeoff * 64;
  const _Float16* resh = y_h + nodeoff * 64;
  float* Cf = zout + nodeoff * 64;
  const _Float16* WT = WoutT + (size_t)t * 64 * 72;
  const float* bias = b_out + t * 64;
  const float* rsc = scale + t * 64;
  const float* rsh = shift + t * 64;

  int tid = threadIdx.x;
  int w = tid >> 6, l = tid & 63;
  int lr = l & 15, lg = l >> 4;

  for (int idx = tid; idx < 64 * 72 / 8; idx += 256)
    *(half8_t*)&Bs[idx * 8] = *(const half8_t*)&WT[(size_t)idx * 8];

  half8_t afrag[2][2];
#pragma unroll
  for (int rt = 0; rt < 2; ++rt) {
    int gr = row0 + w * 32 + rt * 16 + lr;
    bool ok = gr < M;
#pragma unroll
    for (int ks = 0; ks < 2; ++ks) {
      half8_t h8 = {};
      if (ok) h8 = *(const half8_t*)&Ah[(size_t)gr * 64 + ks * 32 + lg * 8];
      afrag[rt][ks] = h8;
    }
  }
  __syncthreads();

  f32x4_t acc[2][4] = {};
#pragma unroll
  for (int ks = 0; ks < 2; ++ks) {
#pragma unroll
    for (int ct = 0; ct < 4; ++ct) {
      half8_t b = *(const half8_t*)&Bs[(ct * 16 + lr) * 72 + ks * 32 + lg * 8];
      acc[0][ct] = __builtin_amdgcn_mfma_f32_16x16x32_f16(afrag[0][ks], b, acc[0][ct], 0, 0, 0);
      acc[1][ct] = __builtin_amdgcn_mfma_f32_16x16x32_f16(afrag[1][ks], b, acc[1][ct], 0, 0, 0);
    }
  }

  float g = 1.f / (1.f + __expf(-skip[t]));
  float gb = 1.f - g;
#pragma unroll
  for (int rt = 0; rt < 2; ++rt) {
    int rbase = row0 + w * 32 + rt * 16 + lg * 4;
#pragma unroll
    for (int ct = 0; ct < 4; ++ct) {
      int col = ct * 16 + lr;
      float bval = bias[col];
#pragma unroll
      for (int j = 0; j < 4; ++j) {
        int row = rbase + j;
        if (row >= M) continue;
        float val = acc[rt][ct][j] + bval;
        float rv = (float)resh[(size_t)row * 64 + col];
        Cf[(size_t)row * 64 + col] = g * val + gb * (rsc[col] * rv + rsh[col]);
      }
    }
  }
}

// ---------------- K9: merged predictions ----------------

__global__ void pred_all(const int* __restrict__ pos, const int* __restrict__ neg,
                         const float* __restrict__ zq, const float* __restrict__ za,
                         float* __restrict__ outp) {
  int i = blockIdx.x * blockDim.x + threadIdx.x;
  if (i >= N_POS + N_NEG) return;
  int k; const int* qi; const int* ai; float* o;
  if (i < N_POS) { k = i; qi = pos; ai = pos + N_POS; o = outp; }
  else { k = i - N_POS; qi = neg; ai = neg + N_NEG; o = outp + N_POS; }
  const float4* a = (const float4*)(zq + (size_t)qi[k] * 64);
  const float4* b = (const float4*)(za + (size_t)ai[k] * 64);
  float ssum = 0.f;
#pragma unroll
  for (int j = 0; j < 16; ++j) {
    float4 x = a[j], y = b[j];
    ssum += x.x * y.x + x.y * y.y + x.z * y.z + x.w * y.w;
  }
  o[k] = ssum;
}

// ---------------- host launch ----------------

extern "C" void kernel_launch(void* const* d_in, const int* in_sizes, int n_in,
                              void* d_out, int out_size, void* d_ws, size_t ws_size,
                              hipStream_t stream) {
  const float* xq = (const float*)d_in[0];
  const float* xa = (const float*)d_in[1];
  const float* xe = (const float*)d_in[2];
  const int* e_e2q = (const int*)d_in[3];
  const int* e_e2e = (const int*)d_in[4];
  const int* e_e2a = (const int*)d_in[5];
  const int* e_q2a = (const int*)d_in[6];
  const int* pos_idx = (const int*)d_in[7];
  const int* neg_idx = (const int*)d_in[8];
  const float* W_in = (const float*)d_in[9];
  const float* b_in = (const float*)d_in[10];
  const float* bn_gamma = (const float*)d_in[11];
  const float* bn_beta = (const float*)d_in[12];
  const float* W_kqv = (const float*)d_in[13];
  const float* b_kqv = (const float*)d_in[14];
  const float* A_k = (const float*)d_in[15];
  const float* A_v = (const float*)d_in[16];
  const float* p_rel = (const float*)d_in[17];
  const float* W_out = (const float*)d_in[18];
  const float* b_out = (const float*)d_in[19];
  const float* skip = (const float*)d_in[20];
  float* out = (float*)d_out;

  float* ws = (float*)d_ws;
  size_t off = 0;
  _Float16* y_h = (_Float16*)(ws + off);    off += (size_t)NT_TOTAL * 32;
  _Float16* kqvQ = (_Float16*)(ws + off);   off += (size_t)NQ * 96;
  _Float16* kqvE = (_Float16*)(ws + off);   off += (size_t)NE * 160;
  _Float16* kqvA = (_Float16*)(ws + off);   off += (size_t)NA * 64;
  _Float16* agg_h = (_Float16*)(ws + off);  off += (size_t)NT_TOTAL * 32;
  float* stats = ws + off;                  off += 384;
  float* scale = ws + off;                  off += 192;
  float* shift = ws + off;                  off += 192;
  float* bias2 = ws + off;                  off += 576;
  float* bias_big = ws + off;               off += 640;
  _Float16* WqT = (_Float16*)(ws + off);    off += 192 * 72 / 2;
  _Float16* WeT = (_Float16*)(ws + off);    off += 320 * 72 / 2;
  _Float16* WaT = (_Float16*)(ws + off);    off += 128 * 72 / 2;
  _Float16* WinT = (_Float16*)(ws + off);   off += 3 * 64 * 136 / 2;
  _Float16* WoutT = (_Float16*)(ws + off);  off += 3 * 64 * 72 / 2;
  float* bstats = ws + off;                 off += (size_t)GIN_TOT * 128;
  unsigned* row_start = (unsigned*)(ws + off); off += NT_TOTAL;
  unsigned* cursor = (unsigned*)(ws + off);    off += NT_TOTAL;
  unsigned* bsums = (unsigned*)(ws + off);     off += 1024;
  unsigned* eidx = (unsigned*)(ws + off);      off += E_TOTAL + 8;

  float* zq_out = out + (N_POS + N_NEG);

  prep_misc<<<dim3(512), dim3(256), 0, stream>>>((float*)row_start, W_in, WinT, W_out, WoutT);

  inproj_hist_all<<<dim3(GIN_TOT + HB), dim3(256), 0, stream>>>(
      xq, xa, xe, WinT, b_in, y_h, bstats,
      e_e2q + E_E2Q, e_e2e + E_E2E, e_e2a + E_E2A, e_q2a + E_Q2A, row_start);

  reduce_scan1<<<dim3(384 + NBLK_SCAN), dim3(256), 0, stream>>>(
      bstats, stats, row_start, bsums);

  scan2_bn<<<dim3(2), dim3(256), 0, stream>>>(
      bsums, NBLK_SCAN, stats, bn_gamma, bn_beta, scale, shift, b_kqv, W_kqv, bias2);

  scan3_wprep<<<dim3(NBLK_SCAN + 160), dim3(256), 0, stream>>>(
      row_start, bsums, cursor, W_kqv, bias2, A_k, A_v, scale,
      WqT, WeT, WaT, bias_big);

  kqv_scatter2<<<dim3(KS2_TOT), dim3(256), SMEM_KQV2, stream>>>(
      y_h, WqT, WeT, WaT, bias_big, kqvQ, kqvE, kqvA,
      e_e2q, e_e2q + E_E2Q, e_e2e, e_e2e + E_E2E,
      e_e2a, e_e2a + E_E2A, e_q2a, e_q2a + E_Q2A, cursor, eidx);

  gather_all<<<dim3(GB_Q + GB_E + GB_A), dim3(256), 0, stream>>>(
      row_start, cursor, eidx, kqvQ, kqvE, kqvA, p_rel, agg_h);

  gemm_out_all<<<dim3(TOP_Q + TOP_A + TOP_E), dim3(256), 0, stream>>>(
      agg_h, y_h, WoutT, b_out, scale, shift, skip, zq_out);

  pred_all<<<dim3(CDIV(N_POS + N_NEG, 256)), dim3(256), 0, stream>>>(
      pos_idx, neg_idx, zq_out, zq_out + (size_t)NQ * 64, out);
}

// Round 22
// 645.030 us; speedup vs baseline: 1.0385x; 1.0263x over previous
//
#include <hip/hip_runtime.h>
#include <hip/hip_bf16.h>
#include <hip/hip_fp16.h>
#include <math.h>

#define NQ 8192
#define NA 32768
#define NE 500000
#define F_IN 128
#define E_E2Q 131072
#define E_E2E 800000
#define E_E2A 262144
#define E_Q2A 32768
#define N_POS 8192
#define N_NEG 24576

#define NT_TOTAL (NQ + NA + NE)
#define E_TOTAL (E_E2Q + E_E2E + E_E2A + E_Q2A)
#define NBLK_SCAN ((NT_TOTAL + 1023) / 1024)         // 529
#define CDIV(a, b) (((a) + (b) - 1) / (b))

#define BASE_Q 0
#define BASE_A NQ
#define BASE_E (NQ + NA)

// in-proj block counts (1 block per bstats row)
#define GIN_Q 128
#define GIN_A 512
#define GIN_E 768
#define GIN_TOT (GIN_Q + GIN_A + GIN_E)   // 1408
#define HB 1024                            // hist blocks appended

// gather grid
#define GB_Q 2048
#define GB_E 4096
#define GB_A 8192

// out-proj grid
#define TOP_Q 64
#define TOP_A 256
#define TOP_E 3907

// kqv_scatter3 grid: kqv (BM=128 direct-A) first, scatter LAST
#define KQ3_E 3907      // row blocks of 128; x2 col tiles (BNT=160)
#define KQ3_Q 64        // x2 col tiles (BNT=96)
#define KQ3_A 256       // single tile (BNT=128)
#define SCB 2048
#define KS3_TOT (2 * KQ3_E + 2 * KQ3_Q + KQ3_A + SCB)   // 10246
#define SMEM_KQV3 43008

typedef _Float16 half8_t __attribute__((ext_vector_type(8)));
typedef _Float16 half2_t __attribute__((ext_vector_type(2)));
typedef float f32x4_t __attribute__((ext_vector_type(4)));

__device__ inline void load_lds16(const void* g, void* l) {
  __builtin_amdgcn_global_load_lds((const __attribute__((address_space(1))) void*)g,
                                   (__attribute__((address_space(3))) void*)l, 16, 0, 0);
}

__device__ inline float fast_gelu(float v) {
  float u = 1.5957691216057308f * fmaf(0.044715f * v * v, v, v);
  return v / (1.f + __expf(-u));
}

// ---------------- K1: prep (zero row_start + WinT + WoutT) ----------------

__global__ __launch_bounds__(256) void prep_misc(
    float* __restrict__ row_start_f,
    const float* __restrict__ W_in, _Float16* __restrict__ WinT,
    const float* __restrict__ W_out, _Float16* __restrict__ WoutT)
{
  int bid = blockIdx.x;
  if (bid < 128) {
    size_t i = (size_t)bid * 256 + threadIdx.x;
    size_t stride = (size_t)128 * 256;
    for (; i < NT_TOTAL; i += stride) row_start_f[i] = 0.f;
  } else if (bid < 320) {
    int b = bid - 128;
    int t = b >> 6, n = b & 63, k = threadIdx.x;
    if (k < 136) {
      float v = (k < 128) ? W_in[(size_t)t * 128 * 64 + (size_t)k * 64 + n] : 0.f;
      WinT[((size_t)t * 64 + n) * 136 + k] = (_Float16)v;
    }
  } else {
    int b = bid - 320;
    int t = b >> 6, n = b & 63, k = threadIdx.x;
    if (k < 72) {
      float v = (k < 64) ? W_out[(size_t)t * 64 * 64 + (size_t)k * 64 + n] : 0.f;
      WoutT[((size_t)t * 64 + n) * 72 + k] = (_Float16)v;
    }
  }
}

// ---------------- K2: in-proj (pipelined LDS stage) + hist, block-range merged ----------------

__global__ __launch_bounds__(256) void inproj_hist_all(
    const float* __restrict__ xq, const float* __restrict__ xa,
    const float* __restrict__ xe,
    const _Float16* __restrict__ WinT, const float* __restrict__ b_in,
    _Float16* __restrict__ y_h, float* __restrict__ bstats,
    const int* __restrict__ hd0, const int* __restrict__ hd1,
    const int* __restrict__ hd2, const int* __restrict__ hd3,
    unsigned* __restrict__ cnt)
{
  __shared__ __align__(16) float bufA[32 * 128];
  __shared__ __align__(16) float bufB[32 * 128];
  __shared__ _Float16 Bs[64 * 136];
  __shared__ float s1[64], s2[64];

  int bid = blockIdx.x;
  if (bid >= GIN_TOT) {
    int i = (bid - GIN_TOT) * 256 + threadIdx.x;
    int stride = HB * 256;
    for (; i < E_TOTAL; i += stride) {
      if (i < E_E2Q) atomicAdd(&cnt[BASE_Q + hd0[i]], 1u);
      else if (i < E_E2Q + E_E2E) atomicAdd(&cnt[BASE_E + hd1[i - E_E2Q]], 1u);
      else if (i < E_E2Q + E_E2E + E_E2A)
        atomicAdd(&cnt[BASE_A + hd2[i - E_E2Q - E_E2E]], 1u);
      else atomicAdd(&cnt[BASE_A + hd3[i - E_E2Q - E_E2E - E_E2A]], 1u);
    }
    return;
  }

  int t, lb, nb;
  const float* Af;
  _Float16* oh;
  if (bid < GIN_Q)              { t = 0; lb = bid;                 nb = GIN_Q; Af = xq; oh = y_h; }
  else if (bid < GIN_Q + GIN_A) { t = 1; lb = bid - GIN_Q;         nb = GIN_A; Af = xa; oh = y_h + (size_t)NQ * 64; }
  else                          { t = 2; lb = bid - GIN_Q - GIN_A; nb = GIN_E; Af = xe; oh = y_h + (size_t)(NQ + NA) * 64; }
  int M = (t == 0) ? NQ : (t == 1) ? NA : NE;
  int nh = CDIV(M, 32);
  const _Float16* WT = WinT + (size_t)t * 64 * 136;
  const float* bias = b_in + t * 64;

  int tid = threadIdx.x, w = tid >> 6, l = tid & 63;
  int lr = l & 15, lg = l >> 4;
  int wrow = (w & 1) * 16;
  int wcol = (w >> 1) * 32;

  for (int idx = tid; idx < 64 * 136 / 8; idx += 256)
    *(half8_t*)&Bs[idx * 8] = *(const half8_t*)&WT[(size_t)idx * 8];
  if (tid < 64) { s1[tid] = 0.f; s2[tid] = 0.f; }

  float bval[2];
  bval[0] = bias[wcol + lr];
  bval[1] = bias[wcol + 16 + lr];
  float ps1[2] = {}, ps2[2] = {};

  auto stage = [&](float* buf, int h) {
    const char* srcbase = (const char*)Af + (size_t)h * 32 * 512;
    int rowlim = M - h * 32;
#pragma unroll
    for (int r = 0; r < 4; ++r) {
      int unit = r * 4 + w;
      char* ldst = (char*)buf + unit * 1024;
      int p = unit * 1024 + l * 16;
      int row = p >> 9;
      const char* src = (row < rowlim) ? srcbase + (size_t)row * 512 + (p & 511)
                                       : srcbase;
      load_lds16(src, ldst);
    }
  };

  int h0 = lb;
  if (h0 < nh) stage(bufA, h0);
  __syncthreads();

  float* cur = bufA;
  float* nxt = bufB;
  for (int h = h0; h < nh; h += nb) {
    int h2 = h + nb;
    bool more = h2 < nh;
    if (more) {
      stage(nxt, h2);
      asm volatile("s_waitcnt vmcnt(4)" ::: "memory");
    } else {
      asm volatile("s_waitcnt vmcnt(0)" ::: "memory");
    }
    __builtin_amdgcn_sched_barrier(0);
    __builtin_amdgcn_s_barrier();

    f32x4_t acc[2] = {};
#pragma unroll
    for (int ks = 0; ks < 4; ++ks) {
      const float4* pa = (const float4*)((const char*)cur +
                          (wrow + lr) * 512 + ks * 128 + lg * 32);
      float4 x0 = pa[0], x1 = pa[1];
      half8_t a0 = {(_Float16)x0.x, (_Float16)x0.y, (_Float16)x0.z, (_Float16)x0.w,
                    (_Float16)x1.x, (_Float16)x1.y, (_Float16)x1.z, (_Float16)x1.w};
#pragma unroll
      for (int ct = 0; ct < 2; ++ct) {
        half8_t b = *(const half8_t*)&Bs[(wcol + ct * 16 + lr) * 136 + ks * 32 + lg * 8];
        acc[ct] = __builtin_amdgcn_mfma_f32_16x16x32_f16(a0, b, acc[ct], 0, 0, 0);
      }
    }
    int rbase = h * 32 + wrow + lg * 4;
#pragma unroll
    for (int ct = 0; ct < 2; ++ct) {
      int col = wcol + ct * 16 + lr;
#pragma unroll
      for (int j = 0; j < 4; ++j) {
        int row = rbase + j;
        if (row >= M) continue;
        float val = fmaxf(acc[ct][j] + bval[ct], 0.f);
        oh[(size_t)row * 64 + col] = (_Float16)val;
        ps1[ct] += val;
        ps2[ct] += val * val;
      }
    }
    __builtin_amdgcn_s_barrier();
    float* tmp = cur; cur = nxt; nxt = tmp;
  }

#pragma unroll
  for (int ct = 0; ct < 2; ++ct) {
    int col = wcol + ct * 16 + lr;
    atomicAdd(&s1[col], ps1[ct]);
    atomicAdd(&s2[col], ps2[ct]);
  }
  __syncthreads();
  if (tid < 64) {
    bstats[(size_t)blockIdx.x * 128 + tid] = s1[tid];
    bstats[(size_t)blockIdx.x * 128 + 64 + tid] = s2[tid];
  }
}

// ---------------- K3: stats_reduce + scan1 merged ----------------

__global__ __launch_bounds__(256) void reduce_scan1(
    const float* __restrict__ bstats, float* __restrict__ stats,
    unsigned* __restrict__ arr, unsigned* __restrict__ bsums)
{
  __shared__ __align__(16) char shbuf[1024];
  int bid = blockIdx.x;
  int t0 = threadIdx.x;
  if (bid < 384) {
    float* sh = (float*)shbuf;
    int t = bid >> 7, c = bid & 127;
    int nb = (t == 0) ? GIN_Q : (t == 1) ? GIN_A : GIN_E;
    int base = (t == 0) ? 0 : (t == 1) ? GIN_Q : (GIN_Q + GIN_A);
    float s = 0.f;
    for (int i = t0; i < nb; i += 256)
      s += bstats[(size_t)(base + i) * 128 + c];
    sh[t0] = s;
    __syncthreads();
    for (int off2 = 128; off2 > 0; off2 >>= 1) {
      if (t0 < off2) sh[t0] += sh[t0 + off2];
      __syncthreads();
    }
    if (t0 == 0) stats[t * 128 + c] = sh[0];
  } else {
    unsigned* sh = (unsigned*)shbuf;
    int blk = bid - 384;
    int base = blk * 1024 + t0 * 4;
    unsigned v[4];
    unsigned s = 0;
#pragma unroll
    for (int j = 0; j < 4; ++j) {
      v[j] = (base + j < NT_TOTAL) ? arr[base + j] : 0u;
      s += v[j];
    }
    sh[t0] = s;
    __syncthreads();
    for (int off = 1; off < 256; off <<= 1) {
      unsigned x = (t0 >= off) ? sh[t0 - off] : 0u;
      __syncthreads();
      sh[t0] += x;
      __syncthreads();
    }
    unsigned run = sh[t0] - s;
#pragma unroll
    for (int j = 0; j < 4; ++j) {
      if (base + j < NT_TOTAL) arr[base + j] = run;
      run += v[j];
    }
    if (t0 == 255) bsums[blk] = sh[255];
  }
}

// ---------------- K4: scan2 (block 0) + bn_finalize+kqv_bias2 (block 1) ----------------

__global__ __launch_bounds__(256) void scan2_bn(
    unsigned* __restrict__ bsums, int nbk,
    const float* __restrict__ stats,
    const float* __restrict__ gamma, const float* __restrict__ beta,
    float* __restrict__ scale, float* __restrict__ shift,
    const float* __restrict__ b_kqv, const float* __restrict__ W_kqv,
    float* __restrict__ bias2)
{
  int t0 = threadIdx.x;
  if (blockIdx.x == 0) {
    __shared__ unsigned sh[256];
    __shared__ unsigned carry;
    if (t0 == 0) carry = 0;
    __syncthreads();
    for (int chunk = 0; chunk < nbk; chunk += 256) {
      int i = chunk + t0;
      unsigned v = (i < nbk) ? bsums[i] : 0u;
      sh[t0] = v;
      __syncthreads();
      for (int off = 1; off < 256; off <<= 1) {
        unsigned x = (t0 >= off) ? sh[t0 - off] : 0u;
        __syncthreads();
        sh[t0] += x;
        __syncthreads();
      }
      unsigned inc = sh[t0];
      unsigned c = carry;
      __syncthreads();
      if (i < nbk) bsums[i] = c + inc - v;
      if (t0 == 255) carry = c + sh[255];
      __syncthreads();
    }
  } else {
    __shared__ float sshift[192];
    if (t0 < 192) {
      int ty = t0 >> 6, c = t0 & 63;
      float invN = (ty == 0) ? (1.f / NQ) : (ty == 1) ? (1.f / NA) : (1.f / NE);
      float mu = stats[ty * 128 + c] * invN;
      float var = stats[ty * 128 + 64 + c] * invN - mu * mu;
      float rs = rsqrtf(var + 1e-5f);
      float gm = gamma[t0];
      float sc = gm * rs;
      float sf = beta[t0] - gm * mu * rs;
      scale[t0] = sc;
      shift[t0] = sf;
      sshift[t0] = sf;
    }
    __syncthreads();
    for (int idx = t0; idx < 576; idx += 256) {
      int t = idx / 192, n = idx % 192;
      float s = b_kqv[t * 192 + n];
      for (int k = 0; k < 64; ++k)
        s += sshift[t * 64 + k] * W_kqv[(size_t)t * 64 * 192 + k * 192 + n];
      bias2[t * 192 + n] = s;
    }
  }
}

// ---------------- K5: scan3 + wprep_kqv merged ----------------

__global__ __launch_bounds__(256) void scan3_wprep(
    unsigned* __restrict__ arr, const unsigned* __restrict__ bsums,
    unsigned* __restrict__ cursor,
    const float* __restrict__ W_kqv, const float* __restrict__ bias2,
    const float* __restrict__ A_k, const float* __restrict__ A_v,
    const float* __restrict__ scale,
    _Float16* __restrict__ WqT, _Float16* __restrict__ WeT,
    _Float16* __restrict__ WaT, float* __restrict__ bias_big)
{
  int bid = blockIdx.x;
  int t0 = threadIdx.x;
  if (bid < NBLK_SCAN) {
    int base = bid * 1024 + t0 * 4;
    unsigned add = bsums[bid];
#pragma unroll
    for (int j = 0; j < 4; ++j) {
      int idx = base + j;
      if (idx < NT_TOTAL) {
        unsigned r = arr[idx] + add;
        arr[idx] = r;
        cursor[idx] = r;
      }
    }
    return;
  }
  int j = (bid - NBLK_SCAN) * 4 + (t0 >> 6);
  int c = t0 & 63;
  if (j >= 640) return;
  int t, jj, bofs;
  _Float16* W;
  if (j < 192)      { t = 0; jj = j;       W = WqT; bofs = 0; }
  else if (j < 512) { t = 2; jj = j - 192; W = WeT; bofs = 192; }
  else              { t = 1; jj = j - 512; W = WaT; bofs = 512; }
  const float* Wt = W_kqv + (size_t)t * 64 * 192;
  const float* b2 = bias2 + t * 192;
  int mode = 0, rel = 0, sub = 0;
  if (t == 1) { mode = 1; rel = (jj < 64) ? 2 : 3; sub = jj & 63; }
  else if (jj >= 64 && jj < 128) { mode = 1; rel = (t == 0) ? 0 : 1; sub = jj - 64; }
  else if (jj >= 128) {
    mode = 2; sub = (jj - 128) & 63;
    rel = (t == 0) ? 3 : ((jj - 128) >> 6);
  }
  int h = sub >> 5, x = sub & 31;
  float wv, bv;
  if (mode == 0) {
    wv = Wt[(size_t)c * 192 + jj];
    bv = b2[jj];
  } else if (mode == 1) {
    const float* Ar = A_k + ((size_t)rel * 2048 + h * 1024 + x * 32);
    float s = 0.f, sb = 0.f;
    for (int f = 0; f < 32; ++f) {
      float a = Ar[f];
      s = fmaf(a, Wt[(size_t)c * 192 + 64 + h * 32 + f], s);
      sb = fmaf(a, b2[64 + h * 32 + f], sb);
    }
    wv = s; bv = sb;
  } else {
    const float* Ar = A_v + ((size_t)rel * 2048 + h * 1024 + x);
    float s = 0.f, sb = 0.f;
    for (int d = 0; d < 32; ++d) {
      float a = Ar[d * 32];
      s = fmaf(a, Wt[(size_t)c * 192 + 128 + h * 32 + d], s);
      sb = fmaf(a, b2[128 + h * 32 + d], sb);
    }
    wv = s; bv = sb;
  }
  wv *= scale[t * 64 + c];
  W[(size_t)jj * 72 + c] = (_Float16)wv;
  if (c < 8) W[(size_t)jj * 72 + 64 + c] = (_Float16)0.f;
  if (c == 0) bias_big[bofs + jj] = bv;
}

// ---------------- kqv GEMM body (BM=128, 512 thr, direct-A, col-split waves) ----------------

template <int BNT>
__device__ __forceinline__ void kqv_bodyD(
    char* smem,
    const _Float16* __restrict__ Ah,
    const _Float16* __restrict__ WT, const float* __restrict__ bias, int M,
    _Float16* __restrict__ oh, int LDO, int row0, int colbase)
{
  constexpr int KP = 72;
  constexpr int TP = BNT + 8;
  constexpr int NCTW = BNT / 32;     // col tiles per col-wave
  _Float16* Bs = (_Float16*)smem;
  _Float16* Ts = (_Float16*)smem;    // overlay after MFMA
  int tid = threadIdx.x;
  int w = tid >> 6, l = tid & 63;
  int rw = w >> 1, cw = w & 1;       // 4 row-waves x 2 col-waves
  int lr = l & 15, lg = l >> 4;

  // stage B
  {
    const _Float16* wsrc = WT + (size_t)colbase * KP;
    for (int idx = tid; idx < BNT * KP / 8; idx += 512)
      *(half8_t*)&Bs[idx * 8] = *(const half8_t*)&wsrc[(size_t)idx * 8];
  }
  // direct A fragments (rows rw*32 + rt*16 + lr)
  half8_t afrag[2][2];
#pragma unroll
  for (int rt = 0; rt < 2; ++rt) {
    int gr = row0 + rw * 32 + rt * 16 + lr;
    bool ok = gr < M;
#pragma unroll
    for (int ks = 0; ks < 2; ++ks) {
      half8_t h8 = {};
      if (ok) h8 = *(const half8_t*)&Ah[(size_t)gr * 64 + ks * 32 + lg * 8];
      afrag[rt][ks] = h8;
    }
  }
  __syncthreads();   // Bs staged

  f32x4_t acc[2][NCTW] = {};
#pragma unroll
  for (int ks = 0; ks < 2; ++ks) {
#pragma unroll
    for (int ct = 0; ct < NCTW; ++ct) {
      half8_t b = *(const half8_t*)&Bs[(cw * (BNT / 2) + ct * 16 + lr) * KP + ks * 32 + lg * 8];
      acc[0][ct] = __builtin_amdgcn_mfma_f32_16x16x32_f16(afrag[0][ks], b, acc[0][ct], 0, 0, 0);
      acc[1][ct] = __builtin_amdgcn_mfma_f32_16x16x32_f16(afrag[1][ks], b, acc[1][ct], 0, 0, 0);
    }
  }

  float bval[NCTW];
#pragma unroll
  for (int ct = 0; ct < NCTW; ++ct)
    bval[ct] = bias[colbase + cw * (BNT / 2) + ct * 16 + lr];

  __syncthreads();   // all waves done reading Bs -> Ts may overwrite
#pragma unroll
  for (int rt = 0; rt < 2; ++rt) {
    int r2base = rw * 32 + rt * 16 + lg * 4;
#pragma unroll
    for (int ct = 0; ct < NCTW; ++ct) {
      int colL = cw * (BNT / 2) + ct * 16 + lr;
#pragma unroll
      for (int j = 0; j < 4; ++j)
        Ts[(r2base + j) * TP + colL] = (_Float16)(acc[rt][ct][j] + bval[ct]);
    }
  }
  __syncthreads();
  constexpr int C8 = BNT / 8;
  for (int idx = tid; idx < 128 * C8; idx += 512) {
    int r2 = idx / C8, c8 = (idx % C8) * 8;
    int gr = row0 + r2;
    if (gr < M)
      *(half8_t*)&oh[(size_t)gr * LDO + colbase + c8] = *(const half8_t*)&Ts[r2 * TP + c8];
  }
}

// ---------------- K6: kqv GEMMs (direct-A) + scatter LAST, merged (512 threads) ----------------

__global__ __launch_bounds__(512) void kqv_scatter3(
    const _Float16* __restrict__ y_h,
    const _Float16* __restrict__ WqT, const _Float16* __restrict__ WeT,
    const _Float16* __restrict__ WaT, const float* __restrict__ bias_big,
    _Float16* __restrict__ kqvQ, _Float16* __restrict__ kqvE,
    _Float16* __restrict__ kqvA,
    const int* __restrict__ s0, const int* __restrict__ d0,
    const int* __restrict__ s1, const int* __restrict__ d1,
    const int* __restrict__ s2, const int* __restrict__ d2,
    const int* __restrict__ s3, const int* __restrict__ d3,
    unsigned* __restrict__ cursor, unsigned* __restrict__ eidx)
{
  extern __shared__ __align__(16) char smem[];
  int bid = blockIdx.x;
  if (bid < 2 * KQ3_E) {
    int ct = bid / KQ3_E;
    int rb = bid % KQ3_E;
    kqv_bodyD<160>(smem, y_h + (size_t)(NQ + NA) * 64, WeT, bias_big + 192, NE,
                   kqvE, 320, rb * 128, ct * 160);
  } else if (bid < 2 * KQ3_E + 2 * KQ3_Q) {
    int b = bid - 2 * KQ3_E;
    int ct = b / KQ3_Q;
    int rb = b % KQ3_Q;
    kqv_bodyD<96>(smem, y_h, WqT, bias_big, NQ, kqvQ, 192, rb * 128, ct * 96);
  } else if (bid < 2 * KQ3_E + 2 * KQ3_Q + KQ3_A) {
    int b = bid - 2 * KQ3_E - 2 * KQ3_Q;
    kqv_bodyD<128>(smem, y_h + (size_t)NQ * 64, WaT, bias_big + 512, NA,
                   kqvA, 128, b * 128, 0);
  } else {
    // ---- scatter range (appended last; drains under GEMM tail) ----
    int i = (bid - 2 * KQ3_E - 2 * KQ3_Q - KQ3_A) * 512 + threadIdx.x;
    int stride = SCB * 512;
    for (; i < E_TOTAL; i += stride) {
      unsigned pos, pay;
      if (i < E_E2Q) {
        pos = atomicAdd(&cursor[BASE_Q + d0[i]], 1u);
        pay = (unsigned)(s0[i] * 320);
      } else if (i < E_E2Q + E_E2E) {
        int k = i - E_E2Q;
        pos = atomicAdd(&cursor[BASE_E + d1[k]], 1u);
        pay = (unsigned)(s1[k] * 320);
      } else if (i < E_E2Q + E_E2E + E_E2A) {
        int k = i - E_E2Q - E_E2E;
        pos = atomicAdd(&cursor[BASE_A + d2[k]], 1u);
        pay = (unsigned)(s2[k] * 320);
      } else {
        int k = i - E_E2Q - E_E2E - E_E2A;
        pos = atomicAdd(&cursor[BASE_A + d3[k]], 1u);
        pay = (unsigned)(s3[k] * 192) | 0x80000000u;
      }
      eidx[pos] = pay;
    }
  }
}

// ---------------- gather body ----------------

template <int NREL>
__device__ __forceinline__ void gather_body(
    int bidLocal, int nblocks, int N, int nodebase,
    const unsigned* __restrict__ row_start, const unsigned* __restrict__ row_end,
    const unsigned* __restrict__ eidx,
    const _Float16* __restrict__ baseA, int vofA,
    const _Float16* __restrict__ baseB, int vofB,
    const _Float16* __restrict__ qtA, int ldqA,
    const _Float16* __restrict__ qtB, int ldqB,
    const float* __restrict__ prelA, const float* __restrict__ prelB,
    _Float16* __restrict__ agg)
{
  int lane = threadIdx.x & 63;
  int h = lane >> 5, f = lane & 31;
  int idx2 = h * 32 + 2 * (f & 15);
  const float isd = 0.17677669529663687f;
  float pr0 = prelA[h] * isd;
  float pr1 = (NREL == 2) ? prelB[h] * isd : 0.f;

  int wid = (int)(((size_t)bidLocal * 256 + threadIdx.x) >> 6);
  int nw = nblocks * 4;

  int n0 = wid;
  unsigned b0s = 0, b0e = 0, e00 = 0, e01 = 0;
  half2_t q00p = {}, q01p = {};
  if (n0 < N) {
    b0s = row_start[nodebase + n0];
    b0e = row_end[nodebase + n0];
    q00p = *(const half2_t*)&qtA[(size_t)n0 * ldqA + idx2];
    if (NREL == 2) q01p = *(const half2_t*)&qtB[(size_t)n0 * ldqB + idx2];
    e00 = eidx[b0s];
    e01 = eidx[b0s + 1];
  }
  int n1 = n0 + nw;
  unsigned b1s = 0, b1e = 0;
  half2_t q10p = {}, q11p = {};
  if (n0 < N && n1 < N) {
    b1s = row_start[nodebase + n1];
    b1e = row_end[nodebase + n1];
    q10p = *(const half2_t*)&qtA[(size_t)n1 * ldqA + idx2];
    if (NREL == 2) q11p = *(const half2_t*)&qtB[(size_t)n1 * ldqB + idx2];
  }

  while (n0 < N) {
    unsigned e10 = 0, e11 = 0;
    if (n1 < N) {
      e10 = eidx[b1s];
      e11 = eidx[b1s + 1];
    }
    int n2 = n1 + nw;
    unsigned b2s = 0, b2e = 0;
    half2_t q20p = {}, q21p = {};
    if (n2 < N) {
      b2s = row_start[nodebase + n2];
      b2e = row_end[nodebase + n2];
      q20p = *(const half2_t*)&qtA[(size_t)n2 * ldqA + idx2];
      if (NREL == 2) q21p = *(const half2_t*)&qtB[(size_t)n2 * ldqB + idx2];
    }

    float vs = 0.f, ss = 0.f;
    unsigned i = b0s;

    auto do_pair = [&](unsigned p1, unsigned p2) {
      unsigned o1 = p1 & 0x7FFFFFFFu, o2 = p2 & 0x7FFFFFFFu;
      bool r1 = (NREL == 2) && (p1 >> 31);
      bool r2 = (NREL == 2) && (p2 >> 31);
      const _Float16* b1 = (r1 ? baseB : baseA) + o1;
      const _Float16* b2 = (r2 ? baseB : baseA) + o2;
      half2_t k21 = *(const half2_t*)&b1[idx2];
      float v1 = (float)b1[(r1 ? vofB : vofA) + lane];
      half2_t k22 = *(const half2_t*)&b2[idx2];
      float v2 = (float)b2[(r2 ? vofB : vofA) + lane];
      float sa = __builtin_amdgcn_fdot2(k21, r1 ? q01p : q00p, 0.f, false);
      float sb = __builtin_amdgcn_fdot2(k22, r2 ? q01p : q00p, 0.f, false);
#pragma unroll
      for (int off = 1; off <= 8; off <<= 1) {
        sa += __shfl_xor(sa, off, 32);
        sb += __shfl_xor(sb, off, 32);
      }
      float w1 = __expf(sa * (r1 ? pr1 : pr0));
      float w2 = __expf(sb * (r2 ? pr1 : pr0));
      ss += w1 + w2;
      vs = fmaf(w1, v1, vs);
      vs = fmaf(w2, v2, vs);
    };
    auto do_single = [&](unsigned p1) {
      unsigned o1 = p1 & 0x7FFFFFFFu;
      bool r1 = (NREL == 2) && (p1 >> 31);
      const _Float16* b1 = (r1 ? baseB : baseA) + o1;
      half2_t k21 = *(const half2_t*)&b1[idx2];
      float v1 = (float)b1[(r1 ? vofB : vofA) + lane];
      float sa = __builtin_amdgcn_fdot2(k21, r1 ? q01p : q00p, 0.f, false);
#pragma unroll
      for (int off = 1; off <= 8; off <<= 1) sa += __shfl_xor(sa, off, 32);
      float w1 = __expf(sa * (r1 ? pr1 : pr0));
      ss += w1;
      vs = fmaf(w1, v1, vs);
    };

    if (i + 2 <= b0e) { do_pair(e00, e01); i += 2; }
    else if (i < b0e) { do_single(e00); i = b0e; }
    for (; i + 2 <= b0e; i += 2) do_pair(eidx[i], eidx[i + 1]);
    if (i < b0e) do_single(eidx[i]);

    float val = (ss > 0.f) ? vs / ss : 0.f;
    val = fast_gelu(val);
    agg[((size_t)(nodebase + n0)) * 64 + lane] = (_Float16)val;

    n0 = n1; b0s = b1s; b0e = b1e; q00p = q10p; q01p = q11p; e00 = e10; e01 = e11;
    n1 = n2; b1s = b2s; b1e = b2e; q10p = q20p; q11p = q21p;
  }
}

__global__ __launch_bounds__(256) void gather_all(
    const unsigned* __restrict__ row_start, const unsigned* __restrict__ row_end,
    const unsigned* __restrict__ eidx,
    const _Float16* __restrict__ kqvQ, const _Float16* __restrict__ kqvE,
    const _Float16* __restrict__ kqvA,
    const float* __restrict__ p_rel, _Float16* __restrict__ agg)
{
  int bid = blockIdx.x;
  if (bid < GB_Q) {
    gather_body<1>(bid, GB_Q, NQ, BASE_Q, row_start, row_end, eidx,
                   kqvE, 128, kqvE, 128, kqvQ + 64, 192, kqvQ + 64, 192,
                   p_rel + 0, p_rel + 0, agg);
  } else if (bid < GB_Q + GB_E) {
    gather_body<1>(bid - GB_Q, GB_E, NE, BASE_E, row_start, row_end, eidx,
                   kqvE, 192, kqvE, 192, kqvE + 64, 320, kqvE + 64, 320,
                   p_rel + 2, p_rel + 2, agg);
  } else {
    gather_body<2>(bid - GB_Q - GB_E, GB_A, NA, BASE_A, row_start, row_end, eidx,
                   kqvE, 256, kqvQ, 128, kqvA, 128, kqvA + 64, 128,
                   p_rel + 4, p_rel + 6, agg);
  }
}

// ---------------- K8: merged out-proj ----------------

__global__ __launch_bounds__(256) void gemm_out_all(
    const _Float16* __restrict__ agg_h, const _Float16* __restrict__ y_h,
    const _Float16* __restrict__ WoutT, const float* __restrict__ b_out,
    const float* __restrict__ scale, const float* __restrict__ shift,
    const float* __restrict__ skip, float* __restrict__ zout)
{
  __shared__ _Float16 Bs[64 * 72];
  int bid = blockIdx.x;
  int t, row0, M;
  size_t nodeoff;
  if (bid < TOP_Q)              { t = 0; row0 = bid * 128;              M = NQ; nodeoff = 0; }
  else if (bid < TOP_Q + TOP_A) { t = 1; row0 = (bid - TOP_Q) * 128;    M = NA; nodeoff = NQ; }
  else                          { t = 2; row0 = (bid - TOP_Q - TOP_A) * 128; M = NE; nodeoff = NQ + NA; }
  const _Float16* Ah = agg_h + nodeoff * 64;
  const _Float16* resh = y_h + nodeoff * 64;
  float* Cf = zout + nodeoff * 64;
  const _Float16* WT = WoutT + (size_t)t * 64 * 72;
  const float* bias = b_out + t * 64;
  const float* rsc = scale + t * 64;
  const float* rsh = shift + t * 64;

  int tid = threadIdx.x;
  int w = tid >> 6, l = tid & 63;
  int lr = l & 15, lg = l >> 4;

  for (int idx = tid; idx < 64 * 72 / 8; idx += 256)
    *(half8_t*)&Bs[idx * 8] = *(const half8_t*)&WT[(size_t)idx * 8];

  half8_t afrag[2][2];
#pragma unroll
  for (int rt = 0; rt < 2; ++rt) {
    int gr = row0 + w * 32 + rt * 16 + lr;
    bool ok = gr < M;
#pragma unroll
    for (int ks = 0; ks < 2; ++ks) {
      half8_t h8 = {};
      if (ok) h8 = *(const half8_t*)&Ah[(size_t)gr * 64 + ks * 32 + lg * 8];
      afrag[rt][ks] = h8;
    }
  }
  __syncthreads();

  f32x4_t acc[2][4] = {};
#pragma unroll
  for (int ks = 0; ks < 2; ++ks) {
#pragma unroll
    for (int ct = 0; ct < 4; ++ct) {
      half8_t b = *(const half8_t*)&Bs[(ct * 16 + lr) * 72 + ks * 32 + lg * 8];
      acc[0][ct] = __builtin_amdgcn_mfma_f32_16x16x32_f16(afrag[0][ks], b, acc[0][ct], 0, 0, 0);
      acc[1][ct] = __builtin_amdgcn_mfma_f32_16x16x32_f16(afrag[1][ks], b, acc[1][ct], 0, 0, 0);
    }
  }

  float g = 1.f / (1.f + __expf(-skip[t]));
  float gb = 1.f - g;
#pragma unroll
  for (int rt = 0; rt < 2; ++rt) {
    int rbase = row0 + w * 32 + rt * 16 + lg * 4;
#pragma unroll
    for (int ct = 0; ct < 4; ++ct) {
      int col = ct * 16 + lr;
      float bval = bias[col];
#pragma unroll
      for (int j = 0; j < 4; ++j) {
        int row = rbase + j;
        if (row >= M) continue;
        float val = acc[rt][ct][j] + bval;
        float rv = (float)resh[(size_t)row * 64 + col];
        Cf[(size_t)row * 64 + col] = g * val + gb * (rsc[col] * rv + rsh[col]);
      }
    }
  }
}

// ---------------- K9: merged predictions ----------------

__global__ void pred_all(const int* __restrict__ pos, const int* __restrict__ neg,
                         const float* __restrict__ zq, const float* __restrict__ za,
                         float* __restrict__ outp) {
  int i = blockIdx.x * blockDim.x + threadIdx.x;
  if (i >= N_POS + N_NEG) return;
  int k; const int* qi; const int* ai; float* o;
  if (i < N_POS) { k = i; qi = pos; ai = pos + N_POS; o = outp; }
  else { k = i - N_POS; qi = neg; ai = neg + N_NEG; o = outp + N_POS; }
  const float4* a = (const float4*)(zq + (size_t)qi[k] * 64);
  const float4* b = (const float4*)(za + (size_t)ai[k] * 64);
  float ssum = 0.f;
#pragma unroll
  for (int j = 0; j < 16; ++j) {
    float4 x = a[j], y = b[j];
    ssum += x.x * y.x + x.y * y.y + x.z * y.z + x.w * y.w;
  }
  o[k] = ssum;
}

// ---------------- host launch ----------------

extern "C" void kernel_launch(void* const* d_in, const int* in_sizes, int n_in,
                              void* d_out, int out_size, void* d_ws, size_t ws_size,
                              hipStream_t stream) {
  const float* xq = (const float*)d_in[0];
  const float* xa = (const float*)d_in[1];
  const float* xe = (const float*)d_in[2];
  const int* e_e2q = (const int*)d_in[3];
  const int* e_e2e = (const int*)d_in[4];
  const int* e_e2a = (const int*)d_in[5];
  const int* e_q2a = (const int*)d_in[6];
  const int* pos_idx = (const int*)d_in[7];
  const int* neg_idx = (const int*)d_in[8];
  const float* W_in = (const float*)d_in[9];
  const float* b_in = (const float*)d_in[10];
  const float* bn_gamma = (const float*)d_in[11];
  const float* bn_beta = (const float*)d_in[12];
  const float* W_kqv = (const float*)d_in[13];
  const float* b_kqv = (const float*)d_in[14];
  const float* A_k = (const float*)d_in[15];
  const float* A_v = (const float*)d_in[16];
  const float* p_rel = (const float*)d_in[17];
  const float* W_out = (const float*)d_in[18];
  const float* b_out = (const float*)d_in[19];
  const float* skip = (const float*)d_in[20];
  float* out = (float*)d_out;

  float* ws = (float*)d_ws;
  size_t off = 0;
  _Float16* y_h = (_Float16*)(ws + off);    off += (size_t)NT_TOTAL * 32;
  _Float16* kqvQ = (_Float16*)(ws + off);   off += (size_t)NQ * 96;
  _Float16* kqvE = (_Float16*)(ws + off);   off += (size_t)NE * 160;
  _Float16* kqvA = (_Float16*)(ws + off);   off += (size_t)NA * 64;
  _Float16* agg_h = (_Float16*)(ws + off);  off += (size_t)NT_TOTAL * 32;
  float* stats = ws + off;                  off += 384;
  float* scale = ws + off;                  off += 192;
  float* shift = ws + off;                  off += 192;
  float* bias2 = ws + off;                  off += 576;
  float* bias_big = ws + off;               off += 640;
  _Float16* WqT = (_Float16*)(ws + off);    off += 192 * 72 / 2;
  _Float16* WeT = (_Float16*)(ws + off);    off += 320 * 72 / 2;
  _Float16* WaT = (_Float16*)(ws + off);    off += 128 * 72 / 2;
  _Float16* WinT = (_Float16*)(ws + off);   off += 3 * 64 * 136 / 2;
  _Float16* WoutT = (_Float16*)(ws + off);  off += 3 * 64 * 72 / 2;
  float* bstats = ws + off;                 off += (size_t)GIN_TOT * 128;
  unsigned* row_start = (unsigned*)(ws + off); off += NT_TOTAL;
  unsigned* cursor = (unsigned*)(ws + off);    off += NT_TOTAL;
  unsigned* bsums = (unsigned*)(ws + off);     off += 1024;
  unsigned* eidx = (unsigned*)(ws + off);      off += E_TOTAL + 8;

  float* zq_out = out + (N_POS + N_NEG);

  prep_misc<<<dim3(512), dim3(256), 0, stream>>>((float*)row_start, W_in, WinT, W_out, WoutT);

  inproj_hist_all<<<dim3(GIN_TOT + HB), dim3(256), 0, stream>>>(
      xq, xa, xe, WinT, b_in, y_h, bstats,
      e_e2q + E_E2Q, e_e2e + E_E2E, e_e2a + E_E2A, e_q2a + E_Q2A, row_start);

  reduce_scan1<<<dim3(384 + NBLK_SCAN), dim3(256), 0, stream>>>(
      bstats, stats, row_start, bsums);

  scan2_bn<<<dim3(2), dim3(256), 0, stream>>>(
      bsums, NBLK_SCAN, stats, bn_gamma, bn_beta, scale, shift, b_kqv, W_kqv, bias2);

  scan3_wprep<<<dim3(NBLK_SCAN + 160), dim3(256), 0, stream>>>(
      row_start, bsums, cursor, W_kqv, bias2, A_k, A_v, scale,
      WqT, WeT, WaT, bias_big);

  kqv_scatter3<<<dim3(KS3_TOT), dim3(512), SMEM_KQV3, stream>>>(
      y_h, WqT, WeT, WaT, bias_big, kqvQ, kqvE, kqvA,
      e_e2q, e_e2q + E_E2Q, e_e2e, e_e2e + E_E2E,
      e_e2a, e_e2a + E_E2A, e_q2a, e_q2a + E_Q2A, cursor, eidx);

  gather_all<<<dim3(GB_Q + GB_E + GB_A), dim3(256), 0, stream>>>(
      row_start, cursor, eidx, kqvQ, kqvE, kqvA, p_rel, agg_h);

  gemm_out_all<<<dim3(TOP_Q + TOP_A + TOP_E), dim3(256), 0, stream>>>(
      agg_h, y_h, WoutT, b_out, scale, shift, skip, zq_out);

  pred_all<<<dim3(CDIV(N_POS + N_NEG, 256)), dim3(256), 0, stream>>>(
      pos_idx, neg_idx, zq_out, zq_out + (size_t)NQ * 64, out);
}

// Round 23
// 640.875 us; speedup vs baseline: 1.0452x; 1.0065x over previous
//
#include <hip/hip_runtime.h>
#include <hip/hip_bf16.h>
#include <hip/hip_fp16.h>
#include <math.h>

#define NQ 8192
#define NA 32768
#define NE 500000
#define F_IN 128
#define E_E2Q 131072
#define E_E2E 800000
#define E_E2A 262144
#define E_Q2A 32768
#define N_POS 8192
#define N_NEG 24576

#define NT_TOTAL (NQ + NA + NE)
#define E_TOTAL (E_E2Q + E_E2E + E_E2A + E_Q2A)
#define NBLK_SCAN ((NT_TOTAL + 1023) / 1024)         // 529
#define CDIV(a, b) (((a) + (b) - 1) / (b))

#define BASE_Q 0
#define BASE_A NQ
#define BASE_E (NQ + NA)

// in-proj block counts (1 block per bstats row)
#define GIN_Q 128
#define GIN_A 512
#define GIN_E 768
#define GIN_TOT (GIN_Q + GIN_A + GIN_E)   // 1408
#define HB 1024                            // hist blocks appended

// gather grid
#define GB_Q 2048
#define GB_E 4096
#define GB_A 8192

// out-proj grid
#define TOP_Q 64
#define TOP_A 256
#define TOP_E 3907

// kqv_scatter3 grid: kqv (BM=128 direct-A) first, scatter LAST
#define KQ3_E 3907      // row blocks of 128; x2 col tiles (BNT=160)
#define KQ3_Q 64        // x2 col tiles (BNT=96)
#define KQ3_A 256       // single tile (BNT=128)
#define SCB 2048
#define KS3_TOT (2 * KQ3_E + 2 * KQ3_Q + KQ3_A + SCB)   // 10246
#define SMEM_KQV3 23040   // max(Bs 160*72*2, Ts 64*168*2)

typedef _Float16 half8_t __attribute__((ext_vector_type(8)));
typedef _Float16 half2_t __attribute__((ext_vector_type(2)));
typedef float f32x4_t __attribute__((ext_vector_type(4)));

__device__ inline void load_lds16(const void* g, void* l) {
  __builtin_amdgcn_global_load_lds((const __attribute__((address_space(1))) void*)g,
                                   (__attribute__((address_space(3))) void*)l, 16, 0, 0);
}

__device__ inline float fast_gelu(float v) {
  float u = 1.5957691216057308f * fmaf(0.044715f * v * v, v, v);
  return v / (1.f + __expf(-u));
}

// ---------------- K1: prep (zero row_start + WinT + WoutT) ----------------

__global__ __launch_bounds__(256) void prep_misc(
    float* __restrict__ row_start_f,
    const float* __restrict__ W_in, _Float16* __restrict__ WinT,
    const float* __restrict__ W_out, _Float16* __restrict__ WoutT)
{
  int bid = blockIdx.x;
  if (bid < 128) {
    size_t i = (size_t)bid * 256 + threadIdx.x;
    size_t stride = (size_t)128 * 256;
    for (; i < NT_TOTAL; i += stride) row_start_f[i] = 0.f;
  } else if (bid < 320) {
    int b = bid - 128;
    int t = b >> 6, n = b & 63, k = threadIdx.x;
    if (k < 136) {
      float v = (k < 128) ? W_in[(size_t)t * 128 * 64 + (size_t)k * 64 + n] : 0.f;
      WinT[((size_t)t * 64 + n) * 136 + k] = (_Float16)v;
    }
  } else {
    int b = bid - 320;
    int t = b >> 6, n = b & 63, k = threadIdx.x;
    if (k < 72) {
      float v = (k < 64) ? W_out[(size_t)t * 64 * 64 + (size_t)k * 64 + n] : 0.f;
      WoutT[((size_t)t * 64 + n) * 72 + k] = (_Float16)v;
    }
  }
}

// ---------------- K2: in-proj (pipelined LDS stage) + hist, block-range merged ----------------

__global__ __launch_bounds__(256) void inproj_hist_all(
    const float* __restrict__ xq, const float* __restrict__ xa,
    const float* __restrict__ xe,
    const _Float16* __restrict__ WinT, const float* __restrict__ b_in,
    _Float16* __restrict__ y_h, float* __restrict__ bstats,
    const int* __restrict__ hd0, const int* __restrict__ hd1,
    const int* __restrict__ hd2, const int* __restrict__ hd3,
    unsigned* __restrict__ cnt)
{
  __shared__ __align__(16) float bufA[32 * 128];
  __shared__ __align__(16) float bufB[32 * 128];
  __shared__ _Float16 Bs[64 * 136];
  __shared__ float s1[64], s2[64];

  int bid = blockIdx.x;
  if (bid >= GIN_TOT) {
    int i = (bid - GIN_TOT) * 256 + threadIdx.x;
    int stride = HB * 256;
    for (; i < E_TOTAL; i += stride) {
      if (i < E_E2Q) atomicAdd(&cnt[BASE_Q + hd0[i]], 1u);
      else if (i < E_E2Q + E_E2E) atomicAdd(&cnt[BASE_E + hd1[i - E_E2Q]], 1u);
      else if (i < E_E2Q + E_E2E + E_E2A)
        atomicAdd(&cnt[BASE_A + hd2[i - E_E2Q - E_E2E]], 1u);
      else atomicAdd(&cnt[BASE_A + hd3[i - E_E2Q - E_E2E - E_E2A]], 1u);
    }
    return;
  }

  int t, lb, nb;
  const float* Af;
  _Float16* oh;
  if (bid < GIN_Q)              { t = 0; lb = bid;                 nb = GIN_Q; Af = xq; oh = y_h; }
  else if (bid < GIN_Q + GIN_A) { t = 1; lb = bid - GIN_Q;         nb = GIN_A; Af = xa; oh = y_h + (size_t)NQ * 64; }
  else                          { t = 2; lb = bid - GIN_Q - GIN_A; nb = GIN_E; Af = xe; oh = y_h + (size_t)(NQ + NA) * 64; }
  int M = (t == 0) ? NQ : (t == 1) ? NA : NE;
  int nh = CDIV(M, 32);
  const _Float16* WT = WinT + (size_t)t * 64 * 136;
  const float* bias = b_in + t * 64;

  int tid = threadIdx.x, w = tid >> 6, l = tid & 63;
  int lr = l & 15, lg = l >> 4;
  int wrow = (w & 1) * 16;
  int wcol = (w >> 1) * 32;

  for (int idx = tid; idx < 64 * 136 / 8; idx += 256)
    *(half8_t*)&Bs[idx * 8] = *(const half8_t*)&WT[(size_t)idx * 8];
  if (tid < 64) { s1[tid] = 0.f; s2[tid] = 0.f; }

  float bval[2];
  bval[0] = bias[wcol + lr];
  bval[1] = bias[wcol + 16 + lr];
  float ps1[2] = {}, ps2[2] = {};

  auto stage = [&](float* buf, int h) {
    const char* srcbase = (const char*)Af + (size_t)h * 32 * 512;
    int rowlim = M - h * 32;
#pragma unroll
    for (int r = 0; r < 4; ++r) {
      int unit = r * 4 + w;
      char* ldst = (char*)buf + unit * 1024;
      int p = unit * 1024 + l * 16;
      int row = p >> 9;
      const char* src = (row < rowlim) ? srcbase + (size_t)row * 512 + (p & 511)
                                       : srcbase;
      load_lds16(src, ldst);
    }
  };

  int h0 = lb;
  if (h0 < nh) stage(bufA, h0);
  __syncthreads();

  float* cur = bufA;
  float* nxt = bufB;
  for (int h = h0; h < nh; h += nb) {
    int h2 = h + nb;
    bool more = h2 < nh;
    if (more) {
      stage(nxt, h2);
      asm volatile("s_waitcnt vmcnt(4)" ::: "memory");
    } else {
      asm volatile("s_waitcnt vmcnt(0)" ::: "memory");
    }
    __builtin_amdgcn_sched_barrier(0);
    __builtin_amdgcn_s_barrier();

    f32x4_t acc[2] = {};
#pragma unroll
    for (int ks = 0; ks < 4; ++ks) {
      const float4* pa = (const float4*)((const char*)cur +
                          (wrow + lr) * 512 + ks * 128 + lg * 32);
      float4 x0 = pa[0], x1 = pa[1];
      half8_t a0 = {(_Float16)x0.x, (_Float16)x0.y, (_Float16)x0.z, (_Float16)x0.w,
                    (_Float16)x1.x, (_Float16)x1.y, (_Float16)x1.z, (_Float16)x1.w};
#pragma unroll
      for (int ct = 0; ct < 2; ++ct) {
        half8_t b = *(const half8_t*)&Bs[(wcol + ct * 16 + lr) * 136 + ks * 32 + lg * 8];
        acc[ct] = __builtin_amdgcn_mfma_f32_16x16x32_f16(a0, b, acc[ct], 0, 0, 0);
      }
    }
    int rbase = h * 32 + wrow + lg * 4;
#pragma unroll
    for (int ct = 0; ct < 2; ++ct) {
      int col = wcol + ct * 16 + lr;
#pragma unroll
      for (int j = 0; j < 4; ++j) {
        int row = rbase + j;
        if (row >= M) continue;
        float val = fmaxf(acc[ct][j] + bval[ct], 0.f);
        oh[(size_t)row * 64 + col] = (_Float16)val;
        ps1[ct] += val;
        ps2[ct] += val * val;
      }
    }
    __builtin_amdgcn_s_barrier();
    float* tmp = cur; cur = nxt; nxt = tmp;
  }

#pragma unroll
  for (int ct = 0; ct < 2; ++ct) {
    int col = wcol + ct * 16 + lr;
    atomicAdd(&s1[col], ps1[ct]);
    atomicAdd(&s2[col], ps2[ct]);
  }
  __syncthreads();
  if (tid < 64) {
    bstats[(size_t)blockIdx.x * 128 + tid] = s1[tid];
    bstats[(size_t)blockIdx.x * 128 + 64 + tid] = s2[tid];
  }
}

// ---------------- K3: stats_reduce + scan1 merged ----------------

__global__ __launch_bounds__(256) void reduce_scan1(
    const float* __restrict__ bstats, float* __restrict__ stats,
    unsigned* __restrict__ arr, unsigned* __restrict__ bsums)
{
  __shared__ __align__(16) char shbuf[1024];
  int bid = blockIdx.x;
  int t0 = threadIdx.x;
  if (bid < 384) {
    float* sh = (float*)shbuf;
    int t = bid >> 7, c = bid & 127;
    int nb = (t == 0) ? GIN_Q : (t == 1) ? GIN_A : GIN_E;
    int base = (t == 0) ? 0 : (t == 1) ? GIN_Q : (GIN_Q + GIN_A);
    float s = 0.f;
    for (int i = t0; i < nb; i += 256)
      s += bstats[(size_t)(base + i) * 128 + c];
    sh[t0] = s;
    __syncthreads();
    for (int off2 = 128; off2 > 0; off2 >>= 1) {
      if (t0 < off2) sh[t0] += sh[t0 + off2];
      __syncthreads();
    }
    if (t0 == 0) stats[t * 128 + c] = sh[0];
  } else {
    unsigned* sh = (unsigned*)shbuf;
    int blk = bid - 384;
    int base = blk * 1024 + t0 * 4;
    unsigned v[4];
    unsigned s = 0;
#pragma unroll
    for (int j = 0; j < 4; ++j) {
      v[j] = (base + j < NT_TOTAL) ? arr[base + j] : 0u;
      s += v[j];
    }
    sh[t0] = s;
    __syncthreads();
    for (int off = 1; off < 256; off <<= 1) {
      unsigned x = (t0 >= off) ? sh[t0 - off] : 0u;
      __syncthreads();
      sh[t0] += x;
      __syncthreads();
    }
    unsigned run = sh[t0] - s;
#pragma unroll
    for (int j = 0; j < 4; ++j) {
      if (base + j < NT_TOTAL) arr[base + j] = run;
      run += v[j];
    }
    if (t0 == 255) bsums[blk] = sh[255];
  }
}

// ---------------- K4: scan2 (block 0) + bn_finalize+kqv_bias2 (block 1) ----------------

__global__ __launch_bounds__(256) void scan2_bn(
    unsigned* __restrict__ bsums, int nbk,
    const float* __restrict__ stats,
    const float* __restrict__ gamma, const float* __restrict__ beta,
    float* __restrict__ scale, float* __restrict__ shift,
    const float* __restrict__ b_kqv, const float* __restrict__ W_kqv,
    float* __restrict__ bias2)
{
  int t0 = threadIdx.x;
  if (blockIdx.x == 0) {
    __shared__ unsigned sh[256];
    __shared__ unsigned carry;
    if (t0 == 0) carry = 0;
    __syncthreads();
    for (int chunk = 0; chunk < nbk; chunk += 256) {
      int i = chunk + t0;
      unsigned v = (i < nbk) ? bsums[i] : 0u;
      sh[t0] = v;
      __syncthreads();
      for (int off = 1; off < 256; off <<= 1) {
        unsigned x = (t0 >= off) ? sh[t0 - off] : 0u;
        __syncthreads();
        sh[t0] += x;
        __syncthreads();
      }
      unsigned inc = sh[t0];
      unsigned c = carry;
      __syncthreads();
      if (i < nbk) bsums[i] = c + inc - v;
      if (t0 == 255) carry = c + sh[255];
      __syncthreads();
    }
  } else {
    __shared__ float sshift[192];
    if (t0 < 192) {
      int ty = t0 >> 6, c = t0 & 63;
      float invN = (ty == 0) ? (1.f / NQ) : (ty == 1) ? (1.f / NA) : (1.f / NE);
      float mu = stats[ty * 128 + c] * invN;
      float var = stats[ty * 128 + 64 + c] * invN - mu * mu;
      float rs = rsqrtf(var + 1e-5f);
      float gm = gamma[t0];
      float sc = gm * rs;
      float sf = beta[t0] - gm * mu * rs;
      scale[t0] = sc;
      shift[t0] = sf;
      sshift[t0] = sf;
    }
    __syncthreads();
    for (int idx = t0; idx < 576; idx += 256) {
      int t = idx / 192, n = idx % 192;
      float s = b_kqv[t * 192 + n];
      for (int k = 0; k < 64; ++k)
        s += sshift[t * 64 + k] * W_kqv[(size_t)t * 64 * 192 + k * 192 + n];
      bias2[t * 192 + n] = s;
    }
  }
}

// ---------------- K5: scan3 + wprep_kqv merged ----------------

__global__ __launch_bounds__(256) void scan3_wprep(
    unsigned* __restrict__ arr, const unsigned* __restrict__ bsums,
    unsigned* __restrict__ cursor,
    const float* __restrict__ W_kqv, const float* __restrict__ bias2,
    const float* __restrict__ A_k, const float* __restrict__ A_v,
    const float* __restrict__ scale,
    _Float16* __restrict__ WqT, _Float16* __restrict__ WeT,
    _Float16* __restrict__ WaT, float* __restrict__ bias_big)
{
  int bid = blockIdx.x;
  int t0 = threadIdx.x;
  if (bid < NBLK_SCAN) {
    int base = bid * 1024 + t0 * 4;
    unsigned add = bsums[bid];
#pragma unroll
    for (int j = 0; j < 4; ++j) {
      int idx = base + j;
      if (idx < NT_TOTAL) {
        unsigned r = arr[idx] + add;
        arr[idx] = r;
        cursor[idx] = r;
      }
    }
    return;
  }
  int j = (bid - NBLK_SCAN) * 4 + (t0 >> 6);
  int c = t0 & 63;
  if (j >= 640) return;
  int t, jj, bofs;
  _Float16* W;
  if (j < 192)      { t = 0; jj = j;       W = WqT; bofs = 0; }
  else if (j < 512) { t = 2; jj = j - 192; W = WeT; bofs = 192; }
  else              { t = 1; jj = j - 512; W = WaT; bofs = 512; }
  const float* Wt = W_kqv + (size_t)t * 64 * 192;
  const float* b2 = bias2 + t * 192;
  int mode = 0, rel = 0, sub = 0;
  if (t == 1) { mode = 1; rel = (jj < 64) ? 2 : 3; sub = jj & 63; }
  else if (jj >= 64 && jj < 128) { mode = 1; rel = (t == 0) ? 0 : 1; sub = jj - 64; }
  else if (jj >= 128) {
    mode = 2; sub = (jj - 128) & 63;
    rel = (t == 0) ? 3 : ((jj - 128) >> 6);
  }
  int h = sub >> 5, x = sub & 31;
  float wv, bv;
  if (mode == 0) {
    wv = Wt[(size_t)c * 192 + jj];
    bv = b2[jj];
  } else if (mode == 1) {
    const float* Ar = A_k + ((size_t)rel * 2048 + h * 1024 + x * 32);
    float s = 0.f, sb = 0.f;
    for (int f = 0; f < 32; ++f) {
      float a = Ar[f];
      s = fmaf(a, Wt[(size_t)c * 192 + 64 + h * 32 + f], s);
      sb = fmaf(a, b2[64 + h * 32 + f], sb);
    }
    wv = s; bv = sb;
  } else {
    const float* Ar = A_v + ((size_t)rel * 2048 + h * 1024 + x);
    float s = 0.f, sb = 0.f;
    for (int d = 0; d < 32; ++d) {
      float a = Ar[d * 32];
      s = fmaf(a, Wt[(size_t)c * 192 + 128 + h * 32 + d], s);
      sb = fmaf(a, b2[128 + h * 32 + d], sb);
    }
    wv = s; bv = sb;
  }
  wv *= scale[t * 64 + c];
  W[(size_t)jj * 72 + c] = (_Float16)wv;
  if (c < 8) W[(size_t)jj * 72 + 64 + c] = (_Float16)0.f;
  if (c == 0) bias_big[bofs + jj] = bv;
}

// ---------------- kqv GEMM body (BM=128, 512 thr, direct-A, two-pass 64-row Ts) ----------------

template <int BNT>
__device__ __forceinline__ void kqv_bodyD(
    char* smem,
    const _Float16* __restrict__ Ah,
    const _Float16* __restrict__ WT, const float* __restrict__ bias, int M,
    _Float16* __restrict__ oh, int LDO, int row0, int colbase)
{
  constexpr int KP = 72;
  constexpr int TP = BNT + 8;
  constexpr int NCTW = BNT / 32;     // col tiles per col-wave
  _Float16* Bs = (_Float16*)smem;
  _Float16* Ts = (_Float16*)smem;    // overlay after MFMA (64 rows)
  int tid = threadIdx.x;
  int w = tid >> 6, l = tid & 63;
  int rw = w >> 1, cw = w & 1;       // 4 row-waves x 2 col-waves
  int lr = l & 15, lg = l >> 4;

  // stage B
  {
    const _Float16* wsrc = WT + (size_t)colbase * KP;
    for (int idx = tid; idx < BNT * KP / 8; idx += 512)
      *(half8_t*)&Bs[idx * 8] = *(const half8_t*)&wsrc[(size_t)idx * 8];
  }
  // direct A fragments (rows rw*32 + rt*16 + lr)
  half8_t afrag[2][2];
#pragma unroll
  for (int rt = 0; rt < 2; ++rt) {
    int gr = row0 + rw * 32 + rt * 16 + lr;
    bool ok = gr < M;
#pragma unroll
    for (int ks = 0; ks < 2; ++ks) {
      half8_t h8 = {};
      if (ok) h8 = *(const half8_t*)&Ah[(size_t)gr * 64 + ks * 32 + lg * 8];
      afrag[rt][ks] = h8;
    }
  }
  __syncthreads();   // Bs staged

  f32x4_t acc[2][NCTW] = {};
#pragma unroll
  for (int ks = 0; ks < 2; ++ks) {
#pragma unroll
    for (int ct = 0; ct < NCTW; ++ct) {
      half8_t b = *(const half8_t*)&Bs[(cw * (BNT / 2) + ct * 16 + lr) * KP + ks * 32 + lg * 8];
      acc[0][ct] = __builtin_amdgcn_mfma_f32_16x16x32_f16(afrag[0][ks], b, acc[0][ct], 0, 0, 0);
      acc[1][ct] = __builtin_amdgcn_mfma_f32_16x16x32_f16(afrag[1][ks], b, acc[1][ct], 0, 0, 0);
    }
  }

  float bval[NCTW];
#pragma unroll
  for (int ct = 0; ct < NCTW; ++ct)
    bval[ct] = bias[colbase + cw * (BNT / 2) + ct * 16 + lr];

  __syncthreads();   // all waves done reading Bs -> Ts may overwrite

  // two passes: 64 local rows each (pass rt handles rows rw*32+rt*16+..)
#pragma unroll
  for (int rt = 0; rt < 2; ++rt) {
    int r2base = rw * 16 + lg * 4;   // compacted local row in Ts
#pragma unroll
    for (int ct = 0; ct < NCTW; ++ct) {
      int colL = cw * (BNT / 2) + ct * 16 + lr;
#pragma unroll
      for (int j = 0; j < 4; ++j)
        Ts[(r2base + j) * TP + colL] = (_Float16)(acc[rt][ct][j] + bval[ct]);
    }
    __syncthreads();
    constexpr int C8 = BNT / 8;
    for (int idx = tid; idx < 64 * C8; idx += 512) {
      int r2 = idx / C8, c8 = (idx % C8) * 8;
      int gr = row0 + (r2 >> 4) * 32 + rt * 16 + (r2 & 15);
      if (gr < M)
        *(half8_t*)&oh[(size_t)gr * LDO + colbase + c8] = *(const half8_t*)&Ts[r2 * TP + c8];
    }
    __syncthreads();   // before next pass overwrites Ts
  }
}

// ---------------- K6: kqv GEMMs (direct-A) + scatter LAST, merged (512 threads) ----------------

__global__ __launch_bounds__(512) void kqv_scatter3(
    const _Float16* __restrict__ y_h,
    const _Float16* __restrict__ WqT, const _Float16* __restrict__ WeT,
    const _Float16* __restrict__ WaT, const float* __restrict__ bias_big,
    _Float16* __restrict__ kqvQ, _Float16* __restrict__ kqvE,
    _Float16* __restrict__ kqvA,
    const int* __restrict__ s0, const int* __restrict__ d0,
    const int* __restrict__ s1, const int* __restrict__ d1,
    const int* __restrict__ s2, const int* __restrict__ d2,
    const int* __restrict__ s3, const int* __restrict__ d3,
    unsigned* __restrict__ cursor, unsigned* __restrict__ eidx)
{
  extern __shared__ __align__(16) char smem[];
  int bid = blockIdx.x;
  if (bid < 2 * KQ3_E) {
    int ct = bid / KQ3_E;
    int rb = bid % KQ3_E;
    kqv_bodyD<160>(smem, y_h + (size_t)(NQ + NA) * 64, WeT, bias_big + 192, NE,
                   kqvE, 320, rb * 128, ct * 160);
  } else if (bid < 2 * KQ3_E + 2 * KQ3_Q) {
    int b = bid - 2 * KQ3_E;
    int ct = b / KQ3_Q;
    int rb = b % KQ3_Q;
    kqv_bodyD<96>(smem, y_h, WqT, bias_big, NQ, kqvQ, 192, rb * 128, ct * 96);
  } else if (bid < 2 * KQ3_E + 2 * KQ3_Q + KQ3_A) {
    int b = bid - 2 * KQ3_E - 2 * KQ3_Q;
    kqv_bodyD<128>(smem, y_h + (size_t)NQ * 64, WaT, bias_big + 512, NA,
                   kqvA, 128, b * 128, 0);
  } else {
    // ---- scatter range (appended last; drains under GEMM tail) ----
    int i = (bid - 2 * KQ3_E - 2 * KQ3_Q - KQ3_A) * 512 + threadIdx.x;
    int stride = SCB * 512;
    for (; i < E_TOTAL; i += stride) {
      unsigned pos, pay;
      if (i < E_E2Q) {
        pos = atomicAdd(&cursor[BASE_Q + d0[i]], 1u);
        pay = (unsigned)(s0[i] * 320);
      } else if (i < E_E2Q + E_E2E) {
        int k = i - E_E2Q;
        pos = atomicAdd(&cursor[BASE_E + d1[k]], 1u);
        pay = (unsigned)(s1[k] * 320);
      } else if (i < E_E2Q + E_E2E + E_E2A) {
        int k = i - E_E2Q - E_E2E;
        pos = atomicAdd(&cursor[BASE_A + d2[k]], 1u);
        pay = (unsigned)(s2[k] * 320);
      } else {
        int k = i - E_E2Q - E_E2E - E_E2A;
        pos = atomicAdd(&cursor[BASE_A + d3[k]], 1u);
        pay = (unsigned)(s3[k] * 192) | 0x80000000u;
      }
      eidx[pos] = pay;
    }
  }
}

// ---------------- gather body ----------------

template <int NREL>
__device__ __forceinline__ void gather_body(
    int bidLocal, int nblocks, int N, int nodebase,
    const unsigned* __restrict__ row_start, const unsigned* __restrict__ row_end,
    const unsigned* __restrict__ eidx,
    const _Float16* __restrict__ baseA, int vofA,
    const _Float16* __restrict__ baseB, int vofB,
    const _Float16* __restrict__ qtA, int ldqA,
    const _Float16* __restrict__ qtB, int ldqB,
    const float* __restrict__ prelA, const float* __restrict__ prelB,
    _Float16* __restrict__ agg)
{
  int lane = threadIdx.x & 63;
  int h = lane >> 5, f = lane & 31;
  int idx2 = h * 32 + 2 * (f & 15);
  const float isd = 0.17677669529663687f;
  float pr0 = prelA[h] * isd;
  float pr1 = (NREL == 2) ? prelB[h] * isd : 0.f;

  int wid = (int)(((size_t)bidLocal * 256 + threadIdx.x) >> 6);
  int nw = nblocks * 4;

  int n0 = wid;
  unsigned b0s = 0, b0e = 0, e00 = 0, e01 = 0;
  half2_t q00p = {}, q01p = {};
  if (n0 < N) {
    b0s = row_start[nodebase + n0];
    b0e = row_end[nodebase + n0];
    q00p = *(const half2_t*)&qtA[(size_t)n0 * ldqA + idx2];
    if (NREL == 2) q01p = *(const half2_t*)&qtB[(size_t)n0 * ldqB + idx2];
    e00 = eidx[b0s];
    e01 = eidx[b0s + 1];
  }
  int n1 = n0 + nw;
  unsigned b1s = 0, b1e = 0;
  half2_t q10p = {}, q11p = {};
  if (n0 < N && n1 < N) {
    b1s = row_start[nodebase + n1];
    b1e = row_end[nodebase + n1];
    q10p = *(const half2_t*)&qtA[(size_t)n1 * ldqA + idx2];
    if (NREL == 2) q11p = *(const half2_t*)&qtB[(size_t)n1 * ldqB + idx2];
  }

  while (n0 < N) {
    unsigned e10 = 0, e11 = 0;
    if (n1 < N) {
      e10 = eidx[b1s];
      e11 = eidx[b1s + 1];
    }
    int n2 = n1 + nw;
    unsigned b2s = 0, b2e = 0;
    half2_t q20p = {}, q21p = {};
    if (n2 < N) {
      b2s = row_start[nodebase + n2];
      b2e = row_end[nodebase + n2];
      q20p = *(const half2_t*)&qtA[(size_t)n2 * ldqA + idx2];
      if (NREL == 2) q21p = *(const half2_t*)&qtB[(size_t)n2 * ldqB + idx2];
    }

    float vs = 0.f, ss = 0.f;
    unsigned i = b0s;

    auto do_pair = [&](unsigned p1, unsigned p2) {
      unsigned o1 = p1 & 0x7FFFFFFFu, o2 = p2 & 0x7FFFFFFFu;
      bool r1 = (NREL == 2) && (p1 >> 31);
      bool r2 = (NREL == 2) && (p2 >> 31);
      const _Float16* b1 = (r1 ? baseB : baseA) + o1;
      const _Float16* b2 = (r2 ? baseB : baseA) + o2;
      half2_t k21 = *(const half2_t*)&b1[idx2];
      float v1 = (float)b1[(r1 ? vofB : vofA) + lane];
      half2_t k22 = *(const half2_t*)&b2[idx2];
      float v2 = (float)b2[(r2 ? vofB : vofA) + lane];
      float sa = __builtin_amdgcn_fdot2(k21, r1 ? q01p : q00p, 0.f, false);
      float sb = __builtin_amdgcn_fdot2(k22, r2 ? q01p : q00p, 0.f, false);
#pragma unroll
      for (int off = 1; off <= 8; off <<= 1) {
        sa += __shfl_xor(sa, off, 32);
        sb += __shfl_xor(sb, off, 32);
      }
      float w1 = __expf(sa * (r1 ? pr1 : pr0));
      float w2 = __expf(sb * (r2 ? pr1 : pr0));
      ss += w1 + w2;
      vs = fmaf(w1, v1, vs);
      vs = fmaf(w2, v2, vs);
    };
    auto do_single = [&](unsigned p1) {
      unsigned o1 = p1 & 0x7FFFFFFFu;
      bool r1 = (NREL == 2) && (p1 >> 31);
      const _Float16* b1 = (r1 ? baseB : baseA) + o1;
      half2_t k21 = *(const half2_t*)&b1[idx2];
      float v1 = (float)b1[(r1 ? vofB : vofA) + lane];
      float sa = __builtin_amdgcn_fdot2(k21, r1 ? q01p : q00p, 0.f, false);
#pragma unroll
      for (int off = 1; off <= 8; off <<= 1) sa += __shfl_xor(sa, off, 32);
      float w1 = __expf(sa * (r1 ? pr1 : pr0));
      ss += w1;
      vs = fmaf(w1, v1, vs);
    };

    if (i + 2 <= b0e) { do_pair(e00, e01); i += 2; }
    else if (i < b0e) { do_single(e00); i = b0e; }
    for (; i + 2 <= b0e; i += 2) do_pair(eidx[i], eidx[i + 1]);
    if (i < b0e) do_single(eidx[i]);

    float val = (ss > 0.f) ? vs / ss : 0.f;
    val = fast_gelu(val);
    agg[((size_t)(nodebase + n0)) * 64 + lane] = (_Float16)val;

    n0 = n1; b0s = b1s; b0e = b1e; q00p = q10p; q01p = q11p; e00 = e10; e01 = e11;
    n1 = n2; b1s = b2s; b1e = b2e; q10p = q20p; q11p = q21p;
  }
}

__global__ __launch_bounds__(256) void gather_all(
    const unsigned* __restrict__ row_start, const unsigned* __restrict__ row_end,
    const unsigned* __restrict__ eidx,
    const _Float16* __restrict__ kqvQ, const _Float16* __restrict__ kqvE,
    const _Float16* __restrict__ kqvA,
    const float* __restrict__ p_rel, _Float16* __restrict__ agg)
{
  int bid = blockIdx.x;
  if (bid < GB_Q) {
    gather_body<1>(bid, GB_Q, NQ, BASE_Q, row_start, row_end, eidx,
                   kqvE, 128, kqvE, 128, kqvQ + 64, 192, kqvQ + 64, 192,
                   p_rel + 0, p_rel + 0, agg);
  } else if (bid < GB_Q + GB_E) {
    gather_body<1>(bid - GB_Q, GB_E, NE, BASE_E, row_start, row_end, eidx,
                   kqvE, 192, kqvE, 192, kqvE + 64, 320, kqvE + 64, 320,
                   p_rel + 2, p_rel + 2, agg);
  } else {
    gather_body<2>(bid - GB_Q - GB_E, GB_A, NA, BASE_A, row_start, row_end, eidx,
                   kqvE, 256, kqvQ, 128, kqvA, 128, kqvA + 64, 128,
                   p_rel + 4, p_rel + 6, agg);
  }
}

// ---------------- K8: merged out-proj ----------------

__global__ __launch_bounds__(256) void gemm_out_all(
    const _Float16* __restrict__ agg_h, const _Float16* __restrict__ y_h,
    const _Float16* __restrict__ WoutT, const float* __restrict__ b_out,
    const float* __restrict__ scale, const float* __restrict__ shift,
    const float* __restrict__ skip, float* __restrict__ zout)
{
  __shared__ _Float16 Bs[64 * 72];
  int bid = blockIdx.x;
  int t, row0, M;
  size_t nodeoff;
  if (bid < TOP_Q)              { t = 0; row0 = bid * 128;              M = NQ; nodeoff = 0; }
  else if (bid < TOP_Q + TOP_A) { t = 1; row0 = (bid - TOP_Q) * 128;    M = NA; nodeoff = NQ; }
  else                          { t = 2; row0 = (bid - TOP_Q - TOP_A) * 128; M = NE; nodeoff = NQ + NA; }
  const _Float16* Ah = agg_h + nodeoff * 64;
  const _Float16* resh = y_h + nodeoff * 64;
  float* Cf = zout + nodeoff * 64;
  const _Float16* WT = WoutT + (size_t)t * 64 * 72;
  const float* bias = b_out + t * 64;
  const float* rsc = scale + t * 64;
  const float* rsh = shift + t * 64;

  int tid = threadIdx.x;
  int w = tid >> 6, l = tid & 63;
  int lr = l & 15, lg = l >> 4;

  for (int idx = tid; idx < 64 * 72 / 8; idx += 256)
    *(half8_t*)&Bs[idx * 8] = *(const half8_t*)&WT[(size_t)idx * 8];

  half8_t afrag[2][2];
#pragma unroll
  for (int rt = 0; rt < 2; ++rt) {
    int gr = row0 + w * 32 + rt * 16 + lr;
    bool ok = gr < M;
#pragma unroll
    for (int ks = 0; ks < 2; ++ks) {
      half8_t h8 = {};
      if (ok) h8 = *(const half8_t*)&Ah[(size_t)gr * 64 + ks * 32 + lg * 8];
      afrag[rt][ks] = h8;
    }
  }
  __syncthreads();

  f32x4_t acc[2][4] = {};
#pragma unroll
  for (int ks = 0; ks < 2; ++ks) {
#pragma unroll
    for (int ct = 0; ct < 4; ++ct) {
      half8_t b = *(const half8_t*)&Bs[(ct * 16 + lr) * 72 + ks * 32 + lg * 8];
      acc[0][ct] = __builtin_amdgcn_mfma_f32_16x16x32_f16(afrag[0][ks], b, acc[0][ct], 0, 0, 0);
      acc[1][ct] = __builtin_amdgcn_mfma_f32_16x16x32_f16(afrag[1][ks], b, acc[1][ct], 0, 0, 0);
    }
  }

  float g = 1.f / (1.f + __expf(-skip[t]));
  float gb = 1.f - g;
#pragma unroll
  for (int rt = 0; rt < 2; ++rt) {
    int rbase = row0 + w * 32 + rt * 16 + lg * 4;
#pragma unroll
    for (int ct = 0; ct < 4; ++ct) {
      int col = ct * 16 + lr;
      float bval = bias[col];
#pragma unroll
      for (int j = 0; j < 4; ++j) {
        int row = rbase + j;
        if (row >= M) continue;
        float val = acc[rt][ct][j] + bval;
        float rv = (float)resh[(size_t)row * 64 + col];
        Cf[(size_t)row * 64 + col] = g * val + gb * (rsc[col] * rv + rsh[col]);
      }
    }
  }
}

// ---------------- K9: merged predictions ----------------

__global__ void pred_all(const int* __restrict__ pos, const int* __restrict__ neg,
                         const float* __restrict__ zq, const float* __restrict__ za,
                         float* __restrict__ outp) {
  int i = blockIdx.x * blockDim.x + threadIdx.x;
  if (i >= N_POS + N_NEG) return;
  int k; const int* qi; const int* ai; float* o;
  if (i < N_POS) { k = i; qi = pos; ai = pos + N_POS; o = outp; }
  else { k = i - N_POS; qi = neg; ai = neg + N_NEG; o = outp + N_POS; }
  const float4* a = (const float4*)(zq + (size_t)qi[k] * 64);
  const float4* b = (const float4*)(za + (size_t)ai[k] * 64);
  float ssum = 0.f;
#pragma unroll
  for (int j = 0; j < 16; ++j) {
    float4 x = a[j], y = b[j];
    ssum += x.x * y.x + x.y * y.y + x.z * y.z + x.w * y.w;
  }
  o[k] = ssum;
}

// ---------------- host launch ----------------

extern "C" void kernel_launch(void* const* d_in, const int* in_sizes, int n_in,
                              void* d_out, int out_size, void* d_ws, size_t ws_size,
                              hipStream_t stream) {
  const float* xq = (const float*)d_in[0];
  const float* xa = (const float*)d_in[1];
  const float* xe = (const float*)d_in[2];
  const int* e_e2q = (const int*)d_in[3];
  const int* e_e2e = (const int*)d_in[4];
  const int* e_e2a = (const int*)d_in[5];
  const int* e_q2a = (const int*)d_in[6];
  const int* pos_idx = (const int*)d_in[7];
  const int* neg_idx = (const int*)d_in[8];
  const float* W_in = (const float*)d_in[9];
  const float* b_in = (const float*)d_in[10];
  const float* bn_gamma = (const float*)d_in[11];
  const float* bn_beta = (const float*)d_in[12];
  const float* W_kqv = (const float*)d_in[13];
  const float* b_kqv = (const float*)d_in[14];
  const float* A_k = (const float*)d_in[15];
  const float* A_v = (const float*)d_in[16];
  const float* p_rel = (const float*)d_in[17];
  const float* W_out = (const float*)d_in[18];
  const float* b_out = (const float*)d_in[19];
  const float* skip = (const float*)d_in[20];
  float* out = (float*)d_out;

  float* ws = (float*)d_ws;
  size_t off = 0;
  _Float16* y_h = (_Float16*)(ws + off);    off += (size_t)NT_TOTAL * 32;
  _Float16* kqvQ = (_Float16*)(ws + off);   off += (size_t)NQ * 96;
  _Float16* kqvE = (_Float16*)(ws + off);   off += (size_t)NE * 160;
  _Float16* kqvA = (_Float16*)(ws + off);   off += (size_t)NA * 64;
  _Float16* agg_h = (_Float16*)(ws + off);  off += (size_t)NT_TOTAL * 32;
  float* stats = ws + off;                  off += 384;
  float* scale = ws + off;                  off += 192;
  float* shift = ws + off;                  off += 192;
  float* bias2 = ws + off;                  off += 576;
  float* bias_big = ws + off;               off += 640;
  _Float16* WqT = (_Float16*)(ws + off);    off += 192 * 72 / 2;
  _Float16* WeT = (_Float16*)(ws + off);    off += 320 * 72 / 2;
  _Float16* WaT = (_Float16*)(ws + off);    off += 128 * 72 / 2;
  _Float16* WinT = (_Float16*)(ws + off);   off += 3 * 64 * 136 / 2;
  _Float16* WoutT = (_Float16*)(ws + off);  off += 3 * 64 * 72 / 2;
  float* bstats = ws + off;                 off += (size_t)GIN_TOT * 128;
  unsigned* row_start = (unsigned*)(ws + off); off += NT_TOTAL;
  unsigned* cursor = (unsigned*)(ws + off);    off += NT_TOTAL;
  unsigned* bsums = (unsigned*)(ws + off);     off += 1024;
  unsigned* eidx = (unsigned*)(ws + off);      off += E_TOTAL + 8;

  float* zq_out = out + (N_POS + N_NEG);

  prep_misc<<<dim3(512), dim3(256), 0, stream>>>((float*)row_start, W_in, WinT, W_out, WoutT);

  inproj_hist_all<<<dim3(GIN_TOT + HB), dim3(256), 0, stream>>>(
      xq, xa, xe, WinT, b_in, y_h, bstats,
      e_e2q + E_E2Q, e_e2e + E_E2E, e_e2a + E_E2A, e_q2a + E_Q2A, row_start);

  reduce_scan1<<<dim3(384 + NBLK_SCAN), dim3(256), 0, stream>>>(
      bstats, stats, row_start, bsums);

  scan2_bn<<<dim3(2), dim3(256), 0, stream>>>(
      bsums, NBLK_SCAN, stats, bn_gamma, bn_beta, scale, shift, b_kqv, W_kqv, bias2);

  scan3_wprep<<<dim3(NBLK_SCAN + 160), dim3(256), 0, stream>>>(
      row_start, bsums, cursor, W_kqv, bias2, A_k, A_v, scale,
      WqT, WeT, WaT, bias_big);

  kqv_scatter3<<<dim3(KS3_TOT), dim3(512), SMEM_KQV3, stream>>>(
      y_h, WqT, WeT, WaT, bias_big, kqvQ, kqvE, kqvA,
      e_e2q, e_e2q + E_E2Q, e_e2e, e_e2e + E_E2E,
      e_e2a, e_e2a + E_E2A, e_q2a, e_q2a + E_Q2A, cursor, eidx);

  gather_all<<<dim3(GB_Q + GB_E + GB_A), dim3(256), 0, stream>>>(
      row_start, cursor, eidx, kqvQ, kqvE, kqvA, p_rel, agg_h);

  gemm_out_all<<<dim3(TOP_Q + TOP_A + TOP_E), dim3(256), 0, stream>>>(
      agg_h, y_h, WoutT, b_out, scale, shift, skip, zq_out);

  pred_all<<<dim3(CDIV(N_POS + N_NEG, 256)), dim3(256), 0, stream>>>(
      pos_idx, neg_idx, zq_out, zq_out + (size_t)NQ * 64, out);
}

// Round 24
// 615.808 us; speedup vs baseline: 1.0878x; 1.0407x over previous
//
#include <hip/hip_runtime.h>
#include <hip/hip_bf16.h>
#include <hip/hip_fp16.h>
#include <math.h>

#define NQ 8192
#define NA 32768
#define NE 500000
#define F_IN 128
#define E_E2Q 131072
#define E_E2E 800000
#define E_E2A 262144
#define E_Q2A 32768
#define N_POS 8192
#define N_NEG 24576

#define NT_TOTAL (NQ + NA + NE)
#define E_TOTAL (E_E2Q + E_E2E + E_E2A + E_Q2A)
#define NBLK_SCAN ((NT_TOTAL + 1023) / 1024)         // 529
#define CDIV(a, b) (((a) + (b) - 1) / (b))

#define BASE_Q 0
#define BASE_A NQ
#define BASE_E (NQ + NA)

// in-proj block counts (1 block per bstats row)
#define GIN_Q 128
#define GIN_A 512
#define GIN_E 768
#define GIN_TOT (GIN_Q + GIN_A + GIN_E)   // 1408
#define HB 1024                            // hist blocks appended

// gather grid
#define GB_Q 2048
#define GB_E 4096
#define GB_A 8192

// out-proj grid
#define TOP_Q 64
#define TOP_A 256
#define TOP_E 3907

// kqv_scatter4: persistent grid-stride GEMM ranges, scatter LAST
#define KQ3_E 3907      // row tiles of 128; x2 col tiles (BNT=160)
#define KQ3_Q 64        // x2 col tiles (BNT=96)
#define KQ3_A 256       // single tile (BNT=128)
#define KQE_B 2048
#define KQQ_B 32
#define KQA_B 64
#define SCB 1024
#define KS4_TOT (KQE_B + KQQ_B + KQA_B + SCB)   // 3168
#define SMEM_KQV 23040   // max(Bs 160*72*2, Ts 64*168*2)

typedef _Float16 half8_t __attribute__((ext_vector_type(8)));
typedef _Float16 half2_t __attribute__((ext_vector_type(2)));
typedef float f32x4_t __attribute__((ext_vector_type(4)));

__device__ inline void load_lds16(const void* g, void* l) {
  __builtin_amdgcn_global_load_lds((const __attribute__((address_space(1))) void*)g,
                                   (__attribute__((address_space(3))) void*)l, 16, 0, 0);
}

__device__ inline float fast_gelu(float v) {
  float u = 1.5957691216057308f * fmaf(0.044715f * v * v, v, v);
  return v / (1.f + __expf(-u));
}

// ---------------- K1: prep (zero row_start + WinT + WoutT) ----------------

__global__ __launch_bounds__(256) void prep_misc(
    float* __restrict__ row_start_f,
    const float* __restrict__ W_in, _Float16* __restrict__ WinT,
    const float* __restrict__ W_out, _Float16* __restrict__ WoutT)
{
  int bid = blockIdx.x;
  if (bid < 128) {
    size_t i = (size_t)bid * 256 + threadIdx.x;
    size_t stride = (size_t)128 * 256;
    for (; i < NT_TOTAL; i += stride) row_start_f[i] = 0.f;
  } else if (bid < 320) {
    int b = bid - 128;
    int t = b >> 6, n = b & 63, k = threadIdx.x;
    if (k < 136) {
      float v = (k < 128) ? W_in[(size_t)t * 128 * 64 + (size_t)k * 64 + n] : 0.f;
      WinT[((size_t)t * 64 + n) * 136 + k] = (_Float16)v;
    }
  } else {
    int b = bid - 320;
    int t = b >> 6, n = b & 63, k = threadIdx.x;
    if (k < 72) {
      float v = (k < 64) ? W_out[(size_t)t * 64 * 64 + (size_t)k * 64 + n] : 0.f;
      WoutT[((size_t)t * 64 + n) * 72 + k] = (_Float16)v;
    }
  }
}

// ---------------- K2: in-proj (pipelined LDS stage) + hist, block-range merged ----------------

__global__ __launch_bounds__(256) void inproj_hist_all(
    const float* __restrict__ xq, const float* __restrict__ xa,
    const float* __restrict__ xe,
    const _Float16* __restrict__ WinT, const float* __restrict__ b_in,
    _Float16* __restrict__ y_h, float* __restrict__ bstats,
    const int* __restrict__ hd0, const int* __restrict__ hd1,
    const int* __restrict__ hd2, const int* __restrict__ hd3,
    unsigned* __restrict__ cnt)
{
  __shared__ __align__(16) float bufA[32 * 128];
  __shared__ __align__(16) float bufB[32 * 128];
  __shared__ _Float16 Bs[64 * 136];
  __shared__ float s1[64], s2[64];

  int bid = blockIdx.x;
  if (bid >= GIN_TOT) {
    int i = (bid - GIN_TOT) * 256 + threadIdx.x;
    int stride = HB * 256;
    for (; i < E_TOTAL; i += stride) {
      if (i < E_E2Q) atomicAdd(&cnt[BASE_Q + hd0[i]], 1u);
      else if (i < E_E2Q + E_E2E) atomicAdd(&cnt[BASE_E + hd1[i - E_E2Q]], 1u);
      else if (i < E_E2Q + E_E2E + E_E2A)
        atomicAdd(&cnt[BASE_A + hd2[i - E_E2Q - E_E2E]], 1u);
      else atomicAdd(&cnt[BASE_A + hd3[i - E_E2Q - E_E2E - E_E2A]], 1u);
    }
    return;
  }

  int t, lb, nb;
  const float* Af;
  _Float16* oh;
  if (bid < GIN_Q)              { t = 0; lb = bid;                 nb = GIN_Q; Af = xq; oh = y_h; }
  else if (bid < GIN_Q + GIN_A) { t = 1; lb = bid - GIN_Q;         nb = GIN_A; Af = xa; oh = y_h + (size_t)NQ * 64; }
  else                          { t = 2; lb = bid - GIN_Q - GIN_A; nb = GIN_E; Af = xe; oh = y_h + (size_t)(NQ + NA) * 64; }
  int M = (t == 0) ? NQ : (t == 1) ? NA : NE;
  int nh = CDIV(M, 32);
  const _Float16* WT = WinT + (size_t)t * 64 * 136;
  const float* bias = b_in + t * 64;

  int tid = threadIdx.x, w = tid >> 6, l = tid & 63;
  int lr = l & 15, lg = l >> 4;
  int wrow = (w & 1) * 16;
  int wcol = (w >> 1) * 32;

  for (int idx = tid; idx < 64 * 136 / 8; idx += 256)
    *(half8_t*)&Bs[idx * 8] = *(const half8_t*)&WT[(size_t)idx * 8];
  if (tid < 64) { s1[tid] = 0.f; s2[tid] = 0.f; }

  float bval[2];
  bval[0] = bias[wcol + lr];
  bval[1] = bias[wcol + 16 + lr];
  float ps1[2] = {}, ps2[2] = {};

  auto stage = [&](float* buf, int h) {
    const char* srcbase = (const char*)Af + (size_t)h * 32 * 512;
    int rowlim = M - h * 32;
#pragma unroll
    for (int r = 0; r < 4; ++r) {
      int unit = r * 4 + w;
      char* ldst = (char*)buf + unit * 1024;
      int p = unit * 1024 + l * 16;
      int row = p >> 9;
      const char* src = (row < rowlim) ? srcbase + (size_t)row * 512 + (p & 511)
                                       : srcbase;
      load_lds16(src, ldst);
    }
  };

  int h0 = lb;
  if (h0 < nh) stage(bufA, h0);
  __syncthreads();

  float* cur = bufA;
  float* nxt = bufB;
  for (int h = h0; h < nh; h += nb) {
    int h2 = h + nb;
    bool more = h2 < nh;
    if (more) {
      stage(nxt, h2);
      asm volatile("s_waitcnt vmcnt(4)" ::: "memory");
    } else {
      asm volatile("s_waitcnt vmcnt(0)" ::: "memory");
    }
    __builtin_amdgcn_sched_barrier(0);
    __builtin_amdgcn_s_barrier();

    f32x4_t acc[2] = {};
#pragma unroll
    for (int ks = 0; ks < 4; ++ks) {
      const float4* pa = (const float4*)((const char*)cur +
                          (wrow + lr) * 512 + ks * 128 + lg * 32);
      float4 x0 = pa[0], x1 = pa[1];
      half8_t a0 = {(_Float16)x0.x, (_Float16)x0.y, (_Float16)x0.z, (_Float16)x0.w,
                    (_Float16)x1.x, (_Float16)x1.y, (_Float16)x1.z, (_Float16)x1.w};
#pragma unroll
      for (int ct = 0; ct < 2; ++ct) {
        half8_t b = *(const half8_t*)&Bs[(wcol + ct * 16 + lr) * 136 + ks * 32 + lg * 8];
        acc[ct] = __builtin_amdgcn_mfma_f32_16x16x32_f16(a0, b, acc[ct], 0, 0, 0);
      }
    }
    int rbase = h * 32 + wrow + lg * 4;
#pragma unroll
    for (int ct = 0; ct < 2; ++ct) {
      int col = wcol + ct * 16 + lr;
#pragma unroll
      for (int j = 0; j < 4; ++j) {
        int row = rbase + j;
        if (row >= M) continue;
        float val = fmaxf(acc[ct][j] + bval[ct], 0.f);
        oh[(size_t)row * 64 + col] = (_Float16)val;
        ps1[ct] += val;
        ps2[ct] += val * val;
      }
    }
    __builtin_amdgcn_s_barrier();
    float* tmp = cur; cur = nxt; nxt = tmp;
  }

#pragma unroll
  for (int ct = 0; ct < 2; ++ct) {
    int col = wcol + ct * 16 + lr;
    atomicAdd(&s1[col], ps1[ct]);
    atomicAdd(&s2[col], ps2[ct]);
  }
  __syncthreads();
  if (tid < 64) {
    bstats[(size_t)blockIdx.x * 128 + tid] = s1[tid];
    bstats[(size_t)blockIdx.x * 128 + 64 + tid] = s2[tid];
  }
}

// ---------------- K3: stats_reduce + scan1 merged ----------------

__global__ __launch_bounds__(256) void reduce_scan1(
    const float* __restrict__ bstats, float* __restrict__ stats,
    unsigned* __restrict__ arr, unsigned* __restrict__ bsums)
{
  __shared__ __align__(16) char shbuf[1024];
  int bid = blockIdx.x;
  int t0 = threadIdx.x;
  if (bid < 384) {
    float* sh = (float*)shbuf;
    int t = bid >> 7, c = bid & 127;
    int nb = (t == 0) ? GIN_Q : (t == 1) ? GIN_A : GIN_E;
    int base = (t == 0) ? 0 : (t == 1) ? GIN_Q : (GIN_Q + GIN_A);
    float s = 0.f;
    for (int i = t0; i < nb; i += 256)
      s += bstats[(size_t)(base + i) * 128 + c];
    sh[t0] = s;
    __syncthreads();
    for (int off2 = 128; off2 > 0; off2 >>= 1) {
      if (t0 < off2) sh[t0] += sh[t0 + off2];
      __syncthreads();
    }
    if (t0 == 0) stats[t * 128 + c] = sh[0];
  } else {
    unsigned* sh = (unsigned*)shbuf;
    int blk = bid - 384;
    int base = blk * 1024 + t0 * 4;
    unsigned v[4];
    unsigned s = 0;
#pragma unroll
    for (int j = 0; j < 4; ++j) {
      v[j] = (base + j < NT_TOTAL) ? arr[base + j] : 0u;
      s += v[j];
    }
    sh[t0] = s;
    __syncthreads();
    for (int off = 1; off < 256; off <<= 1) {
      unsigned x = (t0 >= off) ? sh[t0 - off] : 0u;
      __syncthreads();
      sh[t0] += x;
      __syncthreads();
    }
    unsigned run = sh[t0] - s;
#pragma unroll
    for (int j = 0; j < 4; ++j) {
      if (base + j < NT_TOTAL) arr[base + j] = run;
      run += v[j];
    }
    if (t0 == 255) bsums[blk] = sh[255];
  }
}

// ---------------- K4: scan2 (block 0) + bn_finalize+kqv_bias2 (block 1) ----------------

__global__ __launch_bounds__(256) void scan2_bn(
    unsigned* __restrict__ bsums, int nbk,
    const float* __restrict__ stats,
    const float* __restrict__ gamma, const float* __restrict__ beta,
    float* __restrict__ scale, float* __restrict__ shift,
    const float* __restrict__ b_kqv, const float* __restrict__ W_kqv,
    float* __restrict__ bias2)
{
  int t0 = threadIdx.x;
  if (blockIdx.x == 0) {
    __shared__ unsigned sh[256];
    __shared__ unsigned carry;
    if (t0 == 0) carry = 0;
    __syncthreads();
    for (int chunk = 0; chunk < nbk; chunk += 256) {
      int i = chunk + t0;
      unsigned v = (i < nbk) ? bsums[i] : 0u;
      sh[t0] = v;
      __syncthreads();
      for (int off = 1; off < 256; off <<= 1) {
        unsigned x = (t0 >= off) ? sh[t0 - off] : 0u;
        __syncthreads();
        sh[t0] += x;
        __syncthreads();
      }
      unsigned inc = sh[t0];
      unsigned c = carry;
      __syncthreads();
      if (i < nbk) bsums[i] = c + inc - v;
      if (t0 == 255) carry = c + sh[255];
      __syncthreads();
    }
  } else {
    __shared__ float sshift[192];
    if (t0 < 192) {
      int ty = t0 >> 6, c = t0 & 63;
      float invN = (ty == 0) ? (1.f / NQ) : (ty == 1) ? (1.f / NA) : (1.f / NE);
      float mu = stats[ty * 128 + c] * invN;
      float var = stats[ty * 128 + 64 + c] * invN - mu * mu;
      float rs = rsqrtf(var + 1e-5f);
      float gm = gamma[t0];
      float sc = gm * rs;
      float sf = beta[t0] - gm * mu * rs;
      scale[t0] = sc;
      shift[t0] = sf;
      sshift[t0] = sf;
    }
    __syncthreads();
    for (int idx = t0; idx < 576; idx += 256) {
      int t = idx / 192, n = idx % 192;
      float s = b_kqv[t * 192 + n];
      for (int k = 0; k < 64; ++k)
        s += sshift[t * 64 + k] * W_kqv[(size_t)t * 64 * 192 + k * 192 + n];
      bias2[t * 192 + n] = s;
    }
  }
}

// ---------------- K5: scan3 + wprep_kqv merged ----------------

__global__ __launch_bounds__(256) void scan3_wprep(
    unsigned* __restrict__ arr, const unsigned* __restrict__ bsums,
    unsigned* __restrict__ cursor,
    const float* __restrict__ W_kqv, const float* __restrict__ bias2,
    const float* __restrict__ A_k, const float* __restrict__ A_v,
    const float* __restrict__ scale,
    _Float16* __restrict__ WqT, _Float16* __restrict__ WeT,
    _Float16* __restrict__ WaT, float* __restrict__ bias_big)
{
  int bid = blockIdx.x;
  int t0 = threadIdx.x;
  if (bid < NBLK_SCAN) {
    int base = bid * 1024 + t0 * 4;
    unsigned add = bsums[bid];
#pragma unroll
    for (int j = 0; j < 4; ++j) {
      int idx = base + j;
      if (idx < NT_TOTAL) {
        unsigned r = arr[idx] + add;
        arr[idx] = r;
        cursor[idx] = r;
      }
    }
    return;
  }
  int j = (bid - NBLK_SCAN) * 4 + (t0 >> 6);
  int c = t0 & 63;
  if (j >= 640) return;
  int t, jj, bofs;
  _Float16* W;
  if (j < 192)      { t = 0; jj = j;       W = WqT; bofs = 0; }
  else if (j < 512) { t = 2; jj = j - 192; W = WeT; bofs = 192; }
  else              { t = 1; jj = j - 512; W = WaT; bofs = 512; }
  const float* Wt = W_kqv + (size_t)t * 64 * 192;
  const float* b2 = bias2 + t * 192;
  int mode = 0, rel = 0, sub = 0;
  if (t == 1) { mode = 1; rel = (jj < 64) ? 2 : 3; sub = jj & 63; }
  else if (jj >= 64 && jj < 128) { mode = 1; rel = (t == 0) ? 0 : 1; sub = jj - 64; }
  else if (jj >= 128) {
    mode = 2; sub = (jj - 128) & 63;
    rel = (t == 0) ? 3 : ((jj - 128) >> 6);
  }
  int h = sub >> 5, x = sub & 31;
  float wv, bv;
  if (mode == 0) {
    wv = Wt[(size_t)c * 192 + jj];
    bv = b2[jj];
  } else if (mode == 1) {
    const float* Ar = A_k + ((size_t)rel * 2048 + h * 1024 + x * 32);
    float s = 0.f, sb = 0.f;
    for (int f = 0; f < 32; ++f) {
      float a = Ar[f];
      s = fmaf(a, Wt[(size_t)c * 192 + 64 + h * 32 + f], s);
      sb = fmaf(a, b2[64 + h * 32 + f], sb);
    }
    wv = s; bv = sb;
  } else {
    const float* Ar = A_v + ((size_t)rel * 2048 + h * 1024 + x);
    float s = 0.f, sb = 0.f;
    for (int d = 0; d < 32; ++d) {
      float a = Ar[d * 32];
      s = fmaf(a, Wt[(size_t)c * 192 + 128 + h * 32 + d], s);
      sb = fmaf(a, b2[128 + h * 32 + d], sb);
    }
    wv = s; bv = sb;
  }
  wv *= scale[t * 64 + c];
  W[(size_t)jj * 72 + c] = (_Float16)wv;
  if (c < 8) W[(size_t)jj * 72 + 64 + c] = (_Float16)0.f;
  if (c == 0) bias_big[bofs + jj] = bv;
}

// ---------------- kqv GEMM body (BM=128, 512 thr, direct-A, two-pass 64-row Ts) ----------------

template <int BNT>
__device__ __forceinline__ void kqv_bodyD(
    char* smem,
    const _Float16* __restrict__ Ah,
    const _Float16* __restrict__ WT, const float* __restrict__ bias, int M,
    _Float16* __restrict__ oh, int LDO, int row0, int colbase)
{
  constexpr int KP = 72;
  constexpr int TP = BNT + 8;
  constexpr int NCTW = BNT / 32;     // col tiles per col-wave
  _Float16* Bs = (_Float16*)smem;
  _Float16* Ts = (_Float16*)smem;    // overlay after MFMA (64 rows)
  int tid = threadIdx.x;
  int w = tid >> 6, l = tid & 63;
  int rw = w >> 1, cw = w & 1;       // 4 row-waves x 2 col-waves
  int lr = l & 15, lg = l >> 4;

  // stage B
  {
    const _Float16* wsrc = WT + (size_t)colbase * KP;
    for (int idx = tid; idx < BNT * KP / 8; idx += 512)
      *(half8_t*)&Bs[idx * 8] = *(const half8_t*)&wsrc[(size_t)idx * 8];
  }
  // direct A fragments (rows rw*32 + rt*16 + lr)
  half8_t afrag[2][2];
#pragma unroll
  for (int rt = 0; rt < 2; ++rt) {
    int gr = row0 + rw * 32 + rt * 16 + lr;
    bool ok = gr < M;
#pragma unroll
    for (int ks = 0; ks < 2; ++ks) {
      half8_t h8 = {};
      if (ok) h8 = *(const half8_t*)&Ah[(size_t)gr * 64 + ks * 32 + lg * 8];
      afrag[rt][ks] = h8;
    }
  }
  __syncthreads();   // Bs staged

  f32x4_t acc[2][NCTW] = {};
#pragma unroll
  for (int ks = 0; ks < 2; ++ks) {
#pragma unroll
    for (int ct = 0; ct < NCTW; ++ct) {
      half8_t b = *(const half8_t*)&Bs[(cw * (BNT / 2) + ct * 16 + lr) * KP + ks * 32 + lg * 8];
      acc[0][ct] = __builtin_amdgcn_mfma_f32_16x16x32_f16(afrag[0][ks], b, acc[0][ct], 0, 0, 0);
      acc[1][ct] = __builtin_amdgcn_mfma_f32_16x16x32_f16(afrag[1][ks], b, acc[1][ct], 0, 0, 0);
    }
  }

  float bval[NCTW];
#pragma unroll
  for (int ct = 0; ct < NCTW; ++ct)
    bval[ct] = bias[colbase + cw * (BNT / 2) + ct * 16 + lr];

  __syncthreads();   // all waves done reading Bs -> Ts may overwrite

  // two passes: 64 local rows each (pass rt handles rows rw*32+rt*16+..)
#pragma unroll
  for (int rt = 0; rt < 2; ++rt) {
    int r2base = rw * 16 + lg * 4;   // compacted local row in Ts
#pragma unroll
    for (int ct = 0; ct < NCTW; ++ct) {
      int colL = cw * (BNT / 2) + ct * 16 + lr;
#pragma unroll
      for (int j = 0; j < 4; ++j)
        Ts[(r2base + j) * TP + colL] = (_Float16)(acc[rt][ct][j] + bval[ct]);
    }
    __syncthreads();
    constexpr int C8 = BNT / 8;
    for (int idx = tid; idx < 64 * C8; idx += 512) {
      int r2 = idx / C8, c8 = (idx % C8) * 8;
      int gr = row0 + (r2 >> 4) * 32 + rt * 16 + (r2 & 15);
      if (gr < M)
        *(half8_t*)&oh[(size_t)gr * LDO + colbase + c8] = *(const half8_t*)&Ts[r2 * TP + c8];
    }
    __syncthreads();   // before next pass (or next tile) overwrites Ts
  }
}

// ---------------- K6: persistent kqv GEMMs + scatter LAST (512 threads) ----------------

__global__ __launch_bounds__(512) void kqv_scatter4(
    const _Float16* __restrict__ y_h,
    const _Float16* __restrict__ WqT, const _Float16* __restrict__ WeT,
    const _Float16* __restrict__ WaT, const float* __restrict__ bias_big,
    _Float16* __restrict__ kqvQ, _Float16* __restrict__ kqvE,
    _Float16* __restrict__ kqvA,
    const int* __restrict__ s0, const int* __restrict__ d0,
    const int* __restrict__ s1, const int* __restrict__ d1,
    const int* __restrict__ s2, const int* __restrict__ d2,
    const int* __restrict__ s3, const int* __restrict__ d3,
    unsigned* __restrict__ cursor, unsigned* __restrict__ eidx)
{
  extern __shared__ __align__(16) char smem[];
  int bid = blockIdx.x;
  if (bid < KQE_B) {
    const _Float16* Ae = y_h + (size_t)(NQ + NA) * 64;
    for (int tile = bid; tile < 2 * KQ3_E; tile += KQE_B) {
      int ct = tile / KQ3_E;
      int rb = tile % KQ3_E;
      kqv_bodyD<160>(smem, Ae, WeT, bias_big + 192, NE, kqvE, 320, rb * 128, ct * 160);
    }
  } else if (bid < KQE_B + KQQ_B) {
    int lb = bid - KQE_B;
    for (int tile = lb; tile < 2 * KQ3_Q; tile += KQQ_B) {
      int ct = tile / KQ3_Q;
      int rb = tile % KQ3_Q;
      kqv_bodyD<96>(smem, y_h, WqT, bias_big, NQ, kqvQ, 192, rb * 128, ct * 96);
    }
  } else if (bid < KQE_B + KQQ_B + KQA_B) {
    int lb = bid - KQE_B - KQQ_B;
    const _Float16* Aa = y_h + (size_t)NQ * 64;
    for (int tile = lb; tile < KQ3_A; tile += KQA_B) {
      kqv_bodyD<128>(smem, Aa, WaT, bias_big + 512, NA, kqvA, 128, tile * 128, 0);
    }
  } else {
    // ---- scatter range (appended last; drains under GEMM tail) ----
    int i = (bid - KQE_B - KQQ_B - KQA_B) * 512 + threadIdx.x;
    int stride = SCB * 512;
    for (; i < E_TOTAL; i += stride) {
      unsigned pos, pay;
      if (i < E_E2Q) {
        pos = atomicAdd(&cursor[BASE_Q + d0[i]], 1u);
        pay = (unsigned)(s0[i] * 320);
      } else if (i < E_E2Q + E_E2E) {
        int k = i - E_E2Q;
        pos = atomicAdd(&cursor[BASE_E + d1[k]], 1u);
        pay = (unsigned)(s1[k] * 320);
      } else if (i < E_E2Q + E_E2E + E_E2A) {
        int k = i - E_E2Q - E_E2E;
        pos = atomicAdd(&cursor[BASE_A + d2[k]], 1u);
        pay = (unsigned)(s2[k] * 320);
      } else {
        int k = i - E_E2Q - E_E2E - E_E2A;
        pos = atomicAdd(&cursor[BASE_A + d3[k]], 1u);
        pay = (unsigned)(s3[k] * 192) | 0x80000000u;
      }
      eidx[pos] = pay;
    }
  }
}

// ---------------- gather body ----------------

template <int NREL>
__device__ __forceinline__ void gather_body(
    int bidLocal, int nblocks, int N, int nodebase,
    const unsigned* __restrict__ row_start, const unsigned* __restrict__ row_end,
    const unsigned* __restrict__ eidx,
    const _Float16* __restrict__ baseA, int vofA,
    const _Float16* __restrict__ baseB, int vofB,
    const _Float16* __restrict__ qtA, int ldqA,
    const _Float16* __restrict__ qtB, int ldqB,
    const float* __restrict__ prelA, const float* __restrict__ prelB,
    _Float16* __restrict__ agg)
{
  int lane = threadIdx.x & 63;
  int h = lane >> 5, f = lane & 31;
  int idx2 = h * 32 + 2 * (f & 15);
  const float isd = 0.17677669529663687f;
  float pr0 = prelA[h] * isd;
  float pr1 = (NREL == 2) ? prelB[h] * isd : 0.f;

  int wid = (int)(((size_t)bidLocal * 256 + threadIdx.x) >> 6);
  int nw = nblocks * 4;

  int n0 = wid;
  unsigned b0s = 0, b0e = 0, e00 = 0, e01 = 0;
  half2_t q00p = {}, q01p = {};
  if (n0 < N) {
    b0s = row_start[nodebase + n0];
    b0e = row_end[nodebase + n0];
    q00p = *(const half2_t*)&qtA[(size_t)n0 * ldqA + idx2];
    if (NREL == 2) q01p = *(const half2_t*)&qtB[(size_t)n0 * ldqB + idx2];
    e00 = eidx[b0s];
    e01 = eidx[b0s + 1];
  }
  int n1 = n0 + nw;
  unsigned b1s = 0, b1e = 0;
  half2_t q10p = {}, q11p = {};
  if (n0 < N && n1 < N) {
    b1s = row_start[nodebase + n1];
    b1e = row_end[nodebase + n1];
    q10p = *(const half2_t*)&qtA[(size_t)n1 * ldqA + idx2];
    if (NREL == 2) q11p = *(const half2_t*)&qtB[(size_t)n1 * ldqB + idx2];
  }

  while (n0 < N) {
    unsigned e10 = 0, e11 = 0;
    if (n1 < N) {
      e10 = eidx[b1s];
      e11 = eidx[b1s + 1];
    }
    int n2 = n1 + nw;
    unsigned b2s = 0, b2e = 0;
    half2_t q20p = {}, q21p = {};
    if (n2 < N) {
      b2s = row_start[nodebase + n2];
      b2e = row_end[nodebase + n2];
      q20p = *(const half2_t*)&qtA[(size_t)n2 * ldqA + idx2];
      if (NREL == 2) q21p = *(const half2_t*)&qtB[(size_t)n2 * ldqB + idx2];
    }

    float vs = 0.f, ss = 0.f;
    unsigned i = b0s;

    auto do_pair = [&](unsigned p1, unsigned p2) {
      unsigned o1 = p1 & 0x7FFFFFFFu, o2 = p2 & 0x7FFFFFFFu;
      bool r1 = (NREL == 2) && (p1 >> 31);
      bool r2 = (NREL == 2) && (p2 >> 31);
      const _Float16* b1 = (r1 ? baseB : baseA) + o1;
      const _Float16* b2 = (r2 ? baseB : baseA) + o2;
      half2_t k21 = *(const half2_t*)&b1[idx2];
      float v1 = (float)b1[(r1 ? vofB : vofA) + lane];
      half2_t k22 = *(const half2_t*)&b2[idx2];
      float v2 = (float)b2[(r2 ? vofB : vofA) + lane];
      float sa = __builtin_amdgcn_fdot2(k21, r1 ? q01p : q00p, 0.f, false);
      float sb = __builtin_amdgcn_fdot2(k22, r2 ? q01p : q00p, 0.f, false);
#pragma unroll
      for (int off = 1; off <= 8; off <<= 1) {
        sa += __shfl_xor(sa, off, 32);
        sb += __shfl_xor(sb, off, 32);
      }
      float w1 = __expf(sa * (r1 ? pr1 : pr0));
      float w2 = __expf(sb * (r2 ? pr1 : pr0));
      ss += w1 + w2;
      vs = fmaf(w1, v1, vs);
      vs = fmaf(w2, v2, vs);
    };
    auto do_single = [&](unsigned p1) {
      unsigned o1 = p1 & 0x7FFFFFFFu;
      bool r1 = (NREL == 2) && (p1 >> 31);
      const _Float16* b1 = (r1 ? baseB : baseA) + o1;
      half2_t k21 = *(const half2_t*)&b1[idx2];
      float v1 = (float)b1[(r1 ? vofB : vofA) + lane];
      float sa = __builtin_amdgcn_fdot2(k21, r1 ? q01p : q00p, 0.f, false);
#pragma unroll
      for (int off = 1; off <= 8; off <<= 1) sa += __shfl_xor(sa, off, 32);
      float w1 = __expf(sa * (r1 ? pr1 : pr0));
      ss += w1;
      vs = fmaf(w1, v1, vs);
    };

    if (i + 2 <= b0e) { do_pair(e00, e01); i += 2; }
    else if (i < b0e) { do_single(e00); i = b0e; }
    for (; i + 2 <= b0e; i += 2) do_pair(eidx[i], eidx[i + 1]);
    if (i < b0e) do_single(eidx[i]);

    float val = (ss > 0.f) ? vs / ss : 0.f;
    val = fast_gelu(val);
    agg[((size_t)(nodebase + n0)) * 64 + lane] = (_Float16)val;

    n0 = n1; b0s = b1s; b0e = b1e; q00p = q10p; q01p = q11p; e00 = e10; e01 = e11;
    n1 = n2; b1s = b2s; b1e = b2e; q10p = q20p; q11p = q21p;
  }
}

__global__ __launch_bounds__(256) void gather_all(
    const unsigned* __restrict__ row_start, const unsigned* __restrict__ row_end,
    const unsigned* __restrict__ eidx,
    const _Float16* __restrict__ kqvQ, const _Float16* __restrict__ kqvE,
    const _Float16* __restrict__ kqvA,
    const float* __restrict__ p_rel, _Float16* __restrict__ agg)
{
  int bid = blockIdx.x;
  if (bid < GB_Q) {
    gather_body<1>(bid, GB_Q, NQ, BASE_Q, row_start, row_end, eidx,
                   kqvE, 128, kqvE, 128, kqvQ + 64, 192, kqvQ + 64, 192,
                   p_rel + 0, p_rel + 0, agg);
  } else if (bid < GB_Q + GB_E) {
    gather_body<1>(bid - GB_Q, GB_E, NE, BASE_E, row_start, row_end, eidx,
                   kqvE, 192, kqvE, 192, kqvE + 64, 320, kqvE + 64, 320,
                   p_rel + 2, p_rel + 2, agg);
  } else {
    gather_body<2>(bid - GB_Q - GB_E, GB_A, NA, BASE_A, row_start, row_end, eidx,
                   kqvE, 256, kqvQ, 128, kqvA, 128, kqvA + 64, 128,
                   p_rel + 4, p_rel + 6, agg);
  }
}

// ---------------- K8: merged out-proj ----------------

__global__ __launch_bounds__(256) void gemm_out_all(
    const _Float16* __restrict__ agg_h, const _Float16* __restrict__ y_h,
    const _Float16* __restrict__ WoutT, const float* __restrict__ b_out,
    const float* __restrict__ scale, const float* __restrict__ shift,
    const float* __restrict__ skip, float* __restrict__ zout)
{
  __shared__ _Float16 Bs[64 * 72];
  int bid = blockIdx.x;
  int t, row0, M;
  size_t nodeoff;
  if (bid < TOP_Q)              { t = 0; row0 = bid * 128;              M = NQ; nodeoff = 0; }
  else if (bid < TOP_Q + TOP_A) { t = 1; row0 = (bid - TOP_Q) * 128;    M = NA; nodeoff = NQ; }
  else                          { t = 2; row0 = (bid - TOP_Q - TOP_A) * 128; M = NE; nodeoff = NQ + NA; }
  const _Float16* Ah = agg_h + nodeoff * 64;
  const _Float16* resh = y_h + nodeoff * 64;
  float* Cf = zout + nodeoff * 64;
  const _Float16* WT = WoutT + (size_t)t * 64 * 72;
  const float* bias = b_out + t * 64;
  const float* rsc = scale + t * 64;
  const float* rsh = shift + t * 64;

  int tid = threadIdx.x;
  int w = tid >> 6, l = tid & 63;
  int lr = l & 15, lg = l >> 4;

  for (int idx = tid; idx < 64 * 72 / 8; idx += 256)
    *(half8_t*)&Bs[idx * 8] = *(const half8_t*)&WT[(size_t)idx * 8];

  half8_t afrag[2][2];
#pragma unroll
  for (int rt = 0; rt < 2; ++rt) {
    int gr = row0 + w * 32 + rt * 16 + lr;
    bool ok = gr < M;
#pragma unroll
    for (int ks = 0; ks < 2; ++ks) {
      half8_t h8 = {};
      if (ok) h8 = *(const half8_t*)&Ah[(size_t)gr * 64 + ks * 32 + lg * 8];
      afrag[rt][ks] = h8;
    }
  }
  __syncthreads();

  f32x4_t acc[2][4] = {};
#pragma unroll
  for (int ks = 0; ks < 2; ++ks) {
#pragma unroll
    for (int ct = 0; ct < 4; ++ct) {
      half8_t b = *(const half8_t*)&Bs[(ct * 16 + lr) * 72 + ks * 32 + lg * 8];
      acc[0][ct] = __builtin_amdgcn_mfma_f32_16x16x32_f16(afrag[0][ks], b, acc[0][ct], 0, 0, 0);
      acc[1][ct] = __builtin_amdgcn_mfma_f32_16x16x32_f16(afrag[1][ks], b, acc[1][ct], 0, 0, 0);
    }
  }

  float g = 1.f / (1.f + __expf(-skip[t]));
  float gb = 1.f - g;
#pragma unroll
  for (int rt = 0; rt < 2; ++rt) {
    int rbase = row0 + w * 32 + rt * 16 + lg * 4;
#pragma unroll
    for (int ct = 0; ct < 4; ++ct) {
      int col = ct * 16 + lr;
      float bval = bias[col];
#pragma unroll
      for (int j = 0; j < 4; ++j) {
        int row = rbase + j;
        if (row >= M) continue;
        float val = acc[rt][ct][j] + bval;
        float rv = (float)resh[(size_t)row * 64 + col];
        Cf[(size_t)row * 64 + col] = g * val + gb * (rsc[col] * rv + rsh[col]);
      }
    }
  }
}

// ---------------- K9: merged predictions ----------------

__global__ void pred_all(const int* __restrict__ pos, const int* __restrict__ neg,
                         const float* __restrict__ zq, const float* __restrict__ za,
                         float* __restrict__ outp) {
  int i = blockIdx.x * blockDim.x + threadIdx.x;
  if (i >= N_POS + N_NEG) return;
  int k; const int* qi; const int* ai; float* o;
  if (i < N_POS) { k = i; qi = pos; ai = pos + N_POS; o = outp; }
  else { k = i - N_POS; qi = neg; ai = neg + N_NEG; o = outp + N_POS; }
  const float4* a = (const float4*)(zq + (size_t)qi[k] * 64);
  const float4* b = (const float4*)(za + (size_t)ai[k] * 64);
  float ssum = 0.f;
#pragma unroll
  for (int j = 0; j < 16; ++j) {
    float4 x = a[j], y = b[j];
    ssum += x.x * y.x + x.y * y.y + x.z * y.z + x.w * y.w;
  }
  o[k] = ssum;
}

// ---------------- host launch ----------------

extern "C" void kernel_launch(void* const* d_in, const int* in_sizes, int n_in,
                              void* d_out, int out_size, void* d_ws, size_t ws_size,
                              hipStream_t stream) {
  const float* xq = (const float*)d_in[0];
  const float* xa = (const float*)d_in[1];
  const float* xe = (const float*)d_in[2];
  const int* e_e2q = (const int*)d_in[3];
  const int* e_e2e = (const int*)d_in[4];
  const int* e_e2a = (const int*)d_in[5];
  const int* e_q2a = (const int*)d_in[6];
  const int* pos_idx = (const int*)d_in[7];
  const int* neg_idx = (const int*)d_in[8];
  const float* W_in = (const float*)d_in[9];
  const float* b_in = (const float*)d_in[10];
  const float* bn_gamma = (const float*)d_in[11];
  const float* bn_beta = (const float*)d_in[12];
  const float* W_kqv = (const float*)d_in[13];
  const float* b_kqv = (const float*)d_in[14];
  const float* A_k = (const float*)d_in[15];
  const float* A_v = (const float*)d_in[16];
  const float* p_rel = (const float*)d_in[17];
  const float* W_out = (const float*)d_in[18];
  const float* b_out = (const float*)d_in[19];
  const float* skip = (const float*)d_in[20];
  float* out = (float*)d_out;

  float* ws = (float*)d_ws;
  size_t off = 0;
  _Float16* y_h = (_Float16*)(ws + off);    off += (size_t)NT_TOTAL * 32;
  _Float16* kqvQ = (_Float16*)(ws + off);   off += (size_t)NQ * 96;
  _Float16* kqvE = (_Float16*)(ws + off);   off += (size_t)NE * 160;
  _Float16* kqvA = (_Float16*)(ws + off);   off += (size_t)NA * 64;
  _Float16* agg_h = (_Float16*)(ws + off);  off += (size_t)NT_TOTAL * 32;
  float* stats = ws + off;                  off += 384;
  float* scale = ws + off;                  off += 192;
  float* shift = ws + off;                  off += 192;
  float* bias2 = ws + off;                  off += 576;
  float* bias_big = ws + off;               off += 640;
  _Float16* WqT = (_Float16*)(ws + off);    off += 192 * 72 / 2;
  _Float16* WeT = (_Float16*)(ws + off);    off += 320 * 72 / 2;
  _Float16* WaT = (_Float16*)(ws + off);    off += 128 * 72 / 2;
  _Float16* WinT = (_Float16*)(ws + off);   off += 3 * 64 * 136 / 2;
  _Float16* WoutT = (_Float16*)(ws + off);  off += 3 * 64 * 72 / 2;
  float* bstats = ws + off;                 off += (size_t)GIN_TOT * 128;
  unsigned* row_start = (unsigned*)(ws + off); off += NT_TOTAL;
  unsigned* cursor = (unsigned*)(ws + off);    off += NT_TOTAL;
  unsigned* bsums = (unsigned*)(ws + off);     off += 1024;
  unsigned* eidx = (unsigned*)(ws + off);      off += E_TOTAL + 8;

  float* zq_out = out + (N_POS + N_NEG);

  prep_misc<<<dim3(512), dim3(256), 0, stream>>>((float*)row_start, W_in, WinT, W_out, WoutT);

  inproj_hist_all<<<dim3(GIN_TOT + HB), dim3(256), 0, stream>>>(
      xq, xa, xe, WinT, b_in, y_h, bstats,
      e_e2q + E_E2Q, e_e2e + E_E2E, e_e2a + E_E2A, e_q2a + E_Q2A, row_start);

  reduce_scan1<<<dim3(384 + NBLK_SCAN), dim3(256), 0, stream>>>(
      bstats, stats, row_start, bsums);

  scan2_bn<<<dim3(2), dim3(256), 0, stream>>>(
      bsums, NBLK_SCAN, stats, bn_gamma, bn_beta, scale, shift, b_kqv, W_kqv, bias2);

  scan3_wprep<<<dim3(NBLK_SCAN + 160), dim3(256), 0, stream>>>(
      row_start, bsums, cursor, W_kqv, bias2, A_k, A_v, scale,
      WqT, WeT, WaT, bias_big);

  kqv_scatter4<<<dim3(KS4_TOT), dim3(512), SMEM_KQV, stream>>>(
      y_h, WqT, WeT, WaT, bias_big, kqvQ, kqvE, kqvA,
      e_e2q, e_e2q + E_E2Q, e_e2e, e_e2e + E_E2E,
      e_e2a, e_e2a + E_E2A, e_q2a, e_q2a + E_Q2A, cursor, eidx);

  gather_all<<<dim3(GB_Q + GB_E + GB_A), dim3(256), 0, stream>>>(
      row_start, cursor, eidx, kqvQ, kqvE, kqvA, p_rel, agg_h);

  gemm_out_all<<<dim3(TOP_Q + TOP_A + TOP_E), dim3(256), 0, stream>>>(
      agg_h, y_h, WoutT, b_out, scale, shift, skip, zq_out);

  pred_all<<<dim3(CDIV(N_POS + N_NEG, 256)), dim3(256), 0, stream>>>(
      pos_idx, neg_idx, zq_out, zq_out + (size_t)NQ * 64, out);
}